// Round 1
// baseline (324.610 us; speedup 1.0000x reference)
//
#include <hip/hip_runtime.h>
#include <math.h>

typedef __bf16 bf16x8 __attribute__((ext_vector_type(8)));
typedef float f32x4 __attribute__((ext_vector_type(4)));
typedef unsigned short u16;
typedef unsigned int u32;

__device__ __forceinline__ u16 f2bf(float f) {
  union { float f; u32 u; } v; v.f = f;
  u32 u = v.u;
  return (u16)((u + 0x7FFFu + ((u >> 16) & 1u)) >> 16);
}

__device__ __forceinline__ f32x4 mfma16(bf16x8 a, bf16x8 b, f32x4 c) {
  return __builtin_amdgcn_mfma_f32_16x16x32_bf16(a, b, c, 0, 0, 0);
}

__device__ __forceinline__ void gld16(const void* g, void* l) {
  __builtin_amdgcn_global_load_lds(
      (const __attribute__((address_space(1))) void*)(void*)g,
      (__attribute__((address_space(3))) void*)l,
      16, 0, 0);
}

// ---------------- weight fp32 -> bf16 transpose (Wt[n][k] = W[k][n]) ----------
__global__ __launch_bounds__(256)
void wconv_t(const float* __restrict__ W, u16* __restrict__ Wt, int K, int N) {
  __shared__ float tile[64][65];
  const int k0 = blockIdx.y * 64, n0 = blockIdx.x * 64;
  const int t = threadIdx.x;
  const int tr = t >> 4;
  const int tc = (t & 15) * 4;
#pragma unroll
  for (int it = 0; it < 4; it++) {
    const int r = tr + it * 16;
    const float4 v = *(const float4*)(W + (size_t)(k0 + r) * N + n0 + tc);
    tile[r][tc] = v.x; tile[r][tc + 1] = v.y; tile[r][tc + 2] = v.z; tile[r][tc + 3] = v.w;
  }
  __syncthreads();
#pragma unroll
  for (int it = 0; it < 4; it++) {
    const int rn = tr + it * 16;
    ushort4 o;
    o.x = f2bf(tile[tc][rn]);
    o.y = f2bf(tile[tc + 1][rn]);
    o.z = f2bf(tile[tc + 2][rn]);
    o.w = f2bf(tile[tc + 3][rn]);
    *(ushort4*)(Wt + (size_t)(n0 + rn) * K + k0 + tc) = o;
  }
}

// ---------------- LayerNorm (fp32 in -> bf16 out) ----------------------------
__global__ __launch_bounds__(256)
void ln_bf16(const float* __restrict__ x, const float* __restrict__ w,
             const float* __restrict__ b, u16* __restrict__ out) {
  const int row = blockIdx.x;
  const int t = threadIdx.x;
  const float4 v = *(const float4*)(x + (size_t)row * 1024 + t * 4);
  float s = v.x + v.y + v.z + v.w;
  float s2 = v.x * v.x + v.y * v.y + v.z * v.z + v.w * v.w;
#pragma unroll
  for (int m = 1; m < 64; m <<= 1) {
    s += __shfl_xor(s, m);
    s2 += __shfl_xor(s2, m);
  }
  __shared__ float red[8];
  if ((t & 63) == 0) { red[t >> 6] = s; red[4 + (t >> 6)] = s2; }
  __syncthreads();
  s = red[0] + red[1] + red[2] + red[3];
  s2 = red[4] + red[5] + red[6] + red[7];
  const float mu = s * (1.f / 1024.f);
  const float var = fmaxf(s2 * (1.f / 1024.f) - mu * mu, 0.f);
  const float rstd = rsqrtf(var + 1e-5f);
  const float* wp = w + t * 4;
  const float* bp = b + t * 4;
  ushort4 o;
  o.x = f2bf((v.x - mu) * rstd * wp[0] + bp[0]);
  o.y = f2bf((v.y - mu) * rstd * wp[1] + bp[1]);
  o.z = f2bf((v.z - mu) * rstd * wp[2] + bp[2]);
  o.w = f2bf((v.w - mu) * rstd * wp[3] + bp[3]);
  *(ushort4*)(out + (size_t)row * 1024 + t * 4) = o;
}

// ---------------- bf16 GEMM, 128x128 tile, BK=32, m97 structure --------------
// A: [M][K] bf16 row-major; Bt: [N][K] bf16 (i.e. B transposed). fp32 accum.
// EPI 0: QKV split (writes Q,K row-major bf16; V transposed bf16 [D][S])
// EPI 1: outF = res + C           (fp32)
// EPI 2: outB = bf16(gelu(C + bias))
// EPI 3: outF = res + C + bias    (fp32)
template <int EPI>
__global__ __launch_bounds__(256)
void gemm_bf16(const u16* __restrict__ A, const u16* __restrict__ Bt,
               int M, int N, int K,
               const float* __restrict__ bias, const float* __restrict__ res,
               float* __restrict__ outF, u16* __restrict__ outB,
               u16* __restrict__ qo, u16* __restrict__ ko, u16* __restrict__ vo) {
  __shared__ __attribute__((aligned(16))) u16 lA[128 * 32];
  __shared__ __attribute__((aligned(16))) u16 lB[128 * 32];
  const int t = threadIdx.x;
  const int l = t & 63;
  const int w = t >> 6;
  const int wr = w >> 1, wc = w & 1;
  const int l15 = l & 15, lg = l >> 4;
  const int m0 = blockIdx.y * 128, n0 = blockIdx.x * 128;

  f32x4 acc[4][4] = {};

  const int lr = t >> 2;
  const int lc = (t & 3) << 3;
  const u16* ag0 = A + (size_t)(m0 + lr) * K + lc;
  const u16* ag1 = A + (size_t)(m0 + 64 + lr) * K + lc;
  const u16* bg0 = Bt + (size_t)(n0 + lr) * K + lc;
  const u16* bg1 = Bt + (size_t)(n0 + 64 + lr) * K + lc;
  u16* la0 = &lA[t * 8];
  u16* la1 = &lA[2048 + t * 8];
  u16* lb0 = &lB[t * 8];
  u16* lb1 = &lB[2048 + t * 8];

  for (int k0 = 0; k0 < K; k0 += 32) {
    gld16(ag0 + k0, la0);
    gld16(ag1 + k0, la1);
    gld16(bg0 + k0, lb0);
    gld16(bg1 + k0, lb1);
    __syncthreads();
    bf16x8 af[4], bfr[4];
#pragma unroll
    for (int i = 0; i < 4; i++)
      af[i] = *(const bf16x8*)&lA[(wr * 64 + i * 16 + l15) * 32 + lg * 8];
#pragma unroll
    for (int j = 0; j < 4; j++)
      bfr[j] = *(const bf16x8*)&lB[(wc * 64 + j * 16 + l15) * 32 + lg * 8];
#pragma unroll
    for (int i = 0; i < 4; i++)
#pragma unroll
      for (int j = 0; j < 4; j++)
        acc[i][j] = mfma16(af[i], bfr[j], acc[i][j]);
    __syncthreads();
  }

  const int mr0 = m0 + wr * 64 + lg * 4;
  const int nc0 = n0 + wc * 64 + l15;
#pragma unroll
  for (int i = 0; i < 4; i++) {
    const int mr = mr0 + i * 16;
#pragma unroll
    for (int j = 0; j < 4; j++) {
      const int nc = nc0 + j * 16;
      if (EPI == 0) {
        const int sel = nc >> 10;
        const int cc = nc & 1023;
        if (sel == 2) {
          ushort4 o;
          o.x = f2bf(acc[i][j][0]); o.y = f2bf(acc[i][j][1]);
          o.z = f2bf(acc[i][j][2]); o.w = f2bf(acc[i][j][3]);
          *(ushort4*)(vo + (size_t)cc * 2048 + mr) = o;
        } else {
          u16* dst = (sel == 0) ? qo : ko;
#pragma unroll
          for (int e = 0; e < 4; e++)
            dst[(size_t)(mr + e) * 1024 + cc] = f2bf(acc[i][j][e]);
        }
      } else if (EPI == 1) {
#pragma unroll
        for (int e = 0; e < 4; e++) {
          const size_t idx = (size_t)(mr + e) * N + nc;
          outF[idx] = res[idx] + acc[i][j][e];
        }
      } else if (EPI == 2) {
        const float bb = bias[nc];
#pragma unroll
        for (int e = 0; e < 4; e++) {
          const float v = acc[i][j][e] + bb;
          const float g = 0.5f * v * (1.0f + tanhf(0.7978845608028654f * (v + 0.044715f * v * v * v)));
          outB[(size_t)(mr + e) * N + nc] = f2bf(g);
        }
      } else {
        const float bb = bias[nc];
#pragma unroll
        for (int e = 0; e < 4; e++) {
          const size_t idx = (size_t)(mr + e) * N + nc;
          outF[idx] = res[idx] + acc[i][j][e] + bb;
        }
      }
    }
  }
}

// ---------------- causal flash attention ------------------------------------
// Qb,Kb: [S][D] bf16 (D = h*64+dh); Vt: [D][S] bf16. Ob: [S][D] bf16.
// Block = (q-tile of 64, head). 4 waves; wave owns 16 q rows.
__global__ __launch_bounds__(256)
void attn_fwd(const u16* __restrict__ Qb, const u16* __restrict__ Kb,
              const u16* __restrict__ Vt, u16* __restrict__ Ob) {
  __shared__ __attribute__((aligned(16))) u16 lP[4][16 * 32];
  const int t = threadIdx.x;
  const int l = t & 63, w = t >> 6;
  const int l15 = l & 15, lg = l >> 4;
  const int h = blockIdx.y;
  const int qb = blockIdx.x * 64 + w * 16;

  bf16x8 qf[2];
  qf[0] = *(const bf16x8*)(Qb + (size_t)(qb + l15) * 1024 + h * 64 + lg * 8);
  qf[1] = *(const bf16x8*)(Qb + (size_t)(qb + l15) * 1024 + h * 64 + 32 + lg * 8);

  float mrow[4] = {-1e30f, -1e30f, -1e30f, -1e30f};
  float lrow[4] = {0.f, 0.f, 0.f, 0.f};
  f32x4 accO[4] = {};

  const int nk = (qb + 16 + 31) >> 5;
  for (int kt = 0; kt < nk; kt++) {
    const int k0 = kt * 32;
    f32x4 s0v = {}, s1v = {};
#pragma unroll
    for (int kk = 0; kk < 2; kk++) {
      const bf16x8 kf0 = *(const bf16x8*)(Kb + (size_t)(k0 + l15) * 1024 + h * 64 + kk * 32 + lg * 8);
      const bf16x8 kf1 = *(const bf16x8*)(Kb + (size_t)(k0 + 16 + l15) * 1024 + h * 64 + kk * 32 + lg * 8);
      s0v = mfma16(qf[kk], kf0, s0v);
      s1v = mfma16(qf[kk], kf1, s1v);
    }
#pragma unroll
    for (int e = 0; e < 4; e++) {
      const int qr = qb + lg * 4 + e;
      float s0 = s0v[e] * 0.125f;
      float s1 = s1v[e] * 0.125f;
      if (k0 + l15 > qr) s0 = -1e30f;
      if (k0 + 16 + l15 > qr) s1 = -1e30f;
      float mx = fmaxf(s0, s1);
      mx = fmaxf(mx, __shfl_xor(mx, 1));
      mx = fmaxf(mx, __shfl_xor(mx, 2));
      mx = fmaxf(mx, __shfl_xor(mx, 4));
      mx = fmaxf(mx, __shfl_xor(mx, 8));
      const float mn = fmaxf(mrow[e], mx);
      const float sc = __expf(mrow[e] - mn);
      const float p0 = __expf(s0 - mn);
      const float p1 = __expf(s1 - mn);
      float sm = p0 + p1;
      sm += __shfl_xor(sm, 1);
      sm += __shfl_xor(sm, 2);
      sm += __shfl_xor(sm, 4);
      sm += __shfl_xor(sm, 8);
      lrow[e] = lrow[e] * sc + sm;
      mrow[e] = mn;
      accO[0][e] *= sc; accO[1][e] *= sc; accO[2][e] *= sc; accO[3][e] *= sc;
      lP[w][(lg * 4 + e) * 32 + l15] = f2bf(p0);
      lP[w][(lg * 4 + e) * 32 + 16 + l15] = f2bf(p1);
    }
    const bf16x8 pf = *(const bf16x8*)&lP[w][l15 * 32 + lg * 8];
#pragma unroll
    for (int nb = 0; nb < 4; nb++) {
      const bf16x8 vf = *(const bf16x8*)(Vt + (size_t)(h * 64 + nb * 16 + l15) * 2048 + k0 + lg * 8);
      accO[nb] = mfma16(pf, vf, accO[nb]);
    }
  }
#pragma unroll
  for (int nb = 0; nb < 4; nb++) {
#pragma unroll
    for (int e = 0; e < 4; e++) {
      const float o = accO[nb][e] / lrow[e];
      Ob[(size_t)(qb + lg * 4 + e) * 1024 + h * 64 + nb * 16 + l15] = f2bf(o);
    }
  }
}

// ---------------- launch ----------------------------------------------------
extern "C" void kernel_launch(void* const* d_in, const int* in_sizes, int n_in,
                              void* d_out, int out_size, void* d_ws, size_t ws_size,
                              hipStream_t stream) {
  const float* x     = (const float*)d_in[0];
  const float* W_qkv = (const float*)d_in[1];
  const float* W_o   = (const float*)d_in[2];
  const float* W1    = (const float*)d_in[3];
  const float* b1    = (const float*)d_in[4];
  const float* W2    = (const float*)d_in[5];
  const float* b2    = (const float*)d_in[6];
  const float* ln_aw = (const float*)d_in[7];
  const float* ln_ab = (const float*)d_in[8];
  const float* ln_mw = (const float*)d_in[9];
  const float* ln_mb = (const float*)d_in[10];

  char* ws = (char*)d_ws;
  u16* Wqkv_t = (u16*)(ws);                  // [3072][1024] bf16   6 MB
  u16* Wo_t   = (u16*)(ws + 6291456);        // [1024][1024]        2 MB
  u16* W1_t   = (u16*)(ws + 8388608);        // [4096][1024]        8 MB
  u16* W2_t   = (u16*)(ws + 16777216);       // [1024][4096]        8 MB
  u16* h1     = (u16*)(ws + 25165824);       // [2048][1024]        4 MB
  u16* Qb     = (u16*)(ws + 29360128);       // [2048][1024]        4 MB
  u16* Kb     = (u16*)(ws + 33554432);       // [2048][1024]        4 MB
  u16* Vt     = (u16*)(ws + 37748736);       // [1024][2048]        4 MB
  u16* attnb  = (u16*)(ws + 41943040);       // [2048][1024]        4 MB
  float* x2   = (float*)(ws + 46137344);     // [2048][1024] f32    8 MB
  u16* h2     = (u16*)(ws + 54525952);       // [2048][1024]        4 MB
  u16* ffb    = (u16*)(ws + 58720256);       // [2048][4096]       16 MB
  (void)ws_size; (void)in_sizes; (void)n_in; (void)out_size;

  wconv_t<<<dim3(48, 16), 256, 0, stream>>>(W_qkv, Wqkv_t, 1024, 3072);
  wconv_t<<<dim3(16, 16), 256, 0, stream>>>(W_o, Wo_t, 1024, 1024);
  wconv_t<<<dim3(64, 16), 256, 0, stream>>>(W1, W1_t, 1024, 4096);
  wconv_t<<<dim3(16, 64), 256, 0, stream>>>(W2, W2_t, 4096, 1024);

  ln_bf16<<<2048, 256, 0, stream>>>(x, ln_aw, ln_ab, h1);

  gemm_bf16<0><<<dim3(24, 16), 256, 0, stream>>>(h1, Wqkv_t, 2048, 3072, 1024,
      nullptr, nullptr, nullptr, nullptr, Qb, Kb, Vt);

  attn_fwd<<<dim3(32, 16), 256, 0, stream>>>(Qb, Kb, Vt, attnb);

  gemm_bf16<1><<<dim3(8, 16), 256, 0, stream>>>(attnb, Wo_t, 2048, 1024, 1024,
      nullptr, x, x2, nullptr, nullptr, nullptr, nullptr);

  ln_bf16<<<2048, 256, 0, stream>>>(x2, ln_mw, ln_mb, h2);

  gemm_bf16<2><<<dim3(32, 16), 256, 0, stream>>>(h2, W1_t, 2048, 4096, 1024,
      b1, nullptr, nullptr, ffb, nullptr, nullptr, nullptr);

  gemm_bf16<3><<<dim3(8, 16), 256, 0, stream>>>(ffb, W2_t, 2048, 1024, 4096,
      b2, x2, (float*)d_out, nullptr, nullptr, nullptr, nullptr);
}

// Round 2
// 246.340 us; speedup vs baseline: 1.3177x; 1.3177x over previous
//
#include <hip/hip_runtime.h>
#include <math.h>

typedef __bf16 bf16x8 __attribute__((ext_vector_type(8)));
typedef float f32x4 __attribute__((ext_vector_type(4)));
typedef unsigned short u16;
typedef unsigned short u16x8 __attribute__((ext_vector_type(8)));
typedef unsigned int u32;

__device__ __forceinline__ u16 f2bf(float f) {
  union { float f; u32 u; } v; v.f = f;
  u32 u = v.u;
  return (u16)((u + 0x7FFFu + ((u >> 16) & 1u)) >> 16);
}

__device__ __forceinline__ f32x4 mfma16(bf16x8 a, bf16x8 b, f32x4 c) {
  return __builtin_amdgcn_mfma_f32_16x16x32_bf16(a, b, c, 0, 0, 0);
}

__device__ __forceinline__ void gld16(const void* g, void* l) {
  __builtin_amdgcn_global_load_lds(
      (const __attribute__((address_space(1))) void*)(void*)g,
      (__attribute__((address_space(3))) void*)l,
      16, 0, 0);
}

// ---------------- weight fp32 -> bf16 transpose (Wt[n][k] = W[k][n]) ----------
__global__ __launch_bounds__(256)
void wconv_t(const float* __restrict__ W, u16* __restrict__ Wt, int K, int N) {
  __shared__ float tile[64][65];
  const int k0 = blockIdx.y * 64, n0 = blockIdx.x * 64;
  const int t = threadIdx.x;
  const int tr = t >> 4;
  const int tc = (t & 15) * 4;
#pragma unroll
  for (int it = 0; it < 4; it++) {
    const int r = tr + it * 16;
    const float4 v = *(const float4*)(W + (size_t)(k0 + r) * N + n0 + tc);
    tile[r][tc] = v.x; tile[r][tc + 1] = v.y; tile[r][tc + 2] = v.z; tile[r][tc + 3] = v.w;
  }
  __syncthreads();
#pragma unroll
  for (int it = 0; it < 4; it++) {
    const int rn = tr + it * 16;
    ushort4 o;
    o.x = f2bf(tile[tc][rn]);
    o.y = f2bf(tile[tc + 1][rn]);
    o.z = f2bf(tile[tc + 2][rn]);
    o.w = f2bf(tile[tc + 3][rn]);
    *(ushort4*)(Wt + (size_t)(n0 + rn) * K + k0 + tc) = o;
  }
}

// ---------------- LayerNorm (fp32 in -> bf16 out) ----------------------------
__global__ __launch_bounds__(256)
void ln_bf16(const float* __restrict__ x, const float* __restrict__ w,
             const float* __restrict__ b, u16* __restrict__ out) {
  const int row = blockIdx.x;
  const int t = threadIdx.x;
  const float4 v = *(const float4*)(x + (size_t)row * 1024 + t * 4);
  float s = v.x + v.y + v.z + v.w;
  float s2 = v.x * v.x + v.y * v.y + v.z * v.z + v.w * v.w;
#pragma unroll
  for (int m = 1; m < 64; m <<= 1) {
    s += __shfl_xor(s, m);
    s2 += __shfl_xor(s2, m);
  }
  __shared__ float red[8];
  if ((t & 63) == 0) { red[t >> 6] = s; red[4 + (t >> 6)] = s2; }
  __syncthreads();
  s = red[0] + red[1] + red[2] + red[3];
  s2 = red[4] + red[5] + red[6] + red[7];
  const float mu = s * (1.f / 1024.f);
  const float var = fmaxf(s2 * (1.f / 1024.f) - mu * mu, 0.f);
  const float rstd = rsqrtf(var + 1e-5f);
  const float* wp = w + t * 4;
  const float* bp = b + t * 4;
  ushort4 o;
  o.x = f2bf((v.x - mu) * rstd * wp[0] + bp[0]);
  o.y = f2bf((v.y - mu) * rstd * wp[1] + bp[1]);
  o.z = f2bf((v.z - mu) * rstd * wp[2] + bp[2]);
  o.w = f2bf((v.w - mu) * rstd * wp[3] + bp[3]);
  *(ushort4*)(out + (size_t)row * 1024 + t * 4) = o;
}

// ---------------- bf16 GEMM, BMx128 tile, BK=32, m97 structure ---------------
// A: [M][K] bf16 row-major; Bt: [N][K] bf16 (B transposed). fp32 accum.
// BM = 128: 4 waves as 2x2 of 64x64.  BM = 64: 4 waves as 1x4 of 64x32.
// EPI 0: QKV split (Q,K row-major bf16; V transposed bf16 [D][S])
// EPI 1: outF = res + C           (fp32)
// EPI 2: outB = bf16(gelu(C + bias))
// EPI 3: outF = res + C + bias    (fp32)
template <int BM, int EPI>
__global__ __launch_bounds__(256)
void gemm_bf16(const u16* __restrict__ A, const u16* __restrict__ Bt,
               int M, int N, int K,
               const float* __restrict__ bias, const float* __restrict__ res,
               float* __restrict__ outF, u16* __restrict__ outB,
               u16* __restrict__ qo, u16* __restrict__ ko, u16* __restrict__ vo) {
  __shared__ __attribute__((aligned(16))) u16 lA[BM * 32];
  __shared__ __attribute__((aligned(16))) u16 lB[128 * 32];
  const int t = threadIdx.x;
  const int l = t & 63;
  const int w = t >> 6;
  const int WR = (BM == 128) ? (w >> 1) * 64 : 0;
  const int WC = (BM == 128) ? (w & 1) * 64 : w * 32;
  const int NJ = (BM == 128) ? 4 : 2;
  const int l15 = l & 15, lg = l >> 4;
  const int m0 = blockIdx.y * BM, n0 = blockIdx.x * 128;

  f32x4 acc[4][4] = {};

  const int lr = t >> 2;
  const int lc = (t & 3) << 3;
  const u16* ag0 = A + (size_t)(m0 + lr) * K + lc;
  const u16* ag1 = A + (size_t)(m0 + 64 + lr) * K + lc;
  const u16* bg0 = Bt + (size_t)(n0 + lr) * K + lc;
  const u16* bg1 = Bt + (size_t)(n0 + 64 + lr) * K + lc;
  u16* la0 = &lA[t * 8];
  u16* la1 = &lA[2048 + t * 8];
  u16* lb0 = &lB[t * 8];
  u16* lb1 = &lB[2048 + t * 8];

  for (int k0 = 0; k0 < K; k0 += 32) {
    gld16(ag0 + k0, la0);
    if (BM == 128) gld16(ag1 + k0, la1);
    gld16(bg0 + k0, lb0);
    gld16(bg1 + k0, lb1);
    __syncthreads();
    bf16x8 af[4], bfr[4];
#pragma unroll
    for (int i = 0; i < 4; i++)
      af[i] = *(const bf16x8*)&lA[(WR + i * 16 + l15) * 32 + lg * 8];
#pragma unroll
    for (int j = 0; j < NJ; j++)
      bfr[j] = *(const bf16x8*)&lB[(WC + j * 16 + l15) * 32 + lg * 8];
#pragma unroll
    for (int i = 0; i < 4; i++)
#pragma unroll
      for (int j = 0; j < NJ; j++)
        acc[i][j] = mfma16(af[i], bfr[j], acc[i][j]);
    __syncthreads();
  }

  const int mr0 = m0 + WR + lg * 4;
  const int nc0 = n0 + WC + l15;
#pragma unroll
  for (int i = 0; i < 4; i++) {
    const int mr = mr0 + i * 16;
#pragma unroll
    for (int j = 0; j < NJ; j++) {
      const int nc = nc0 + j * 16;
      if (EPI == 0) {
        const int sel = nc >> 10;
        const int cc = nc & 1023;
        if (sel == 2) {
          ushort4 o;
          o.x = f2bf(acc[i][j][0]); o.y = f2bf(acc[i][j][1]);
          o.z = f2bf(acc[i][j][2]); o.w = f2bf(acc[i][j][3]);
          *(ushort4*)(vo + (size_t)cc * 2048 + mr) = o;
        } else {
          u16* dst = (sel == 0) ? qo : ko;
#pragma unroll
          for (int e = 0; e < 4; e++)
            dst[(size_t)(mr + e) * 1024 + cc] = f2bf(acc[i][j][e]);
        }
      } else if (EPI == 1) {
#pragma unroll
        for (int e = 0; e < 4; e++) {
          const size_t idx = (size_t)(mr + e) * N + nc;
          outF[idx] = res[idx] + acc[i][j][e];
        }
      } else if (EPI == 2) {
        const float bb = bias[nc];
#pragma unroll
        for (int e = 0; e < 4; e++) {
          const float v = acc[i][j][e] + bb;
          const float g = 0.5f * v * (1.0f + tanhf(0.7978845608028654f * (v + 0.044715f * v * v * v)));
          outB[(size_t)(mr + e) * N + nc] = f2bf(g);
        }
      } else {
        const float bb = bias[nc];
#pragma unroll
        for (int e = 0; e < 4; e++) {
          const size_t idx = (size_t)(mr + e) * N + nc;
          outF[idx] = res[idx] + acc[i][j][e] + bb;
        }
      }
    }
  }
}

// ---------------- causal flash attention v2 ----------------------------------
// Qb,Kb: [S][1024] bf16; Vt: [1024][2048] bf16 (V^T). Ob: [S][1024] bf16.
// Block = 256 thr (4 waves), one head, 32 q-rows. Waves split K (stride-4
// k-tiles of 32); no-max softmax (scores bounded) makes partials associative;
// LDS combine at end. Swapped QK^T: mfma(K,Q) puts P lane-local per q-col.
__global__ __launch_bounds__(256)
void attn_fwd(const u16* __restrict__ Qb, const u16* __restrict__ Kb,
              const u16* __restrict__ Vt, u16* __restrict__ Ob) {
  __shared__ __attribute__((aligned(16))) char smem[33280];
  float* sO = (float*)smem;            // [4][2048] f32 (after barrier)
  float* sL = (float*)(smem + 32768);  // [4][32]
  u16* lP = (u16*)smem;                // [4 waves][2 g][16 rows][40] (pre-barrier)

  const int t = threadIdx.x;
  const int l = t & 63, w = t >> 6;
  const int l15 = l & 15, lg = l >> 4;
  const int h = blockIdx.y;
  const int qt = 63 - (int)blockIdx.x;  // LPT: heaviest tiles first
  const int qb = qt * 32;

  u16* myP = lP + w * 1280;

  bf16x8 qf[2][2];
#pragma unroll
  for (int g = 0; g < 2; g++)
#pragma unroll
    for (int kk = 0; kk < 2; kk++)
      qf[g][kk] = *(const bf16x8*)(Qb + (size_t)(qb + g * 16 + l15) * 1024 + h * 64 + kk * 32 + lg * 8);

  f32x4 accO[2][4] = {};
  float lsum[2] = {0.f, 0.f};

  for (int kt = w; kt <= qt; kt += 4) {
    const int k0 = kt * 32;
    bf16x8 kf[2][2], vf[4];
#pragma unroll
    for (int f = 0; f < 2; f++)
#pragma unroll
      for (int kk = 0; kk < 2; kk++)
        kf[kk][f] = *(const bf16x8*)(Kb + (size_t)(k0 + f * 16 + l15) * 1024 + h * 64 + kk * 32 + lg * 8);
#pragma unroll
    for (int nb = 0; nb < 4; nb++)
      vf[nb] = *(const bf16x8*)(Vt + (size_t)(h * 64 + nb * 16 + l15) * 2048 + k0 + lg * 8);

    f32x4 sv[2][2] = {};
#pragma unroll
    for (int g = 0; g < 2; g++)
#pragma unroll
      for (int f = 0; f < 2; f++)
#pragma unroll
        for (int kk = 0; kk < 2; kk++)
          sv[g][f] = mfma16(kf[kk][f], qf[g][kk], sv[g][f]);

    // sv[g][f][e] = score(q = qb+g*16+l15, k = k0+f*16+lg*4+e)
    const bool diag = (kt == qt);
#pragma unroll
    for (int g = 0; g < 2; g++) {
#pragma unroll
      for (int f = 0; f < 2; f++) {
        ushort4 pk;
        float ps = 0.f;
#pragma unroll
        for (int e = 0; e < 4; e++) {
          float p = __expf(sv[g][f][e] * 0.125f);
          if (diag && (k0 + f * 16 + lg * 4 + e > qb + g * 16 + l15)) p = 0.f;
          ps += p;
          ((u16*)&pk)[e] = f2bf(p);
        }
        lsum[g] += ps;
        *(ushort4*)(myP + g * 640 + l15 * 40 + f * 16 + lg * 4) = pk;
      }
    }
    // wave-private LDS: compiler orders write->read via lgkmcnt (no barrier)
    bf16x8 pf[2];
#pragma unroll
    for (int g = 0; g < 2; g++)
      pf[g] = *(const bf16x8*)(myP + g * 640 + l15 * 40 + lg * 8);
#pragma unroll
    for (int nb = 0; nb < 4; nb++) {
      accO[0][nb] = mfma16(pf[0], vf[nb], accO[0][nb]);
      accO[1][nb] = mfma16(pf[1], vf[nb], accO[1][nb]);
    }
  }

  float lsr[2];
#pragma unroll
  for (int g = 0; g < 2; g++) {
    float v = lsum[g];
    v += __shfl_xor(v, 16);
    v += __shfl_xor(v, 32);
    lsr[g] = v;
  }

  __syncthreads();  // all waves done with lP; smem becomes sO
#pragma unroll
  for (int g = 0; g < 2; g++) {
#pragma unroll
    for (int nb = 0; nb < 4; nb++)
#pragma unroll
      for (int e = 0; e < 4; e++)
        sO[w * 2048 + (g * 16 + lg * 4 + e) * 64 + nb * 16 + l15] = accO[g][nb][e];
    if (lg == 0) sL[w * 32 + g * 16 + l15] = lsr[g];
  }
  __syncthreads();

  const int base = t * 8;
  const int row = base >> 6;
  const int col = base & 63;
  f32x4 a0 = {}, a1 = {};
  float ls = 0.f;
#pragma unroll
  for (int ww = 0; ww < 4; ww++) {
    a0 += *(const f32x4*)&sO[ww * 2048 + base];
    a1 += *(const f32x4*)&sO[ww * 2048 + base + 4];
    ls += sL[ww * 32 + row];
  }
  const float rinv = 1.0f / ls;
  u16x8 o;
#pragma unroll
  for (int j = 0; j < 4; j++) {
    o[j] = f2bf(a0[j] * rinv);
    o[4 + j] = f2bf(a1[j] * rinv);
  }
  *(u16x8*)(Ob + (size_t)(qb + row) * 1024 + h * 64 + col) = o;
}

// ---------------- launch ----------------------------------------------------
extern "C" void kernel_launch(void* const* d_in, const int* in_sizes, int n_in,
                              void* d_out, int out_size, void* d_ws, size_t ws_size,
                              hipStream_t stream) {
  const float* x     = (const float*)d_in[0];
  const float* W_qkv = (const float*)d_in[1];
  const float* W_o   = (const float*)d_in[2];
  const float* W1    = (const float*)d_in[3];
  const float* b1    = (const float*)d_in[4];
  const float* W2    = (const float*)d_in[5];
  const float* b2    = (const float*)d_in[6];
  const float* ln_aw = (const float*)d_in[7];
  const float* ln_ab = (const float*)d_in[8];
  const float* ln_mw = (const float*)d_in[9];
  const float* ln_mb = (const float*)d_in[10];

  char* ws = (char*)d_ws;
  u16* Wqkv_t = (u16*)(ws);                  // [3072][1024] bf16   6 MB
  u16* Wo_t   = (u16*)(ws + 6291456);        // [1024][1024]        2 MB
  u16* W1_t   = (u16*)(ws + 8388608);        // [4096][1024]        8 MB
  u16* W2_t   = (u16*)(ws + 16777216);       // [1024][4096]        8 MB
  u16* h1     = (u16*)(ws + 25165824);       // [2048][1024]        4 MB
  u16* Qb     = (u16*)(ws + 29360128);       // [2048][1024]        4 MB
  u16* Kb     = (u16*)(ws + 33554432);       // [2048][1024]        4 MB
  u16* Vt     = (u16*)(ws + 37748736);       // [1024][2048]        4 MB
  u16* attnb  = (u16*)(ws + 41943040);       // [2048][1024]        4 MB
  float* x2   = (float*)(ws + 46137344);     // [2048][1024] f32    8 MB
  u16* h2     = (u16*)(ws + 54525952);       // [2048][1024]        4 MB
  u16* ffb    = (u16*)(ws + 58720256);       // [2048][4096]       16 MB
  (void)ws_size; (void)in_sizes; (void)n_in; (void)out_size;

  wconv_t<<<dim3(48, 16), 256, 0, stream>>>(W_qkv, Wqkv_t, 1024, 3072);
  wconv_t<<<dim3(16, 16), 256, 0, stream>>>(W_o, Wo_t, 1024, 1024);
  wconv_t<<<dim3(64, 16), 256, 0, stream>>>(W1, W1_t, 1024, 4096);
  wconv_t<<<dim3(16, 64), 256, 0, stream>>>(W2, W2_t, 4096, 1024);

  ln_bf16<<<2048, 256, 0, stream>>>(x, ln_aw, ln_ab, h1);

  gemm_bf16<128, 0><<<dim3(24, 16), 256, 0, stream>>>(h1, Wqkv_t, 2048, 3072, 1024,
      nullptr, nullptr, nullptr, nullptr, Qb, Kb, Vt);

  attn_fwd<<<dim3(64, 16), 256, 0, stream>>>(Qb, Kb, Vt, attnb);

  gemm_bf16<64, 1><<<dim3(8, 32), 256, 0, stream>>>(attnb, Wo_t, 2048, 1024, 1024,
      nullptr, x, x2, nullptr, nullptr, nullptr, nullptr);

  ln_bf16<<<2048, 256, 0, stream>>>(x2, ln_mw, ln_mb, h2);

  gemm_bf16<128, 2><<<dim3(32, 16), 256, 0, stream>>>(h2, W1_t, 2048, 4096, 1024,
      b1, nullptr, nullptr, ffb, nullptr, nullptr, nullptr);

  gemm_bf16<64, 3><<<dim3(8, 32), 256, 0, stream>>>(ffb, W2_t, 2048, 1024, 4096,
      b2, x2, (float*)d_out, nullptr, nullptr, nullptr, nullptr);
}

// Round 3
// 217.185 us; speedup vs baseline: 1.4946x; 1.1342x over previous
//
#include <hip/hip_runtime.h>
#include <math.h>

typedef __bf16 bf16x8 __attribute__((ext_vector_type(8)));
typedef float f32x4 __attribute__((ext_vector_type(4)));
typedef unsigned short u16;
typedef unsigned short u16x8 __attribute__((ext_vector_type(8)));
typedef unsigned int u32;

__device__ __forceinline__ u16 f2bf(float f) {
  union { float f; u32 u; } v; v.f = f;
  u32 u = v.u;
  return (u16)((u + 0x7FFFu + ((u >> 16) & 1u)) >> 16);
}

__device__ __forceinline__ f32x4 mfma16(bf16x8 a, bf16x8 b, f32x4 c) {
  return __builtin_amdgcn_mfma_f32_16x16x32_bf16(a, b, c, 0, 0, 0);
}

__device__ __forceinline__ void gld16(const void* g, void* l) {
  __builtin_amdgcn_global_load_lds(
      (const __attribute__((address_space(1))) void*)(void*)g,
      (__attribute__((address_space(3))) void*)l,
      16, 0, 0);
}

// ---------------- weight fp32 -> bf16 transpose (Wt[n][k] = W[k][n]) ----------
__global__ __launch_bounds__(256)
void wconv_t(const float* __restrict__ W, u16* __restrict__ Wt, int K, int N) {
  __shared__ float tile[64][65];
  const int k0 = blockIdx.y * 64, n0 = blockIdx.x * 64;
  const int t = threadIdx.x;
  const int tr = t >> 4;
  const int tc = (t & 15) * 4;
#pragma unroll
  for (int it = 0; it < 4; it++) {
    const int r = tr + it * 16;
    const float4 v = *(const float4*)(W + (size_t)(k0 + r) * N + n0 + tc);
    tile[r][tc] = v.x; tile[r][tc + 1] = v.y; tile[r][tc + 2] = v.z; tile[r][tc + 3] = v.w;
  }
  __syncthreads();
#pragma unroll
  for (int it = 0; it < 4; it++) {
    const int rn = tr + it * 16;
    ushort4 o;
    o.x = f2bf(tile[tc][rn]);
    o.y = f2bf(tile[tc + 1][rn]);
    o.z = f2bf(tile[tc + 2][rn]);
    o.w = f2bf(tile[tc + 3][rn]);
    *(ushort4*)(Wt + (size_t)(n0 + rn) * K + k0 + tc) = o;
  }
}

// ---------------- LayerNorm (fp32 in -> bf16 out) ----------------------------
__global__ __launch_bounds__(256)
void ln_bf16(const float* __restrict__ x, const float* __restrict__ w,
             const float* __restrict__ b, u16* __restrict__ out) {
  const int row = blockIdx.x;
  const int t = threadIdx.x;
  const float4 v = *(const float4*)(x + (size_t)row * 1024 + t * 4);
  float s = v.x + v.y + v.z + v.w;
  float s2 = v.x * v.x + v.y * v.y + v.z * v.z + v.w * v.w;
#pragma unroll
  for (int m = 1; m < 64; m <<= 1) {
    s += __shfl_xor(s, m);
    s2 += __shfl_xor(s2, m);
  }
  __shared__ float red[8];
  if ((t & 63) == 0) { red[t >> 6] = s; red[4 + (t >> 6)] = s2; }
  __syncthreads();
  s = red[0] + red[1] + red[2] + red[3];
  s2 = red[4] + red[5] + red[6] + red[7];
  const float mu = s * (1.f / 1024.f);
  const float var = fmaxf(s2 * (1.f / 1024.f) - mu * mu, 0.f);
  const float rstd = rsqrtf(var + 1e-5f);
  const float* wp = w + t * 4;
  const float* bp = b + t * 4;
  ushort4 o;
  o.x = f2bf((v.x - mu) * rstd * wp[0] + bp[0]);
  o.y = f2bf((v.y - mu) * rstd * wp[1] + bp[1]);
  o.z = f2bf((v.z - mu) * rstd * wp[2] + bp[2]);
  o.w = f2bf((v.w - mu) * rstd * wp[3] + bp[3]);
  *(ushort4*)(out + (size_t)row * 1024 + t * 4) = o;
}

// ---------------- fused: x2 = x + p0 + p1 ; h2 = LN(x2) ----------------------
__global__ __launch_bounds__(256)
void reduce_ln(const float* __restrict__ x, const float* __restrict__ p0,
               const float* __restrict__ p1, const float* __restrict__ w,
               const float* __restrict__ b, float* __restrict__ x2,
               u16* __restrict__ h2) {
  const int row = blockIdx.x;
  const int t = threadIdx.x;
  const size_t base = (size_t)row * 1024 + t * 4;
  float4 v = *(const float4*)(x + base);
  const float4 a = *(const float4*)(p0 + base);
  const float4 c = *(const float4*)(p1 + base);
  v.x += a.x + c.x; v.y += a.y + c.y; v.z += a.z + c.z; v.w += a.w + c.w;
  *(float4*)(x2 + base) = v;
  float s = v.x + v.y + v.z + v.w;
  float s2 = v.x * v.x + v.y * v.y + v.z * v.z + v.w * v.w;
#pragma unroll
  for (int m = 1; m < 64; m <<= 1) {
    s += __shfl_xor(s, m);
    s2 += __shfl_xor(s2, m);
  }
  __shared__ float red[8];
  if ((t & 63) == 0) { red[t >> 6] = s; red[4 + (t >> 6)] = s2; }
  __syncthreads();
  s = red[0] + red[1] + red[2] + red[3];
  s2 = red[4] + red[5] + red[6] + red[7];
  const float mu = s * (1.f / 1024.f);
  const float var = fmaxf(s2 * (1.f / 1024.f) - mu * mu, 0.f);
  const float rstd = rsqrtf(var + 1e-5f);
  const float* wp = w + t * 4;
  const float* bp = b + t * 4;
  ushort4 o;
  o.x = f2bf((v.x - mu) * rstd * wp[0] + bp[0]);
  o.y = f2bf((v.y - mu) * rstd * wp[1] + bp[1]);
  o.z = f2bf((v.z - mu) * rstd * wp[2] + bp[2]);
  o.w = f2bf((v.w - mu) * rstd * wp[3] + bp[3]);
  *(ushort4*)(h2 + base) = o;
}

// ---------------- fused: out = x2 + bias + p0 + p1 ---------------------------
__global__ __launch_bounds__(256)
void reduce_out(const float* __restrict__ x2, const float* __restrict__ bias,
                const float* __restrict__ p0, const float* __restrict__ p1,
                float* __restrict__ out) {
  const size_t base = ((size_t)blockIdx.x * 256 + threadIdx.x) * 4;
  const int col = (int)(base & 1023);
  float4 v = *(const float4*)(x2 + base);
  const float4 a = *(const float4*)(p0 + base);
  const float4 c = *(const float4*)(p1 + base);
  const float4 bb = *(const float4*)(bias + col);
  v.x += a.x + c.x + bb.x;
  v.y += a.y + c.y + bb.y;
  v.z += a.z + c.z + bb.z;
  v.w += a.w + c.w + bb.w;
  *(float4*)(out + base) = v;
}

// ---------------- bf16 GEMM, BMxBN tile, BK=32, m97 structure, split-K -------
// A: [M][K] bf16 row-major; Bt: [N][K] bf16 (B transposed). fp32 accum.
// Wave decomp: 128x128 -> 2x2 of 64x64; 128x64 -> 2x2 of 64x32;
//              64x128 -> 1x4 of 64x32.
// EPI 0: QKV split (Q,K row-major bf16; V transposed bf16 [D][S])
// EPI 2: outB = bf16(gelu(C + bias))
// EPI 4: raw fp32 partial -> (z==0 ? po0 : po1)
template <int BM, int BN, int EPI, int KS>
__global__ __launch_bounds__(256)
void gemm_bf16(const u16* __restrict__ A, const u16* __restrict__ Bt,
               int M, int N, int K,
               const float* __restrict__ bias,
               float* __restrict__ po0, float* __restrict__ po1,
               u16* __restrict__ outB,
               u16* __restrict__ qo, u16* __restrict__ ko, u16* __restrict__ vo) {
  __shared__ __attribute__((aligned(16))) u16 lA[BM * 32];
  __shared__ __attribute__((aligned(16))) u16 lB[BN * 32];
  const int t = threadIdx.x;
  const int l = t & 63;
  const int w = t >> 6;
  constexpr int NJ = (BM == 128 && BN == 128) ? 4 : 2;
  const int WR = (BM == 128) ? (w >> 1) * 64 : 0;
  const int WC = (BM == 128) ? ((BN == 128) ? (w & 1) * 64 : (w & 1) * 32)
                             : w * 32;
  const int l15 = l & 15, lg = l >> 4;
  const int m0 = blockIdx.y * BM, n0 = blockIdx.x * BN;
  const int KC = K / KS;
  const int kbase = blockIdx.z * KC;

  f32x4 acc[4][NJ] = {};

  const int lr = t >> 2;
  const int lc = ((t & 3) << 3) + kbase;
  const u16* ag0 = A + (size_t)(m0 + lr) * K + lc;
  const u16* ag1 = A + (size_t)(m0 + 64 + lr) * K + lc;
  const u16* bg0 = Bt + (size_t)(n0 + lr) * K + lc;
  const u16* bg1 = Bt + (size_t)(n0 + 64 + lr) * K + lc;
  u16* la0 = &lA[t * 8];
  u16* la1 = &lA[2048 + t * 8];
  u16* lb0 = &lB[t * 8];
  u16* lb1 = &lB[2048 + t * 8];

  for (int k0 = 0; k0 < KC; k0 += 32) {
    gld16(ag0 + k0, la0);
    if (BM == 128) gld16(ag1 + k0, la1);
    gld16(bg0 + k0, lb0);
    if (BN == 128) gld16(bg1 + k0, lb1);
    __syncthreads();
    bf16x8 af[4], bfr[NJ];
#pragma unroll
    for (int i = 0; i < 4; i++)
      af[i] = *(const bf16x8*)&lA[(WR + i * 16 + l15) * 32 + lg * 8];
#pragma unroll
    for (int j = 0; j < NJ; j++)
      bfr[j] = *(const bf16x8*)&lB[(WC + j * 16 + l15) * 32 + lg * 8];
#pragma unroll
    for (int i = 0; i < 4; i++)
#pragma unroll
      for (int j = 0; j < NJ; j++)
        acc[i][j] = mfma16(af[i], bfr[j], acc[i][j]);
    __syncthreads();
  }

  float* po = (KS == 2 && blockIdx.z == 1) ? po1 : po0;
  const int mr0 = m0 + WR + lg * 4;
  const int nc0 = n0 + WC + l15;
#pragma unroll
  for (int i = 0; i < 4; i++) {
    const int mr = mr0 + i * 16;
#pragma unroll
    for (int j = 0; j < NJ; j++) {
      const int nc = nc0 + j * 16;
      if (EPI == 0) {
        const int sel = nc >> 10;
        const int cc = nc & 1023;
        if (sel == 2) {
          ushort4 o;
          o.x = f2bf(acc[i][j][0]); o.y = f2bf(acc[i][j][1]);
          o.z = f2bf(acc[i][j][2]); o.w = f2bf(acc[i][j][3]);
          *(ushort4*)(vo + (size_t)cc * 2048 + mr) = o;
        } else {
          u16* dst = (sel == 0) ? qo : ko;
#pragma unroll
          for (int e = 0; e < 4; e++)
            dst[(size_t)(mr + e) * 1024 + cc] = f2bf(acc[i][j][e]);
        }
      } else if (EPI == 2) {
        const float bb = bias[nc];
#pragma unroll
        for (int e = 0; e < 4; e++) {
          const float v = acc[i][j][e] + bb;
          const float g = 0.5f * v * (1.0f + tanhf(0.7978845608028654f * (v + 0.044715f * v * v * v)));
          outB[(size_t)(mr + e) * N + nc] = f2bf(g);
        }
      } else {
#pragma unroll
        for (int e = 0; e < 4; e++)
          po[(size_t)(mr + e) * N + nc] = acc[i][j][e];
      }
    }
  }
}

// ---------------- causal flash attention v2 ----------------------------------
// Qb,Kb: [S][1024] bf16; Vt: [1024][2048] bf16 (V^T). Ob: [S][1024] bf16.
// Block = 256 thr (4 waves), one head, 32 q-rows. Waves split K (stride-4
// k-tiles of 32); no-max softmax (scores bounded) makes partials associative;
// LDS combine at end. Swapped QK^T: mfma(K,Q) puts P lane-local per q-col.
__global__ __launch_bounds__(256)
void attn_fwd(const u16* __restrict__ Qb, const u16* __restrict__ Kb,
              const u16* __restrict__ Vt, u16* __restrict__ Ob) {
  __shared__ __attribute__((aligned(16))) char smem[33280];
  float* sO = (float*)smem;            // [4][2048] f32 (after barrier)
  float* sL = (float*)(smem + 32768);  // [4][32]
  u16* lP = (u16*)smem;                // [4 waves][2 g][16 rows][40] (pre-barrier)

  const int t = threadIdx.x;
  const int l = t & 63, w = t >> 6;
  const int l15 = l & 15, lg = l >> 4;
  const int h = blockIdx.y;
  const int qt = 63 - (int)blockIdx.x;  // LPT: heaviest tiles first
  const int qb = qt * 32;

  u16* myP = lP + w * 1280;

  bf16x8 qf[2][2];
#pragma unroll
  for (int g = 0; g < 2; g++)
#pragma unroll
    for (int kk = 0; kk < 2; kk++)
      qf[g][kk] = *(const bf16x8*)(Qb + (size_t)(qb + g * 16 + l15) * 1024 + h * 64 + kk * 32 + lg * 8);

  f32x4 accO[2][4] = {};
  float lsum[2] = {0.f, 0.f};

  for (int kt = w; kt <= qt; kt += 4) {
    const int k0 = kt * 32;
    bf16x8 kf[2][2], vf[4];
#pragma unroll
    for (int f = 0; f < 2; f++)
#pragma unroll
      for (int kk = 0; kk < 2; kk++)
        kf[kk][f] = *(const bf16x8*)(Kb + (size_t)(k0 + f * 16 + l15) * 1024 + h * 64 + kk * 32 + lg * 8);
#pragma unroll
    for (int nb = 0; nb < 4; nb++)
      vf[nb] = *(const bf16x8*)(Vt + (size_t)(h * 64 + nb * 16 + l15) * 2048 + k0 + lg * 8);

    f32x4 sv[2][2] = {};
#pragma unroll
    for (int g = 0; g < 2; g++)
#pragma unroll
      for (int f = 0; f < 2; f++)
#pragma unroll
        for (int kk = 0; kk < 2; kk++)
          sv[g][f] = mfma16(kf[kk][f], qf[g][kk], sv[g][f]);

    // sv[g][f][e] = score(q = qb+g*16+l15, k = k0+f*16+lg*4+e)
    const bool diag = (kt == qt);
#pragma unroll
    for (int g = 0; g < 2; g++) {
#pragma unroll
      for (int f = 0; f < 2; f++) {
        ushort4 pk;
        float ps = 0.f;
#pragma unroll
        for (int e = 0; e < 4; e++) {
          float p = __expf(sv[g][f][e] * 0.125f);
          if (diag && (k0 + f * 16 + lg * 4 + e > qb + g * 16 + l15)) p = 0.f;
          ps += p;
          ((u16*)&pk)[e] = f2bf(p);
        }
        lsum[g] += ps;
        *(ushort4*)(myP + g * 640 + l15 * 40 + f * 16 + lg * 4) = pk;
      }
    }
    // wave-private LDS: compiler orders write->read via lgkmcnt (no barrier)
    bf16x8 pf[2];
#pragma unroll
    for (int g = 0; g < 2; g++)
      pf[g] = *(const bf16x8*)(myP + g * 640 + l15 * 40 + lg * 8);
#pragma unroll
    for (int nb = 0; nb < 4; nb++) {
      accO[0][nb] = mfma16(pf[0], vf[nb], accO[0][nb]);
      accO[1][nb] = mfma16(pf[1], vf[nb], accO[1][nb]);
    }
  }

  float lsr[2];
#pragma unroll
  for (int g = 0; g < 2; g++) {
    float v = lsum[g];
    v += __shfl_xor(v, 16);
    v += __shfl_xor(v, 32);
    lsr[g] = v;
  }

  __syncthreads();  // all waves done with lP; smem becomes sO
#pragma unroll
  for (int g = 0; g < 2; g++) {
#pragma unroll
    for (int nb = 0; nb < 4; nb++)
#pragma unroll
      for (int e = 0; e < 4; e++)
        sO[w * 2048 + (g * 16 + lg * 4 + e) * 64 + nb * 16 + l15] = accO[g][nb][e];
    if (lg == 0) sL[w * 32 + g * 16 + l15] = lsr[g];
  }
  __syncthreads();

  const int base = t * 8;
  const int row = base >> 6;
  const int col = base & 63;
  f32x4 a0 = {}, a1 = {};
  float ls = 0.f;
#pragma unroll
  for (int ww = 0; ww < 4; ww++) {
    a0 += *(const f32x4*)&sO[ww * 2048 + base];
    a1 += *(const f32x4*)&sO[ww * 2048 + base + 4];
    ls += sL[ww * 32 + row];
  }
  const float rinv = 1.0f / ls;
  u16x8 o;
#pragma unroll
  for (int j = 0; j < 4; j++) {
    o[j] = f2bf(a0[j] * rinv);
    o[4 + j] = f2bf(a1[j] * rinv);
  }
  *(u16x8*)(Ob + (size_t)(qb + row) * 1024 + h * 64 + col) = o;
}

// ---------------- launch ----------------------------------------------------
extern "C" void kernel_launch(void* const* d_in, const int* in_sizes, int n_in,
                              void* d_out, int out_size, void* d_ws, size_t ws_size,
                              hipStream_t stream) {
  const float* x     = (const float*)d_in[0];
  const float* W_qkv = (const float*)d_in[1];
  const float* W_o   = (const float*)d_in[2];
  const float* W1    = (const float*)d_in[3];
  const float* b1    = (const float*)d_in[4];
  const float* W2    = (const float*)d_in[5];
  const float* b2    = (const float*)d_in[6];
  const float* ln_aw = (const float*)d_in[7];
  const float* ln_ab = (const float*)d_in[8];
  const float* ln_mw = (const float*)d_in[9];
  const float* ln_mb = (const float*)d_in[10];

  // workspace layout (lifetime-aliased; peak 67.5 MB):
  char* ws = (char*)d_ws;
  u16* Wqkv_t = (u16*)(ws);                  // [3072][1024] bf16   6 MB  persistent
  u16* Wo_t   = (u16*)(ws + 6291456);        // [1024][1024]        2 MB  persistent
  u16* W1_t   = (u16*)(ws + 8388608);        // [4096][1024]        8 MB  persistent
  u16* W2_t   = (u16*)(ws + 16777216);       // [1024][4096]        8 MB  persistent
  u16* h1     = (u16*)(ws + 25165824);       // [2048][1024]        4 MB  (h2 aliases)
  u16* h2     = h1;                          //                     dead-by-then alias
  u16* Qb     = (u16*)(ws + 29360128);       // [2048][1024]        4 MB
  u16* Kb     = (u16*)(ws + 33554432);       // [2048][1024]        4 MB
  u16* Vt     = (u16*)(ws + 37748736);       // [1024][2048]        4 MB
  u16* attnb  = (u16*)(ws + 41943040);       // [2048][1024]        4 MB
  u16* ffb    = (u16*)(ws + 29360128);       // [2048][4096]       16 MB  aliases Qb..attnb (dead)
  float* p0   = (float*)(ws + 46137344);     // [2048][1024] f32    8 MB  split-K partial
  float* p1   = (float*)(ws + 54525952);     // [2048][1024] f32    8 MB  split-K partial
  float* x2   = (float*)(ws + 62914560);     // [2048][1024] f32    8 MB
  (void)ws_size; (void)in_sizes; (void)n_in; (void)out_size;

  wconv_t<<<dim3(48, 16), 256, 0, stream>>>(W_qkv, Wqkv_t, 1024, 3072);
  wconv_t<<<dim3(16, 16), 256, 0, stream>>>(W_o, Wo_t, 1024, 1024);
  wconv_t<<<dim3(64, 16), 256, 0, stream>>>(W1, W1_t, 1024, 4096);
  wconv_t<<<dim3(16, 64), 256, 0, stream>>>(W2, W2_t, 4096, 1024);

  ln_bf16<<<2048, 256, 0, stream>>>(x, ln_aw, ln_ab, h1);

  // QKV: 128x64 tiles -> 768 blocks (3/CU)
  gemm_bf16<128, 64, 0, 1><<<dim3(48, 16), 256, 0, stream>>>(
      h1, Wqkv_t, 2048, 3072, 1024, nullptr, nullptr, nullptr, nullptr, Qb, Kb, Vt);

  attn_fwd<<<dim3(64, 16), 256, 0, stream>>>(Qb, Kb, Vt, attnb);

  // W_o: 64x128 tiles, split-K=2 -> 512 blocks (2/CU)
  gemm_bf16<64, 128, 4, 2><<<dim3(8, 32, 2), 256, 0, stream>>>(
      attnb, Wo_t, 2048, 1024, 1024, nullptr, p0, p1, nullptr, nullptr, nullptr, nullptr);

  reduce_ln<<<2048, 256, 0, stream>>>(x, p0, p1, ln_mw, ln_mb, x2, h2);

  // FF1: 128x64 tiles -> 1024 blocks (4/CU)
  gemm_bf16<128, 64, 2, 1><<<dim3(64, 16), 256, 0, stream>>>(
      h2, W1_t, 2048, 4096, 1024, b1, nullptr, nullptr, ffb, nullptr, nullptr, nullptr);

  // FF2: 64x128 tiles, split-K=2 -> 512 blocks (2/CU)
  gemm_bf16<64, 128, 4, 2><<<dim3(8, 32, 2), 256, 0, stream>>>(
      ffb, W2_t, 2048, 1024, 4096, nullptr, p0, p1, nullptr, nullptr, nullptr, nullptr);

  reduce_out<<<2048, 256, 0, stream>>>(x2, b2, p0, p1, (float*)d_out);
}

// Round 4
// 191.264 us; speedup vs baseline: 1.6972x; 1.1355x over previous
//
#include <hip/hip_runtime.h>
#include <math.h>

typedef __bf16 bf16;
typedef __bf16 bf16x4 __attribute__((ext_vector_type(4)));
typedef __bf16 bf16x8 __attribute__((ext_vector_type(8)));
typedef float f32x4 __attribute__((ext_vector_type(4)));
typedef unsigned short u16;
typedef unsigned short u16x8 __attribute__((ext_vector_type(8)));
typedef unsigned int u32;

__device__ __forceinline__ u16 f2bf(float f) {
  union { float f; u32 u; } v; v.f = f;
  u32 u = v.u;
  return (u16)((u + 0x7FFFu + ((u >> 16) & 1u)) >> 16);
}

__device__ __forceinline__ f32x4 mfma16(bf16x8 a, bf16x8 b, f32x4 c) {
  return __builtin_amdgcn_mfma_f32_16x16x32_bf16(a, b, c, 0, 0, 0);
}

__device__ __forceinline__ void gld16(const void* g, void* l) {
  __builtin_amdgcn_global_load_lds(
      (const __attribute__((address_space(1))) void*)(void*)g,
      (__attribute__((address_space(3))) void*)l,
      16, 0, 0);
}

// ---------------- weight fp32 -> bf16 transpose (Wt[n][k] = W[k][n]) ----------
__device__ __forceinline__ void wconv_body(const float* __restrict__ W,
                                           u16* __restrict__ Wt, int K, int N,
                                           int bx, int by) {
  __shared__ float tile[64][65];
  const int k0 = by * 64, n0 = bx * 64;
  const int t = threadIdx.x;
  const int tr = t >> 4;
  const int tc = (t & 15) * 4;
#pragma unroll
  for (int it = 0; it < 4; it++) {
    const int r = tr + it * 16;
    const float4 v = *(const float4*)(W + (size_t)(k0 + r) * N + n0 + tc);
    tile[r][tc] = v.x; tile[r][tc + 1] = v.y; tile[r][tc + 2] = v.z; tile[r][tc + 3] = v.w;
  }
  __syncthreads();
#pragma unroll
  for (int it = 0; it < 4; it++) {
    const int rn = tr + it * 16;
    ushort4 o;
    o.x = f2bf(tile[tc][rn]);
    o.y = f2bf(tile[tc + 1][rn]);
    o.z = f2bf(tile[tc + 2][rn]);
    o.w = f2bf(tile[tc + 3][rn]);
    *(ushort4*)(Wt + (size_t)(n0 + rn) * K + k0 + tc) = o;
  }
}

__global__ __launch_bounds__(256)
void wconv_all(const float* __restrict__ Wqkv, const float* __restrict__ Wo,
               const float* __restrict__ W1, const float* __restrict__ W2,
               u16* __restrict__ Wqkv_t, u16* __restrict__ Wo_t,
               u16* __restrict__ W1_t, u16* __restrict__ W2_t) {
  const int id = blockIdx.x;  // uniform per block
  if (id < 768)       { wconv_body(Wqkv, Wqkv_t, 1024, 3072, id % 48, id / 48); }
  else if (id < 1024) { const int j = id - 768;  wconv_body(Wo, Wo_t, 1024, 1024, j % 16, j / 16); }
  else if (id < 2048) { const int j = id - 1024; wconv_body(W1, W1_t, 1024, 4096, j % 64, j / 64); }
  else                { const int j = id - 2048; wconv_body(W2, W2_t, 4096, 1024, j % 16, j / 16); }
}

// ---------------- LayerNorm (fp32 in -> bf16 out) ----------------------------
__global__ __launch_bounds__(256)
void ln_bf16(const float* __restrict__ x, const float* __restrict__ w,
             const float* __restrict__ b, u16* __restrict__ out) {
  const int row = blockIdx.x;
  const int t = threadIdx.x;
  const float4 v = *(const float4*)(x + (size_t)row * 1024 + t * 4);
  float s = v.x + v.y + v.z + v.w;
  float s2 = v.x * v.x + v.y * v.y + v.z * v.z + v.w * v.w;
#pragma unroll
  for (int m = 1; m < 64; m <<= 1) {
    s += __shfl_xor(s, m);
    s2 += __shfl_xor(s2, m);
  }
  __shared__ float red[8];
  if ((t & 63) == 0) { red[t >> 6] = s; red[4 + (t >> 6)] = s2; }
  __syncthreads();
  s = red[0] + red[1] + red[2] + red[3];
  s2 = red[4] + red[5] + red[6] + red[7];
  const float mu = s * (1.f / 1024.f);
  const float var = fmaxf(s2 * (1.f / 1024.f) - mu * mu, 0.f);
  const float rstd = rsqrtf(var + 1e-5f);
  const float* wp = w + t * 4;
  const float* bp = b + t * 4;
  ushort4 o;
  o.x = f2bf((v.x - mu) * rstd * wp[0] + bp[0]);
  o.y = f2bf((v.y - mu) * rstd * wp[1] + bp[1]);
  o.z = f2bf((v.z - mu) * rstd * wp[2] + bp[2]);
  o.w = f2bf((v.w - mu) * rstd * wp[3] + bp[3]);
  *(ushort4*)(out + (size_t)row * 1024 + t * 4) = o;
}

// ---------------- fused: x2 = x + p0 + p1 ; h2 = LN(x2) ----------------------
__global__ __launch_bounds__(256)
void reduce_ln(const float* __restrict__ x, const float* __restrict__ p0,
               const float* __restrict__ p1, const float* __restrict__ w,
               const float* __restrict__ b, float* __restrict__ x2,
               u16* __restrict__ h2) {
  const int row = blockIdx.x;
  const int t = threadIdx.x;
  const size_t base = (size_t)row * 1024 + t * 4;
  float4 v = *(const float4*)(x + base);
  const float4 a = *(const float4*)(p0 + base);
  const float4 c = *(const float4*)(p1 + base);
  v.x += a.x + c.x; v.y += a.y + c.y; v.z += a.z + c.z; v.w += a.w + c.w;
  *(float4*)(x2 + base) = v;
  float s = v.x + v.y + v.z + v.w;
  float s2 = v.x * v.x + v.y * v.y + v.z * v.z + v.w * v.w;
#pragma unroll
  for (int m = 1; m < 64; m <<= 1) {
    s += __shfl_xor(s, m);
    s2 += __shfl_xor(s2, m);
  }
  __shared__ float red[8];
  if ((t & 63) == 0) { red[t >> 6] = s; red[4 + (t >> 6)] = s2; }
  __syncthreads();
  s = red[0] + red[1] + red[2] + red[3];
  s2 = red[4] + red[5] + red[6] + red[7];
  const float mu = s * (1.f / 1024.f);
  const float var = fmaxf(s2 * (1.f / 1024.f) - mu * mu, 0.f);
  const float rstd = rsqrtf(var + 1e-5f);
  const float* wp = w + t * 4;
  const float* bp = b + t * 4;
  ushort4 o;
  o.x = f2bf((v.x - mu) * rstd * wp[0] + bp[0]);
  o.y = f2bf((v.y - mu) * rstd * wp[1] + bp[1]);
  o.z = f2bf((v.z - mu) * rstd * wp[2] + bp[2]);
  o.w = f2bf((v.w - mu) * rstd * wp[3] + bp[3]);
  *(ushort4*)(h2 + base) = o;
}

// ---------------- fused: out = x2 + bias + p0 + p1 ---------------------------
__global__ __launch_bounds__(256)
void reduce_out(const float* __restrict__ x2, const float* __restrict__ bias,
                const float* __restrict__ p0, const float* __restrict__ p1,
                float* __restrict__ out) {
  const size_t base = ((size_t)blockIdx.x * 256 + threadIdx.x) * 4;
  const int col = (int)(base & 1023);
  float4 v = *(const float4*)(x2 + base);
  const float4 a = *(const float4*)(p0 + base);
  const float4 c = *(const float4*)(p1 + base);
  const float4 bb = *(const float4*)(bias + col);
  v.x += a.x + c.x + bb.x;
  v.y += a.y + c.y + bb.y;
  v.z += a.z + c.z + bb.z;
  v.w += a.w + c.w + bb.w;
  *(float4*)(out + base) = v;
}

// ---------------- bf16 GEMM, BMxBN tile, BK=32, m97 structure, split-K -------
template <int BM, int BN, int EPI, int KS>
__global__ __launch_bounds__(256)
void gemm_bf16(const u16* __restrict__ A, const u16* __restrict__ Bt,
               int M, int N, int K,
               const float* __restrict__ bias,
               float* __restrict__ po0, float* __restrict__ po1,
               u16* __restrict__ outB,
               u16* __restrict__ qo, u16* __restrict__ ko, u16* __restrict__ vo) {
  __shared__ __attribute__((aligned(16))) u16 lA[BM * 32];
  __shared__ __attribute__((aligned(16))) u16 lB[BN * 32];
  const int t = threadIdx.x;
  const int l = t & 63;
  const int w = t >> 6;
  constexpr int NJ = (BM == 128 && BN == 128) ? 4 : 2;
  const int WR = (BM == 128) ? (w >> 1) * 64 : 0;
  const int WC = (BM == 128) ? ((BN == 128) ? (w & 1) * 64 : (w & 1) * 32)
                             : w * 32;
  const int l15 = l & 15, lg = l >> 4;
  const int m0 = blockIdx.y * BM, n0 = blockIdx.x * BN;
  const int KC = K / KS;
  const int kbase = blockIdx.z * KC;

  f32x4 acc[4][NJ] = {};

  const int lr = t >> 2;
  const int lc = ((t & 3) << 3) + kbase;
  const u16* ag0 = A + (size_t)(m0 + lr) * K + lc;
  const u16* ag1 = A + (size_t)(m0 + 64 + lr) * K + lc;
  const u16* bg0 = Bt + (size_t)(n0 + lr) * K + lc;
  const u16* bg1 = Bt + (size_t)(n0 + 64 + lr) * K + lc;
  u16* la0 = &lA[t * 8];
  u16* la1 = &lA[2048 + t * 8];
  u16* lb0 = &lB[t * 8];
  u16* lb1 = &lB[2048 + t * 8];

  for (int k0 = 0; k0 < KC; k0 += 32) {
    gld16(ag0 + k0, la0);
    if (BM == 128) gld16(ag1 + k0, la1);
    gld16(bg0 + k0, lb0);
    if (BN == 128) gld16(bg1 + k0, lb1);
    __syncthreads();
    bf16x8 af[4], bfr[NJ];
#pragma unroll
    for (int i = 0; i < 4; i++)
      af[i] = *(const bf16x8*)&lA[(WR + i * 16 + l15) * 32 + lg * 8];
#pragma unroll
    for (int j = 0; j < NJ; j++)
      bfr[j] = *(const bf16x8*)&lB[(WC + j * 16 + l15) * 32 + lg * 8];
#pragma unroll
    for (int i = 0; i < 4; i++)
#pragma unroll
      for (int j = 0; j < NJ; j++)
        acc[i][j] = mfma16(af[i], bfr[j], acc[i][j]);
    __syncthreads();
  }

  float* po = (KS == 2 && blockIdx.z == 1) ? po1 : po0;
  const int mr0 = m0 + WR + lg * 4;
  const int nc0 = n0 + WC + l15;
#pragma unroll
  for (int i = 0; i < 4; i++) {
    const int mr = mr0 + i * 16;
#pragma unroll
    for (int j = 0; j < NJ; j++) {
      const int nc = nc0 + j * 16;
      if (EPI == 0) {
        const int sel = nc >> 10;
        const int cc = nc & 1023;
        if (sel == 2) {
          ushort4 o;
          o.x = f2bf(acc[i][j][0]); o.y = f2bf(acc[i][j][1]);
          o.z = f2bf(acc[i][j][2]); o.w = f2bf(acc[i][j][3]);
          *(ushort4*)(vo + (size_t)cc * 2048 + mr) = o;
        } else {
          u16* dst = (sel == 0) ? qo : ko;
#pragma unroll
          for (int e = 0; e < 4; e++)
            dst[(size_t)(mr + e) * 1024 + cc] = f2bf(acc[i][j][e]);
        }
      } else if (EPI == 2) {
        const float bb = bias[nc];
#pragma unroll
        for (int e = 0; e < 4; e++) {
          const float v = acc[i][j][e] + bb;
          const float g = 0.5f * v * (1.0f + tanhf(0.7978845608028654f * (v + 0.044715f * v * v * v)));
          outB[(size_t)(mr + e) * N + nc] = f2bf(g);
        }
      } else {
#pragma unroll
        for (int e = 0; e < 4; e++)
          po[(size_t)(mr + e) * N + nc] = acc[i][j][e];
      }
    }
  }
}

// ---------------- causal flash attention v3 ----------------------------------
// Register-double-buffered K/V prefetch; exp2-folded no-max softmax; XCD-chunked
// block swizzle (2 heads per XCD -> K/V L2-resident). 4 waves split K stride-4.
__device__ __forceinline__ void attn_load(
    bf16x8 (&kf)[2][2], bf16x8 (&vf)[4],
    const u16* __restrict__ Kb, const u16* __restrict__ Vt,
    int h, int k0, int l15, int lg) {
#pragma unroll
  for (int f = 0; f < 2; f++)
#pragma unroll
    for (int kk = 0; kk < 2; kk++)
      kf[kk][f] = *(const bf16x8*)(Kb + (size_t)(k0 + f * 16 + l15) * 1024 + h * 64 + kk * 32 + lg * 8);
#pragma unroll
  for (int nb = 0; nb < 4; nb++)
    vf[nb] = *(const bf16x8*)(Vt + (size_t)(h * 64 + nb * 16 + l15) * 2048 + k0 + lg * 8);
}

__device__ __forceinline__ void attn_tile(
    const bf16x8 (&kf)[2][2], const bf16x8 (&vf)[4], const bf16x8 (&qf)[2][2],
    f32x4 (&accO)[2][4], float (&lsum)[2], u16* myP,
    int k0, bool diag, int qb, int l15, int lg) {
  f32x4 sv[2][2] = {};
#pragma unroll
  for (int g = 0; g < 2; g++)
#pragma unroll
    for (int f = 0; f < 2; f++)
#pragma unroll
      for (int kk = 0; kk < 2; kk++)
        sv[g][f] = mfma16(kf[kk][f], qf[g][kk], sv[g][f]);
  // sv[g][f][e] = score(q = qb+g*16+l15, k = k0+f*16+lg*4+e)
#pragma unroll
  for (int g = 0; g < 2; g++) {
#pragma unroll
    for (int f = 0; f < 2; f++) {
      bf16x4 pk;
      float ps = 0.f;
#pragma unroll
      for (int e = 0; e < 4; e++) {
        float p = exp2f(sv[g][f][e] * 0.1803368801f);  // exp(s/8)
        if (diag && (k0 + f * 16 + lg * 4 + e > qb + g * 16 + l15)) p = 0.f;
        ps += p;
        pk[e] = (bf16)p;
      }
      lsum[g] += ps;
      *(bf16x4*)(myP + g * 640 + l15 * 40 + f * 16 + lg * 4) = pk;
    }
  }
  const bf16x8 pf0 = *(const bf16x8*)(myP + l15 * 40 + lg * 8);
  const bf16x8 pf1 = *(const bf16x8*)(myP + 640 + l15 * 40 + lg * 8);
#pragma unroll
  for (int nb = 0; nb < 4; nb++) {
    accO[0][nb] = mfma16(pf0, vf[nb], accO[0][nb]);
    accO[1][nb] = mfma16(pf1, vf[nb], accO[1][nb]);
  }
}

__global__ __launch_bounds__(256)
void attn_fwd(const u16* __restrict__ Qb, const u16* __restrict__ Kb,
              const u16* __restrict__ Vt, u16* __restrict__ Ob) {
  __shared__ __attribute__((aligned(16))) char smem[33280];
  float* sO = (float*)smem;            // [4][2048] f32 (after barrier)
  float* sL = (float*)(smem + 32768);  // [4][32]
  u16* lP = (u16*)smem;                // [2 buf][4 waves][1280 u16] (pre-barrier)

  const int t = threadIdx.x;
  const int l = t & 63, w = t >> 6;
  const int l15 = l & 15, lg = l >> 4;
  // XCD-chunked swizzle: xcd = bid%8 gets contiguous 128 vb -> 2 heads/XCD
  const u32 bid = blockIdx.x;
  const u32 vb = (bid & 7) * 128 + (bid >> 3);
  const int h = (int)(vb >> 6);
  const int qt = 63 - (int)(vb & 63);  // LPT within chunk
  const int qb = qt * 32;

  u16* myPA = lP + w * 1280;
  u16* myPB = lP + 5120 + w * 1280;

  bf16x8 qf[2][2];
#pragma unroll
  for (int g = 0; g < 2; g++)
#pragma unroll
    for (int kk = 0; kk < 2; kk++)
      qf[g][kk] = *(const bf16x8*)(Qb + (size_t)(qb + g * 16 + l15) * 1024 + h * 64 + kk * 32 + lg * 8);

  f32x4 accO[2][4] = {};
  float lsum[2] = {0.f, 0.f};

  if (w <= qt) {
    bf16x8 kfA[2][2], vfA[4], kfB[2][2], vfB[4];
    attn_load(kfA, vfA, Kb, Vt, h, w * 32, l15, lg);
    int kt = w;
    while (true) {
      const int ktB = kt + 4;
      const bool hasB = (ktB <= qt);
      attn_load(kfB, vfB, Kb, Vt, h, (hasB ? ktB : kt) * 32, l15, lg);
      attn_tile(kfA, vfA, qf, accO, lsum, myPA, kt * 32, kt == qt, qb, l15, lg);
      if (!hasB) break;
      const int ktA = kt + 8;
      const bool hasA = (ktA <= qt);
      attn_load(kfA, vfA, Kb, Vt, h, (hasA ? ktA : ktB) * 32, l15, lg);
      attn_tile(kfB, vfB, qf, accO, lsum, myPB, ktB * 32, ktB == qt, qb, l15, lg);
      if (!hasA) break;
      kt = ktA;
    }
  }

  float lsr[2];
#pragma unroll
  for (int g = 0; g < 2; g++) {
    float v = lsum[g];
    v += __shfl_xor(v, 16);
    v += __shfl_xor(v, 32);
    lsr[g] = v;
  }

  __syncthreads();  // all waves done with lP; smem becomes sO
#pragma unroll
  for (int g = 0; g < 2; g++) {
#pragma unroll
    for (int nb = 0; nb < 4; nb++)
#pragma unroll
      for (int e = 0; e < 4; e++)
        sO[w * 2048 + (g * 16 + lg * 4 + e) * 64 + nb * 16 + l15] = accO[g][nb][e];
    if (lg == 0) sL[w * 32 + g * 16 + l15] = lsr[g];
  }
  __syncthreads();

  const int base = t * 8;
  const int row = base >> 6;
  const int col = base & 63;
  f32x4 a0 = {}, a1 = {};
  float ls = 0.f;
#pragma unroll
  for (int ww = 0; ww < 4; ww++) {
    a0 += *(const f32x4*)&sO[ww * 2048 + base];
    a1 += *(const f32x4*)&sO[ww * 2048 + base + 4];
    ls += sL[ww * 32 + row];
  }
  const float rinv = 1.0f / ls;
  u16x8 o;
#pragma unroll
  for (int j = 0; j < 4; j++) {
    o[j] = f2bf(a0[j] * rinv);
    o[4 + j] = f2bf(a1[j] * rinv);
  }
  *(u16x8*)(Ob + (size_t)(qb + row) * 1024 + h * 64 + col) = o;
}

// ---------------- launch ----------------------------------------------------
extern "C" void kernel_launch(void* const* d_in, const int* in_sizes, int n_in,
                              void* d_out, int out_size, void* d_ws, size_t ws_size,
                              hipStream_t stream) {
  const float* x     = (const float*)d_in[0];
  const float* W_qkv = (const float*)d_in[1];
  const float* W_o   = (const float*)d_in[2];
  const float* W1    = (const float*)d_in[3];
  const float* b1    = (const float*)d_in[4];
  const float* W2    = (const float*)d_in[5];
  const float* b2    = (const float*)d_in[6];
  const float* ln_aw = (const float*)d_in[7];
  const float* ln_ab = (const float*)d_in[8];
  const float* ln_mw = (const float*)d_in[9];
  const float* ln_mb = (const float*)d_in[10];

  // workspace layout (lifetime-aliased; peak 67.5 MB):
  char* ws = (char*)d_ws;
  u16* Wqkv_t = (u16*)(ws);                  // [3072][1024] bf16   6 MB  persistent
  u16* Wo_t   = (u16*)(ws + 6291456);        // [1024][1024]        2 MB  persistent
  u16* W1_t   = (u16*)(ws + 8388608);        // [4096][1024]        8 MB  persistent
  u16* W2_t   = (u16*)(ws + 16777216);       // [1024][4096]        8 MB  persistent
  u16* h1     = (u16*)(ws + 25165824);       // [2048][1024]        4 MB  (h2 aliases)
  u16* h2     = h1;                          //                     dead-by-then alias
  u16* Qb     = (u16*)(ws + 29360128);       // [2048][1024]        4 MB
  u16* Kb     = (u16*)(ws + 33554432);       // [2048][1024]        4 MB
  u16* Vt     = (u16*)(ws + 37748736);       // [1024][2048]        4 MB
  u16* attnb  = (u16*)(ws + 41943040);       // [2048][1024]        4 MB
  u16* ffb    = (u16*)(ws + 29360128);       // [2048][4096]       16 MB  aliases Qb..attnb (dead)
  float* p0   = (float*)(ws + 46137344);     // [2048][1024] f32    8 MB  split-K partial
  float* p1   = (float*)(ws + 54525952);     // [2048][1024] f32    8 MB  split-K partial
  float* x2   = (float*)(ws + 62914560);     // [2048][1024] f32    8 MB
  (void)ws_size; (void)in_sizes; (void)n_in; (void)out_size;

  wconv_all<<<3072, 256, 0, stream>>>(W_qkv, W_o, W1, W2, Wqkv_t, Wo_t, W1_t, W2_t);

  ln_bf16<<<2048, 256, 0, stream>>>(x, ln_aw, ln_ab, h1);

  // QKV: 128x64 tiles -> 768 blocks (3/CU)
  gemm_bf16<128, 64, 0, 1><<<dim3(48, 16), 256, 0, stream>>>(
      h1, Wqkv_t, 2048, 3072, 1024, nullptr, nullptr, nullptr, nullptr, Qb, Kb, Vt);

  attn_fwd<<<1024, 256, 0, stream>>>(Qb, Kb, Vt, attnb);

  // W_o: 64x128 tiles, split-K=2 -> 512 blocks (2/CU)
  gemm_bf16<64, 128, 4, 2><<<dim3(8, 32, 2), 256, 0, stream>>>(
      attnb, Wo_t, 2048, 1024, 1024, nullptr, p0, p1, nullptr, nullptr, nullptr, nullptr);

  reduce_ln<<<2048, 256, 0, stream>>>(x, p0, p1, ln_mw, ln_mb, x2, h2);

  // FF1: 128x64 tiles -> 1024 blocks (4/CU)
  gemm_bf16<128, 64, 2, 1><<<dim3(64, 16), 256, 0, stream>>>(
      h2, W1_t, 2048, 4096, 1024, b1, nullptr, nullptr, ffb, nullptr, nullptr, nullptr);

  // FF2: 64x128 tiles, split-K=2 -> 512 blocks (2/CU)
  gemm_bf16<64, 128, 4, 2><<<dim3(8, 32, 2), 256, 0, stream>>>(
      ffb, W2_t, 2048, 1024, 4096, nullptr, p0, p1, nullptr, nullptr, nullptr, nullptr);

  reduce_out<<<2048, 256, 0, stream>>>(x2, b2, p0, p1, (float*)d_out);
}

// Round 5
// 187.025 us; speedup vs baseline: 1.7357x; 1.0227x over previous
//
#include <hip/hip_runtime.h>
#include <math.h>

typedef __bf16 bf16;
typedef __bf16 bf16x4 __attribute__((ext_vector_type(4)));
typedef __bf16 bf16x8 __attribute__((ext_vector_type(8)));
typedef float f32x4 __attribute__((ext_vector_type(4)));
typedef unsigned short u16;
typedef unsigned short u16x8 __attribute__((ext_vector_type(8)));
typedef unsigned int u32;

__device__ __forceinline__ u16 f2bf(float f) {
  union { float f; u32 u; } v; v.f = f;
  u32 u = v.u;
  return (u16)((u + 0x7FFFu + ((u >> 16) & 1u)) >> 16);
}

__device__ __forceinline__ f32x4 mfma16(bf16x8 a, bf16x8 b, f32x4 c) {
  return __builtin_amdgcn_mfma_f32_16x16x32_bf16(a, b, c, 0, 0, 0);
}

__device__ __forceinline__ void gld16(const void* g, void* l) {
  __builtin_amdgcn_global_load_lds(
      (const __attribute__((address_space(1))) void*)(void*)g,
      (__attribute__((address_space(3))) void*)l,
      16, 0, 0);
}

// ---------------- weight fp32 -> bf16 transpose (Wt[n][k] = W[k][n]) ----------
__device__ __forceinline__ void wconv_body(const float* __restrict__ W,
                                           u16* __restrict__ Wt, int K, int N,
                                           int bx, int by) {
  __shared__ float tile[64][65];
  const int k0 = by * 64, n0 = bx * 64;
  const int t = threadIdx.x;
  const int tr = t >> 4;
  const int tc = (t & 15) * 4;
#pragma unroll
  for (int it = 0; it < 4; it++) {
    const int r = tr + it * 16;
    const float4 v = *(const float4*)(W + (size_t)(k0 + r) * N + n0 + tc);
    tile[r][tc] = v.x; tile[r][tc + 1] = v.y; tile[r][tc + 2] = v.z; tile[r][tc + 3] = v.w;
  }
  __syncthreads();
#pragma unroll
  for (int it = 0; it < 4; it++) {
    const int rn = tr + it * 16;
    ushort4 o;
    o.x = f2bf(tile[tc][rn]);
    o.y = f2bf(tile[tc + 1][rn]);
    o.z = f2bf(tile[tc + 2][rn]);
    o.w = f2bf(tile[tc + 3][rn]);
    *(ushort4*)(Wt + (size_t)(n0 + rn) * K + k0 + tc) = o;
  }
}

__global__ __launch_bounds__(256)
void wconv_all(const float* __restrict__ Wqkv, const float* __restrict__ Wo,
               const float* __restrict__ W1, const float* __restrict__ W2,
               u16* __restrict__ Wqkv_t, u16* __restrict__ Wo_t,
               u16* __restrict__ W1_t, u16* __restrict__ W2_t) {
  const int id = blockIdx.x;  // uniform per block
  if (id < 768)       { wconv_body(Wqkv, Wqkv_t, 1024, 3072, id % 48, id / 48); }
  else if (id < 1024) { const int j = id - 768;  wconv_body(Wo, Wo_t, 1024, 1024, j % 16, j / 16); }
  else if (id < 2048) { const int j = id - 1024; wconv_body(W1, W1_t, 1024, 4096, j % 64, j / 64); }
  else                { const int j = id - 2048; wconv_body(W2, W2_t, 4096, 1024, j % 16, j / 16); }
}

// ---------------- LayerNorm (fp32 in -> bf16 out) ----------------------------
__global__ __launch_bounds__(256)
void ln_bf16(const float* __restrict__ x, const float* __restrict__ w,
             const float* __restrict__ b, u16* __restrict__ out) {
  const int row = blockIdx.x;
  const int t = threadIdx.x;
  const float4 v = *(const float4*)(x + (size_t)row * 1024 + t * 4);
  float s = v.x + v.y + v.z + v.w;
  float s2 = v.x * v.x + v.y * v.y + v.z * v.z + v.w * v.w;
#pragma unroll
  for (int m = 1; m < 64; m <<= 1) {
    s += __shfl_xor(s, m);
    s2 += __shfl_xor(s2, m);
  }
  __shared__ float red[8];
  if ((t & 63) == 0) { red[t >> 6] = s; red[4 + (t >> 6)] = s2; }
  __syncthreads();
  s = red[0] + red[1] + red[2] + red[3];
  s2 = red[4] + red[5] + red[6] + red[7];
  const float mu = s * (1.f / 1024.f);
  const float var = fmaxf(s2 * (1.f / 1024.f) - mu * mu, 0.f);
  const float rstd = rsqrtf(var + 1e-5f);
  const float* wp = w + t * 4;
  const float* bp = b + t * 4;
  ushort4 o;
  o.x = f2bf((v.x - mu) * rstd * wp[0] + bp[0]);
  o.y = f2bf((v.y - mu) * rstd * wp[1] + bp[1]);
  o.z = f2bf((v.z - mu) * rstd * wp[2] + bp[2]);
  o.w = f2bf((v.w - mu) * rstd * wp[3] + bp[3]);
  *(ushort4*)(out + (size_t)row * 1024 + t * 4) = o;
}

// ---------------- fused: x2 = x + p0 + p1 ; h2 = LN(x2) ----------------------
__global__ __launch_bounds__(256)
void reduce_ln(const float* __restrict__ x, const float* __restrict__ p0,
               const float* __restrict__ p1, const float* __restrict__ w,
               const float* __restrict__ b, float* __restrict__ x2,
               u16* __restrict__ h2) {
  const int row = blockIdx.x;
  const int t = threadIdx.x;
  const size_t base = (size_t)row * 1024 + t * 4;
  float4 v = *(const float4*)(x + base);
  const float4 a = *(const float4*)(p0 + base);
  const float4 c = *(const float4*)(p1 + base);
  v.x += a.x + c.x; v.y += a.y + c.y; v.z += a.z + c.z; v.w += a.w + c.w;
  *(float4*)(x2 + base) = v;
  float s = v.x + v.y + v.z + v.w;
  float s2 = v.x * v.x + v.y * v.y + v.z * v.z + v.w * v.w;
#pragma unroll
  for (int m = 1; m < 64; m <<= 1) {
    s += __shfl_xor(s, m);
    s2 += __shfl_xor(s2, m);
  }
  __shared__ float red[8];
  if ((t & 63) == 0) { red[t >> 6] = s; red[4 + (t >> 6)] = s2; }
  __syncthreads();
  s = red[0] + red[1] + red[2] + red[3];
  s2 = red[4] + red[5] + red[6] + red[7];
  const float mu = s * (1.f / 1024.f);
  const float var = fmaxf(s2 * (1.f / 1024.f) - mu * mu, 0.f);
  const float rstd = rsqrtf(var + 1e-5f);
  const float* wp = w + t * 4;
  const float* bp = b + t * 4;
  ushort4 o;
  o.x = f2bf((v.x - mu) * rstd * wp[0] + bp[0]);
  o.y = f2bf((v.y - mu) * rstd * wp[1] + bp[1]);
  o.z = f2bf((v.z - mu) * rstd * wp[2] + bp[2]);
  o.w = f2bf((v.w - mu) * rstd * wp[3] + bp[3]);
  *(ushort4*)(h2 + base) = o;
}

// ---------------- fused: out = x2 + bias + p0 + p1 ---------------------------
__global__ __launch_bounds__(256)
void reduce_out(const float* __restrict__ x2, const float* __restrict__ bias,
                const float* __restrict__ p0, const float* __restrict__ p1,
                float* __restrict__ out) {
  const size_t base = ((size_t)blockIdx.x * 256 + threadIdx.x) * 4;
  const int col = (int)(base & 1023);
  float4 v = *(const float4*)(x2 + base);
  const float4 a = *(const float4*)(p0 + base);
  const float4 c = *(const float4*)(p1 + base);
  const float4 bb = *(const float4*)(bias + col);
  v.x += a.x + c.x + bb.x;
  v.y += a.y + c.y + bb.y;
  v.z += a.z + c.z + bb.z;
  v.w += a.w + c.w + bb.w;
  *(float4*)(out + base) = v;
}

// ---------------- bf16 GEMM, BMxBN tile, BK=32, dbuf-prefetch, split-K -------
// A: [M][K] bf16 row-major; Bt: [N][K] bf16 (B transposed). fp32 accum.
// T3-minimum pipeline: STAGE(t+1) issued BEFORE compute(t); ONE barrier/iter
// (the compiler's vmcnt(0)-at-barrier then waits on the prefetch, which has
// had the whole compute phase to land). XCD-chunked bx swizzle: each XCD
// owns nx/8 B-columns (L2-resident) and walks A-rows within its chunk.
template <int BM, int BN, int EPI, int KS>
__global__ __launch_bounds__(256)
void gemm_bf16(const u16* __restrict__ A, const u16* __restrict__ Bt,
               int M, int N, int K,
               const float* __restrict__ bias,
               float* __restrict__ po0, float* __restrict__ po1,
               u16* __restrict__ outB,
               u16* __restrict__ qo, u16* __restrict__ ko, u16* __restrict__ vo) {
  constexpr int ASZ = BM * 32;
  constexpr int BSZ = BN * 32;
  __shared__ __attribute__((aligned(16))) u16 lA[2 * ASZ];
  __shared__ __attribute__((aligned(16))) u16 lB[2 * BSZ];
  const int t = threadIdx.x;
  const int l = t & 63;
  const int w = t >> 6;
  constexpr int NJ = (BM == 128 && BN == 128) ? 4 : 2;
  const int WR = (BM == 128) ? (w >> 1) * 64 : 0;
  const int WC = (BM == 128) ? ((BN == 128) ? (w & 1) * 64 : (w & 1) * 32)
                             : w * 32;
  const int l15 = l & 15, lg = l >> 4;

  // XCD-chunked swizzle (requires gridDim.x % 8 == 0; true at all call sites)
  const int nx = gridDim.x;
  const u32 bid = blockIdx.y * nx + blockIdx.x;
  const int nxc = nx >> 3;
  const u32 r = bid >> 3;
  const int bx = (bid & 7) * nxc + (int)(r % (u32)nxc);
  const int by = (int)(r / (u32)nxc);

  const int m0 = by * BM, n0 = bx * BN;
  const int KC = K / KS;
  const int kbase = blockIdx.z * KC;

  f32x4 acc[4][NJ] = {};

  const int lr = t >> 2;
  const int lc = ((t & 3) << 3) + kbase;
  const u16* ag0 = A + (size_t)(m0 + lr) * K + lc;
  const u16* ag1 = A + (size_t)(m0 + 64 + lr) * K + lc;
  const u16* bg0 = Bt + (size_t)(n0 + lr) * K + lc;
  const u16* bg1 = Bt + (size_t)(n0 + 64 + lr) * K + lc;

  const int nt = KC / 32;
  auto stage = [&](int buf, int kt) {
    const int k0 = kt * 32;
    gld16(ag0 + k0, &lA[buf * ASZ + t * 8]);
    if (BM == 128) gld16(ag1 + k0, &lA[buf * ASZ + 2048 + t * 8]);
    gld16(bg0 + k0, &lB[buf * BSZ + t * 8]);
    if (BN == 128) gld16(bg1 + k0, &lB[buf * BSZ + 2048 + t * 8]);
  };

  stage(0, 0);
  __syncthreads();  // vmcnt(0) drain of prologue stage

  for (int kt = 0; kt < nt; kt++) {
    const int cur = kt & 1;
    if (kt + 1 < nt) stage(cur ^ 1, kt + 1);  // prefetch overlaps compute
    bf16x8 af[4], bfr[NJ];
#pragma unroll
    for (int i = 0; i < 4; i++)
      af[i] = *(const bf16x8*)&lA[cur * ASZ + (WR + i * 16 + l15) * 32 + lg * 8];
#pragma unroll
    for (int j = 0; j < NJ; j++)
      bfr[j] = *(const bf16x8*)&lB[cur * BSZ + (WC + j * 16 + l15) * 32 + lg * 8];
#pragma unroll
    for (int i = 0; i < 4; i++)
#pragma unroll
      for (int j = 0; j < NJ; j++)
        acc[i][j] = mfma16(af[i], bfr[j], acc[i][j]);
    __syncthreads();  // single barrier/iter: drains prefetch, syncs buffers
  }

  float* po = (KS == 2 && blockIdx.z == 1) ? po1 : po0;
  const int mr0 = m0 + WR + lg * 4;
  const int nc0 = n0 + WC + l15;
#pragma unroll
  for (int i = 0; i < 4; i++) {
    const int mr = mr0 + i * 16;
#pragma unroll
    for (int j = 0; j < NJ; j++) {
      const int nc = nc0 + j * 16;
      if (EPI == 0) {
        const int sel = nc >> 10;
        const int cc = nc & 1023;
        if (sel == 2) {
          ushort4 o;
          o.x = f2bf(acc[i][j][0]); o.y = f2bf(acc[i][j][1]);
          o.z = f2bf(acc[i][j][2]); o.w = f2bf(acc[i][j][3]);
          *(ushort4*)(vo + (size_t)cc * 2048 + mr) = o;
        } else {
          u16* dst = (sel == 0) ? qo : ko;
#pragma unroll
          for (int e = 0; e < 4; e++)
            dst[(size_t)(mr + e) * 1024 + cc] = f2bf(acc[i][j][e]);
        }
      } else if (EPI == 2) {
        const float bb = bias[nc];
#pragma unroll
        for (int e = 0; e < 4; e++) {
          const float v = acc[i][j][e] + bb;
          const float g = 0.5f * v * (1.0f + tanhf(0.7978845608028654f * (v + 0.044715f * v * v * v)));
          outB[(size_t)(mr + e) * N + nc] = f2bf(g);
        }
      } else {
#pragma unroll
        for (int e = 0; e < 4; e++)
          po[(size_t)(mr + e) * N + nc] = acc[i][j][e];
      }
    }
  }
}

// ---------------- causal flash attention v3 ----------------------------------
// Register-double-buffered K/V prefetch; exp2-folded no-max softmax; XCD-chunked
// block swizzle (2 heads per XCD -> K/V L2-resident). 4 waves split K stride-4.
__device__ __forceinline__ void attn_load(
    bf16x8 (&kf)[2][2], bf16x8 (&vf)[4],
    const u16* __restrict__ Kb, const u16* __restrict__ Vt,
    int h, int k0, int l15, int lg) {
#pragma unroll
  for (int f = 0; f < 2; f++)
#pragma unroll
    for (int kk = 0; kk < 2; kk++)
      kf[kk][f] = *(const bf16x8*)(Kb + (size_t)(k0 + f * 16 + l15) * 1024 + h * 64 + kk * 32 + lg * 8);
#pragma unroll
  for (int nb = 0; nb < 4; nb++)
    vf[nb] = *(const bf16x8*)(Vt + (size_t)(h * 64 + nb * 16 + l15) * 2048 + k0 + lg * 8);
}

__device__ __forceinline__ void attn_tile(
    const bf16x8 (&kf)[2][2], const bf16x8 (&vf)[4], const bf16x8 (&qf)[2][2],
    f32x4 (&accO)[2][4], float (&lsum)[2], u16* myP,
    int k0, bool diag, int qb, int l15, int lg) {
  f32x4 sv[2][2] = {};
#pragma unroll
  for (int g = 0; g < 2; g++)
#pragma unroll
    for (int f = 0; f < 2; f++)
#pragma unroll
      for (int kk = 0; kk < 2; kk++)
        sv[g][f] = mfma16(kf[kk][f], qf[g][kk], sv[g][f]);
  // sv[g][f][e] = score(q = qb+g*16+l15, k = k0+f*16+lg*4+e)
#pragma unroll
  for (int g = 0; g < 2; g++) {
#pragma unroll
    for (int f = 0; f < 2; f++) {
      bf16x4 pk;
      float ps = 0.f;
#pragma unroll
      for (int e = 0; e < 4; e++) {
        float p = exp2f(sv[g][f][e] * 0.1803368801f);  // exp(s/8)
        if (diag && (k0 + f * 16 + lg * 4 + e > qb + g * 16 + l15)) p = 0.f;
        ps += p;
        pk[e] = (bf16)p;
      }
      lsum[g] += ps;
      *(bf16x4*)(myP + g * 640 + l15 * 40 + f * 16 + lg * 4) = pk;
    }
  }
  const bf16x8 pf0 = *(const bf16x8*)(myP + l15 * 40 + lg * 8);
  const bf16x8 pf1 = *(const bf16x8*)(myP + 640 + l15 * 40 + lg * 8);
#pragma unroll
  for (int nb = 0; nb < 4; nb++) {
    accO[0][nb] = mfma16(pf0, vf[nb], accO[0][nb]);
    accO[1][nb] = mfma16(pf1, vf[nb], accO[1][nb]);
  }
}

__global__ __launch_bounds__(256)
void attn_fwd(const u16* __restrict__ Qb, const u16* __restrict__ Kb,
              const u16* __restrict__ Vt, u16* __restrict__ Ob) {
  __shared__ __attribute__((aligned(16))) char smem[33280];
  float* sO = (float*)smem;            // [4][2048] f32 (after barrier)
  float* sL = (float*)(smem + 32768);  // [4][32]
  u16* lP = (u16*)smem;                // [2 buf][4 waves][1280 u16] (pre-barrier)

  const int t = threadIdx.x;
  const int l = t & 63, w = t >> 6;
  const int l15 = l & 15, lg = l >> 4;
  // XCD-chunked swizzle: xcd = bid%8 gets contiguous 128 vb -> 2 heads/XCD
  const u32 bid = blockIdx.x;
  const u32 vb = (bid & 7) * 128 + (bid >> 3);
  const int h = (int)(vb >> 6);
  const int qt = 63 - (int)(vb & 63);  // LPT within chunk
  const int qb = qt * 32;

  u16* myPA = lP + w * 1280;
  u16* myPB = lP + 5120 + w * 1280;

  bf16x8 qf[2][2];
#pragma unroll
  for (int g = 0; g < 2; g++)
#pragma unroll
    for (int kk = 0; kk < 2; kk++)
      qf[g][kk] = *(const bf16x8*)(Qb + (size_t)(qb + g * 16 + l15) * 1024 + h * 64 + kk * 32 + lg * 8);

  f32x4 accO[2][4] = {};
  float lsum[2] = {0.f, 0.f};

  if (w <= qt) {
    bf16x8 kfA[2][2], vfA[4], kfB[2][2], vfB[4];
    attn_load(kfA, vfA, Kb, Vt, h, w * 32, l15, lg);
    int kt = w;
    while (true) {
      const int ktB = kt + 4;
      const bool hasB = (ktB <= qt);
      attn_load(kfB, vfB, Kb, Vt, h, (hasB ? ktB : kt) * 32, l15, lg);
      attn_tile(kfA, vfA, qf, accO, lsum, myPA, kt * 32, kt == qt, qb, l15, lg);
      if (!hasB) break;
      const int ktA = kt + 8;
      const bool hasA = (ktA <= qt);
      attn_load(kfA, vfA, Kb, Vt, h, (hasA ? ktA : ktB) * 32, l15, lg);
      attn_tile(kfB, vfB, qf, accO, lsum, myPB, ktB * 32, ktB == qt, qb, l15, lg);
      if (!hasA) break;
      kt = ktA;
    }
  }

  float lsr[2];
#pragma unroll
  for (int g = 0; g < 2; g++) {
    float v = lsum[g];
    v += __shfl_xor(v, 16);
    v += __shfl_xor(v, 32);
    lsr[g] = v;
  }

  __syncthreads();  // all waves done with lP; smem becomes sO
#pragma unroll
  for (int g = 0; g < 2; g++) {
#pragma unroll
    for (int nb = 0; nb < 4; nb++)
#pragma unroll
      for (int e = 0; e < 4; e++)
        sO[w * 2048 + (g * 16 + lg * 4 + e) * 64 + nb * 16 + l15] = accO[g][nb][e];
    if (lg == 0) sL[w * 32 + g * 16 + l15] = lsr[g];
  }
  __syncthreads();

  const int base = t * 8;
  const int row = base >> 6;
  const int col = base & 63;
  f32x4 a0 = {}, a1 = {};
  float ls = 0.f;
#pragma unroll
  for (int ww = 0; ww < 4; ww++) {
    a0 += *(const f32x4*)&sO[ww * 2048 + base];
    a1 += *(const f32x4*)&sO[ww * 2048 + base + 4];
    ls += sL[ww * 32 + row];
  }
  const float rinv = 1.0f / ls;
  u16x8 o;
#pragma unroll
  for (int j = 0; j < 4; j++) {
    o[j] = f2bf(a0[j] * rinv);
    o[4 + j] = f2bf(a1[j] * rinv);
  }
  *(u16x8*)(Ob + (size_t)(qb + row) * 1024 + h * 64 + col) = o;
}

// ---------------- launch ----------------------------------------------------
extern "C" void kernel_launch(void* const* d_in, const int* in_sizes, int n_in,
                              void* d_out, int out_size, void* d_ws, size_t ws_size,
                              hipStream_t stream) {
  const float* x     = (const float*)d_in[0];
  const float* W_qkv = (const float*)d_in[1];
  const float* W_o   = (const float*)d_in[2];
  const float* W1    = (const float*)d_in[3];
  const float* b1    = (const float*)d_in[4];
  const float* W2    = (const float*)d_in[5];
  const float* b2    = (const float*)d_in[6];
  const float* ln_aw = (const float*)d_in[7];
  const float* ln_ab = (const float*)d_in[8];
  const float* ln_mw = (const float*)d_in[9];
  const float* ln_mb = (const float*)d_in[10];

  // workspace layout (lifetime-aliased; peak 67.5 MB):
  char* ws = (char*)d_ws;
  u16* Wqkv_t = (u16*)(ws);                  // [3072][1024] bf16   6 MB  persistent
  u16* Wo_t   = (u16*)(ws + 6291456);        // [1024][1024]        2 MB  persistent
  u16* W1_t   = (u16*)(ws + 8388608);        // [4096][1024]        8 MB  persistent
  u16* W2_t   = (u16*)(ws + 16777216);       // [1024][4096]        8 MB  persistent
  u16* h1     = (u16*)(ws + 25165824);       // [2048][1024]        4 MB  (h2 aliases)
  u16* h2     = h1;                          //                     dead-by-then alias
  u16* Qb     = (u16*)(ws + 29360128);       // [2048][1024]        4 MB
  u16* Kb     = (u16*)(ws + 33554432);       // [2048][1024]        4 MB
  u16* Vt     = (u16*)(ws + 37748736);       // [1024][2048]        4 MB
  u16* attnb  = (u16*)(ws + 41943040);       // [2048][1024]        4 MB
  u16* ffb    = (u16*)(ws + 29360128);       // [2048][4096]       16 MB  aliases Qb..attnb (dead)
  float* p0   = (float*)(ws + 46137344);     // [2048][1024] f32    8 MB  split-K partial
  float* p1   = (float*)(ws + 54525952);     // [2048][1024] f32    8 MB  split-K partial
  float* x2   = (float*)(ws + 62914560);     // [2048][1024] f32    8 MB
  (void)ws_size; (void)in_sizes; (void)n_in; (void)out_size;

  wconv_all<<<3072, 256, 0, stream>>>(W_qkv, W_o, W1, W2, Wqkv_t, Wo_t, W1_t, W2_t);

  ln_bf16<<<2048, 256, 0, stream>>>(x, ln_aw, ln_ab, h1);

  // QKV: 128x64 tiles -> 768 blocks (3/CU)
  gemm_bf16<128, 64, 0, 1><<<dim3(48, 16), 256, 0, stream>>>(
      h1, Wqkv_t, 2048, 3072, 1024, nullptr, nullptr, nullptr, nullptr, Qb, Kb, Vt);

  attn_fwd<<<1024, 256, 0, stream>>>(Qb, Kb, Vt, attnb);

  // W_o: 64x128 tiles, split-K=2 -> 512 blocks (2/CU)
  gemm_bf16<64, 128, 4, 2><<<dim3(8, 32, 2), 256, 0, stream>>>(
      attnb, Wo_t, 2048, 1024, 1024, nullptr, p0, p1, nullptr, nullptr, nullptr, nullptr);

  reduce_ln<<<2048, 256, 0, stream>>>(x, p0, p1, ln_mw, ln_mb, x2, h2);

  // FF1: 128x64 tiles -> 1024 blocks (4/CU)
  gemm_bf16<128, 64, 2, 1><<<dim3(64, 16), 256, 0, stream>>>(
      h2, W1_t, 2048, 4096, 1024, b1, nullptr, nullptr, ffb, nullptr, nullptr, nullptr);

  // FF2: 64x128 tiles, split-K=2 -> 512 blocks (2/CU)
  gemm_bf16<64, 128, 4, 2><<<dim3(8, 32, 2), 256, 0, stream>>>(
      ffb, W2_t, 2048, 1024, 4096, nullptr, p0, p1, nullptr, nullptr, nullptr, nullptr);

  reduce_out<<<2048, 256, 0, stream>>>(x2, b2, p0, p1, (float*)d_out);
}

// Round 6
// 186.672 us; speedup vs baseline: 1.7389x; 1.0019x over previous
//
#include <hip/hip_runtime.h>
#include <math.h>

typedef __bf16 bf16;
typedef __bf16 bf16x4 __attribute__((ext_vector_type(4)));
typedef __bf16 bf16x8 __attribute__((ext_vector_type(8)));
typedef float f32x4 __attribute__((ext_vector_type(4)));
typedef unsigned short u16;
typedef unsigned short u16x8 __attribute__((ext_vector_type(8)));
typedef unsigned int u32;

__device__ __forceinline__ u16 f2bf(float f) {
  union { float f; u32 u; } v; v.f = f;
  u32 u = v.u;
  return (u16)((u + 0x7FFFu + ((u >> 16) & 1u)) >> 16);
}

__device__ __forceinline__ f32x4 mfma16(bf16x8 a, bf16x8 b, f32x4 c) {
  return __builtin_amdgcn_mfma_f32_16x16x32_bf16(a, b, c, 0, 0, 0);
}

__device__ __forceinline__ void gld16(const void* g, void* l) {
  __builtin_amdgcn_global_load_lds(
      (const __attribute__((address_space(1))) void*)(void*)g,
      (__attribute__((address_space(3))) void*)l,
      16, 0, 0);
}

// ---------------- weight fp32 -> bf16 transpose (Wt[n][k] = W[k][n]) ----------
__device__ __forceinline__ void wconv_body(const float* __restrict__ W,
                                           u16* __restrict__ Wt, int K, int N,
                                           int bx, int by) {
  __shared__ float tile[64][65];
  const int k0 = by * 64, n0 = bx * 64;
  const int t = threadIdx.x;
  const int tr = t >> 4;
  const int tc = (t & 15) * 4;
#pragma unroll
  for (int it = 0; it < 4; it++) {
    const int r = tr + it * 16;
    const float4 v = *(const float4*)(W + (size_t)(k0 + r) * N + n0 + tc);
    tile[r][tc] = v.x; tile[r][tc + 1] = v.y; tile[r][tc + 2] = v.z; tile[r][tc + 3] = v.w;
  }
  __syncthreads();
#pragma unroll
  for (int it = 0; it < 4; it++) {
    const int rn = tr + it * 16;
    ushort4 o;
    o.x = f2bf(tile[tc][rn]);
    o.y = f2bf(tile[tc + 1][rn]);
    o.z = f2bf(tile[tc + 2][rn]);
    o.w = f2bf(tile[tc + 3][rn]);
    *(ushort4*)(Wt + (size_t)(n0 + rn) * K + k0 + tc) = o;
  }
}

__global__ __launch_bounds__(256)
void wconv_all(const float* __restrict__ Wqkv, const float* __restrict__ Wo,
               const float* __restrict__ W1, const float* __restrict__ W2,
               u16* __restrict__ Wqkv_t, u16* __restrict__ Wo_t,
               u16* __restrict__ W1_t, u16* __restrict__ W2_t) {
  const int id = blockIdx.x;  // uniform per block
  if (id < 768)       { wconv_body(Wqkv, Wqkv_t, 1024, 3072, id % 48, id / 48); }
  else if (id < 1024) { const int j = id - 768;  wconv_body(Wo, Wo_t, 1024, 1024, j % 16, j / 16); }
  else if (id < 2048) { const int j = id - 1024; wconv_body(W1, W1_t, 1024, 4096, j % 64, j / 64); }
  else                { const int j = id - 2048; wconv_body(W2, W2_t, 4096, 1024, j % 16, j / 16); }
}

// ---------------- LayerNorm (fp32 in -> bf16 out) ----------------------------
__global__ __launch_bounds__(256)
void ln_bf16(const float* __restrict__ x, const float* __restrict__ w,
             const float* __restrict__ b, u16* __restrict__ out) {
  const int row = blockIdx.x;
  const int t = threadIdx.x;
  const float4 v = *(const float4*)(x + (size_t)row * 1024 + t * 4);
  float s = v.x + v.y + v.z + v.w;
  float s2 = v.x * v.x + v.y * v.y + v.z * v.z + v.w * v.w;
#pragma unroll
  for (int m = 1; m < 64; m <<= 1) {
    s += __shfl_xor(s, m);
    s2 += __shfl_xor(s2, m);
  }
  __shared__ float red[8];
  if ((t & 63) == 0) { red[t >> 6] = s; red[4 + (t >> 6)] = s2; }
  __syncthreads();
  s = red[0] + red[1] + red[2] + red[3];
  s2 = red[4] + red[5] + red[6] + red[7];
  const float mu = s * (1.f / 1024.f);
  const float var = fmaxf(s2 * (1.f / 1024.f) - mu * mu, 0.f);
  const float rstd = rsqrtf(var + 1e-5f);
  const float* wp = w + t * 4;
  const float* bp = b + t * 4;
  ushort4 o;
  o.x = f2bf((v.x - mu) * rstd * wp[0] + bp[0]);
  o.y = f2bf((v.y - mu) * rstd * wp[1] + bp[1]);
  o.z = f2bf((v.z - mu) * rstd * wp[2] + bp[2]);
  o.w = f2bf((v.w - mu) * rstd * wp[3] + bp[3]);
  *(ushort4*)(out + (size_t)row * 1024 + t * 4) = o;
}

// ---------------- fused: x2 = x + p0 + p1 ; h2 = LN(x2) ----------------------
__global__ __launch_bounds__(256)
void reduce_ln(const float* __restrict__ x, const float* __restrict__ p0,
               const float* __restrict__ p1, const float* __restrict__ w,
               const float* __restrict__ b, float* __restrict__ x2,
               u16* __restrict__ h2) {
  const int row = blockIdx.x;
  const int t = threadIdx.x;
  const size_t base = (size_t)row * 1024 + t * 4;
  float4 v = *(const float4*)(x + base);
  const float4 a = *(const float4*)(p0 + base);
  const float4 c = *(const float4*)(p1 + base);
  v.x += a.x + c.x; v.y += a.y + c.y; v.z += a.z + c.z; v.w += a.w + c.w;
  *(float4*)(x2 + base) = v;
  float s = v.x + v.y + v.z + v.w;
  float s2 = v.x * v.x + v.y * v.y + v.z * v.z + v.w * v.w;
#pragma unroll
  for (int m = 1; m < 64; m <<= 1) {
    s += __shfl_xor(s, m);
    s2 += __shfl_xor(s2, m);
  }
  __shared__ float red[8];
  if ((t & 63) == 0) { red[t >> 6] = s; red[4 + (t >> 6)] = s2; }
  __syncthreads();
  s = red[0] + red[1] + red[2] + red[3];
  s2 = red[4] + red[5] + red[6] + red[7];
  const float mu = s * (1.f / 1024.f);
  const float var = fmaxf(s2 * (1.f / 1024.f) - mu * mu, 0.f);
  const float rstd = rsqrtf(var + 1e-5f);
  const float* wp = w + t * 4;
  const float* bp = b + t * 4;
  ushort4 o;
  o.x = f2bf((v.x - mu) * rstd * wp[0] + bp[0]);
  o.y = f2bf((v.y - mu) * rstd * wp[1] + bp[1]);
  o.z = f2bf((v.z - mu) * rstd * wp[2] + bp[2]);
  o.w = f2bf((v.w - mu) * rstd * wp[3] + bp[3]);
  *(ushort4*)(h2 + base) = o;
}

// ---------------- fused: out = x2 + bias + p0 + p1 ---------------------------
__global__ __launch_bounds__(256)
void reduce_out(const float* __restrict__ x2, const float* __restrict__ bias,
                const float* __restrict__ p0, const float* __restrict__ p1,
                float* __restrict__ out) {
  const size_t base = ((size_t)blockIdx.x * 256 + threadIdx.x) * 4;
  const int col = (int)(base & 1023);
  float4 v = *(const float4*)(x2 + base);
  const float4 a = *(const float4*)(p0 + base);
  const float4 c = *(const float4*)(p1 + base);
  const float4 bb = *(const float4*)(bias + col);
  v.x += a.x + c.x + bb.x;
  v.y += a.y + c.y + bb.y;
  v.z += a.z + c.z + bb.z;
  v.w += a.w + c.w + bb.w;
  *(float4*)(out + base) = v;
}

// ---------------- bf16 GEMM, BMxBN tile, BK=32, counted-vmcnt pipeline -------
// A: [M][K] bf16 row-major; Bt: [N][K] bf16 (B transposed). fp32 accum.
// T3/T4-minimum: stage(t+1) -> s_waitcnt vmcnt(3) [waits tile t ONLY; the 3
// just-issued loads stay in flight] -> s_barrier -> ds_read -> lgkmcnt(0) ->
// s_barrier [buffer free] -> MFMA overlapping the in-flight loads. No vmcnt(0)
// in the main loop (raw s_barrier emits no drain, unlike __syncthreads).
template <int BM, int BN, int EPI, int KS>
__global__ __launch_bounds__(256)
void gemm_bf16(const u16* __restrict__ A, const u16* __restrict__ Bt,
               int M, int N, int K,
               const float* __restrict__ bias,
               float* __restrict__ po0, float* __restrict__ po1,
               u16* __restrict__ outB,
               u16* __restrict__ qo, u16* __restrict__ ko, u16* __restrict__ vo) {
  constexpr int ASZ = BM * 32;
  constexpr int BSZ = BN * 32;
  __shared__ __attribute__((aligned(16))) u16 lA[2 * ASZ];
  __shared__ __attribute__((aligned(16))) u16 lB[2 * BSZ];
  const int t = threadIdx.x;
  const int l = t & 63;
  const int w = t >> 6;
  constexpr int NJ = (BM == 128 && BN == 128) ? 4 : 2;
  const int WR = (BM == 128) ? (w >> 1) * 64 : 0;
  const int WC = (BM == 128) ? ((BN == 128) ? (w & 1) * 64 : (w & 1) * 32)
                             : w * 32;
  const int l15 = l & 15, lg = l >> 4;

  // XCD-chunked swizzle (requires gridDim.x % 8 == 0; true at all call sites)
  const int nx = gridDim.x;
  const u32 bid = blockIdx.y * nx + blockIdx.x;
  const int nxc = nx >> 3;
  const u32 r = bid >> 3;
  const int bx = (bid & 7) * nxc + (int)(r % (u32)nxc);
  const int by = (int)(r / (u32)nxc);

  const int m0 = by * BM, n0 = bx * BN;
  const int KC = K / KS;
  const int kbase = blockIdx.z * KC;

  f32x4 acc[4][NJ] = {};

  const int lr = t >> 2;
  const int lc = ((t & 3) << 3) + kbase;
  const u16* ag0 = A + (size_t)(m0 + lr) * K + lc;
  const u16* ag1 = A + (size_t)(m0 + 64 + lr) * K + lc;
  const u16* bg0 = Bt + (size_t)(n0 + lr) * K + lc;
  const u16* bg1 = Bt + (size_t)(n0 + 64 + lr) * K + lc;

  const int nt = KC / 32;
  auto stage = [&](int buf, int kt) {  // exactly 3 gld16 for all variants
    const int k0 = kt * 32;
    gld16(ag0 + k0, &lA[buf * ASZ + t * 8]);
    if (BM == 128) gld16(ag1 + k0, &lA[buf * ASZ + 2048 + t * 8]);
    gld16(bg0 + k0, &lB[buf * BSZ + t * 8]);
    if (BN == 128) gld16(bg1 + k0, &lB[buf * BSZ + 2048 + t * 8]);
  };

  stage(0, 0);

  for (int kt = 0; kt < nt; kt++) {
    const int cur = kt & 1;
    if (kt + 1 < nt) {
      stage(cur ^ 1, kt + 1);  // 3 more in flight (6 total)
      asm volatile("s_waitcnt vmcnt(3)" ::: "memory");  // tile kt landed
    } else {
      asm volatile("s_waitcnt vmcnt(0)" ::: "memory");
    }
    __builtin_amdgcn_s_barrier();  // buf[cur] visible to all waves
    bf16x8 af[4], bfr[NJ];
#pragma unroll
    for (int i = 0; i < 4; i++)
      af[i] = *(const bf16x8*)&lA[cur * ASZ + (WR + i * 16 + l15) * 32 + lg * 8];
#pragma unroll
    for (int j = 0; j < NJ; j++)
      bfr[j] = *(const bf16x8*)&lB[cur * BSZ + (WC + j * 16 + l15) * 32 + lg * 8];
    asm volatile("s_waitcnt lgkmcnt(0)" ::: "memory");  // reads in regs
    __builtin_amdgcn_s_barrier();        // all waves done reading buf[cur]
    __builtin_amdgcn_sched_barrier(0);   // pin MFMA below (rule #18)
#pragma unroll
    for (int i = 0; i < 4; i++)
#pragma unroll
      for (int j = 0; j < NJ; j++)
        acc[i][j] = mfma16(af[i], bfr[j], acc[i][j]);  // overlaps t+1 loads
  }

  float* po = (KS == 2 && blockIdx.z == 1) ? po1 : po0;
  const int mr0 = m0 + WR + lg * 4;
  const int nc0 = n0 + WC + l15;
#pragma unroll
  for (int i = 0; i < 4; i++) {
    const int mr = mr0 + i * 16;
#pragma unroll
    for (int j = 0; j < NJ; j++) {
      const int nc = nc0 + j * 16;
      if (EPI == 0) {
        const int sel = nc >> 10;
        const int cc = nc & 1023;
        if (sel == 2) {
          ushort4 o;
          o.x = f2bf(acc[i][j][0]); o.y = f2bf(acc[i][j][1]);
          o.z = f2bf(acc[i][j][2]); o.w = f2bf(acc[i][j][3]);
          *(ushort4*)(vo + (size_t)cc * 2048 + mr) = o;
        } else {
          u16* dst = (sel == 0) ? qo : ko;
#pragma unroll
          for (int e = 0; e < 4; e++)
            dst[(size_t)(mr + e) * 1024 + cc] = f2bf(acc[i][j][e]);
        }
      } else if (EPI == 2) {
        const float bb = bias[nc];
#pragma unroll
        for (int e = 0; e < 4; e++) {
          const float v = acc[i][j][e] + bb;
          const float g = 0.5f * v * (1.0f + tanhf(0.7978845608028654f * (v + 0.044715f * v * v * v)));
          outB[(size_t)(mr + e) * N + nc] = f2bf(g);
        }
      } else {
#pragma unroll
        for (int e = 0; e < 4; e++)
          po[(size_t)(mr + e) * N + nc] = acc[i][j][e];
      }
    }
  }
}

// ---------------- causal flash attention v3 ----------------------------------
// Register-double-buffered K/V prefetch; exp2-folded no-max softmax; XCD-chunked
// block swizzle (2 heads per XCD -> K/V L2-resident). 4 waves split K stride-4.
// s_setprio(1) around MFMA clusters (T5: attn-positive, m191).
__device__ __forceinline__ void attn_load(
    bf16x8 (&kf)[2][2], bf16x8 (&vf)[4],
    const u16* __restrict__ Kb, const u16* __restrict__ Vt,
    int h, int k0, int l15, int lg) {
#pragma unroll
  for (int f = 0; f < 2; f++)
#pragma unroll
    for (int kk = 0; kk < 2; kk++)
      kf[kk][f] = *(const bf16x8*)(Kb + (size_t)(k0 + f * 16 + l15) * 1024 + h * 64 + kk * 32 + lg * 8);
#pragma unroll
  for (int nb = 0; nb < 4; nb++)
    vf[nb] = *(const bf16x8*)(Vt + (size_t)(h * 64 + nb * 16 + l15) * 2048 + k0 + lg * 8);
}

__device__ __forceinline__ void attn_tile(
    const bf16x8 (&kf)[2][2], const bf16x8 (&vf)[4], const bf16x8 (&qf)[2][2],
    f32x4 (&accO)[2][4], float (&lsum)[2], u16* myP,
    int k0, bool diag, int qb, int l15, int lg) {
  f32x4 sv[2][2] = {};
  __builtin_amdgcn_s_setprio(1);
#pragma unroll
  for (int g = 0; g < 2; g++)
#pragma unroll
    for (int f = 0; f < 2; f++)
#pragma unroll
      for (int kk = 0; kk < 2; kk++)
        sv[g][f] = mfma16(kf[kk][f], qf[g][kk], sv[g][f]);
  __builtin_amdgcn_s_setprio(0);
  // sv[g][f][e] = score(q = qb+g*16+l15, k = k0+f*16+lg*4+e)
#pragma unroll
  for (int g = 0; g < 2; g++) {
#pragma unroll
    for (int f = 0; f < 2; f++) {
      bf16x4 pk;
      float ps = 0.f;
#pragma unroll
      for (int e = 0; e < 4; e++) {
        float p = exp2f(sv[g][f][e] * 0.1803368801f);  // exp(s/8)
        if (diag && (k0 + f * 16 + lg * 4 + e > qb + g * 16 + l15)) p = 0.f;
        ps += p;
        pk[e] = (bf16)p;
      }
      lsum[g] += ps;
      *(bf16x4*)(myP + g * 640 + l15 * 40 + f * 16 + lg * 4) = pk;
    }
  }
  const bf16x8 pf0 = *(const bf16x8*)(myP + l15 * 40 + lg * 8);
  const bf16x8 pf1 = *(const bf16x8*)(myP + 640 + l15 * 40 + lg * 8);
  __builtin_amdgcn_s_setprio(1);
#pragma unroll
  for (int nb = 0; nb < 4; nb++) {
    accO[0][nb] = mfma16(pf0, vf[nb], accO[0][nb]);
    accO[1][nb] = mfma16(pf1, vf[nb], accO[1][nb]);
  }
  __builtin_amdgcn_s_setprio(0);
}

__global__ __launch_bounds__(256)
void attn_fwd(const u16* __restrict__ Qb, const u16* __restrict__ Kb,
              const u16* __restrict__ Vt, u16* __restrict__ Ob) {
  __shared__ __attribute__((aligned(16))) char smem[33280];
  float* sO = (float*)smem;            // [4][2048] f32 (after barrier)
  float* sL = (float*)(smem + 32768);  // [4][32]
  u16* lP = (u16*)smem;                // [2 buf][4 waves][1280 u16] (pre-barrier)

  const int t = threadIdx.x;
  const int l = t & 63, w = t >> 6;
  const int l15 = l & 15, lg = l >> 4;
  // XCD-chunked swizzle: xcd = bid%8 gets contiguous 128 vb -> 2 heads/XCD
  const u32 bid = blockIdx.x;
  const u32 vb = (bid & 7) * 128 + (bid >> 3);
  const int h = (int)(vb >> 6);
  const int qt = 63 - (int)(vb & 63);  // LPT within chunk
  const int qb = qt * 32;

  u16* myPA = lP + w * 1280;
  u16* myPB = lP + 5120 + w * 1280;

  bf16x8 qf[2][2];
#pragma unroll
  for (int g = 0; g < 2; g++)
#pragma unroll
    for (int kk = 0; kk < 2; kk++)
      qf[g][kk] = *(const bf16x8*)(Qb + (size_t)(qb + g * 16 + l15) * 1024 + h * 64 + kk * 32 + lg * 8);

  f32x4 accO[2][4] = {};
  float lsum[2] = {0.f, 0.f};

  if (w <= qt) {
    bf16x8 kfA[2][2], vfA[4], kfB[2][2], vfB[4];
    attn_load(kfA, vfA, Kb, Vt, h, w * 32, l15, lg);
    int kt = w;
    while (true) {
      const int ktB = kt + 4;
      const bool hasB = (ktB <= qt);
      attn_load(kfB, vfB, Kb, Vt, h, (hasB ? ktB : kt) * 32, l15, lg);
      attn_tile(kfA, vfA, qf, accO, lsum, myPA, kt * 32, kt == qt, qb, l15, lg);
      if (!hasB) break;
      const int ktA = kt + 8;
      const bool hasA = (ktA <= qt);
      attn_load(kfA, vfA, Kb, Vt, h, (hasA ? ktA : ktB) * 32, l15, lg);
      attn_tile(kfB, vfB, qf, accO, lsum, myPB, ktB * 32, ktB == qt, qb, l15, lg);
      if (!hasA) break;
      kt = ktA;
    }
  }

  float lsr[2];
#pragma unroll
  for (int g = 0; g < 2; g++) {
    float v = lsum[g];
    v += __shfl_xor(v, 16);
    v += __shfl_xor(v, 32);
    lsr[g] = v;
  }

  __syncthreads();  // all waves done with lP; smem becomes sO
#pragma unroll
  for (int g = 0; g < 2; g++) {
#pragma unroll
    for (int nb = 0; nb < 4; nb++)
#pragma unroll
      for (int e = 0; e < 4; e++)
        sO[w * 2048 + (g * 16 + lg * 4 + e) * 64 + nb * 16 + l15] = accO[g][nb][e];
    if (lg == 0) sL[w * 32 + g * 16 + l15] = lsr[g];
  }
  __syncthreads();

  const int base = t * 8;
  const int row = base >> 6;
  const int col = base & 63;
  f32x4 a0 = {}, a1 = {};
  float ls = 0.f;
#pragma unroll
  for (int ww = 0; ww < 4; ww++) {
    a0 += *(const f32x4*)&sO[ww * 2048 + base];
    a1 += *(const f32x4*)&sO[ww * 2048 + base + 4];
    ls += sL[ww * 32 + row];
  }
  const float rinv = 1.0f / ls;
  u16x8 o;
#pragma unroll
  for (int j = 0; j < 4; j++) {
    o[j] = f2bf(a0[j] * rinv);
    o[4 + j] = f2bf(a1[j] * rinv);
  }
  *(u16x8*)(Ob + (size_t)(qb + row) * 1024 + h * 64 + col) = o;
}

// ---------------- launch ----------------------------------------------------
extern "C" void kernel_launch(void* const* d_in, const int* in_sizes, int n_in,
                              void* d_out, int out_size, void* d_ws, size_t ws_size,
                              hipStream_t stream) {
  const float* x     = (const float*)d_in[0];
  const float* W_qkv = (const float*)d_in[1];
  const float* W_o   = (const float*)d_in[2];
  const float* W1    = (const float*)d_in[3];
  const float* b1    = (const float*)d_in[4];
  const float* W2    = (const float*)d_in[5];
  const float* b2    = (const float*)d_in[6];
  const float* ln_aw = (const float*)d_in[7];
  const float* ln_ab = (const float*)d_in[8];
  const float* ln_mw = (const float*)d_in[9];
  const float* ln_mb = (const float*)d_in[10];

  // workspace layout (lifetime-aliased; peak 67.5 MB):
  char* ws = (char*)d_ws;
  u16* Wqkv_t = (u16*)(ws);                  // [3072][1024] bf16   6 MB  persistent
  u16* Wo_t   = (u16*)(ws + 6291456);        // [1024][1024]        2 MB  persistent
  u16* W1_t   = (u16*)(ws + 8388608);        // [4096][1024]        8 MB  persistent
  u16* W2_t   = (u16*)(ws + 16777216);       // [1024][4096]        8 MB  persistent
  u16* h1     = (u16*)(ws + 25165824);       // [2048][1024]        4 MB  (h2 aliases)
  u16* h2     = h1;                          //                     dead-by-then alias
  u16* Qb     = (u16*)(ws + 29360128);       // [2048][1024]        4 MB
  u16* Kb     = (u16*)(ws + 33554432);       // [2048][1024]        4 MB
  u16* Vt     = (u16*)(ws + 37748736);       // [1024][2048]        4 MB
  u16* attnb  = (u16*)(ws + 41943040);       // [2048][1024]        4 MB
  u16* ffb    = (u16*)(ws + 29360128);       // [2048][4096]       16 MB  aliases Qb..attnb (dead)
  float* p0   = (float*)(ws + 46137344);     // [2048][1024] f32    8 MB  split-K partial
  float* p1   = (float*)(ws + 54525952);     // [2048][1024] f32    8 MB  split-K partial
  float* x2   = (float*)(ws + 62914560);     // [2048][1024] f32    8 MB
  (void)ws_size; (void)in_sizes; (void)n_in; (void)out_size;

  wconv_all<<<3072, 256, 0, stream>>>(W_qkv, W_o, W1, W2, Wqkv_t, Wo_t, W1_t, W2_t);

  ln_bf16<<<2048, 256, 0, stream>>>(x, ln_aw, ln_ab, h1);

  // QKV: 128x64 tiles -> 768 blocks (3/CU)
  gemm_bf16<128, 64, 0, 1><<<dim3(48, 16), 256, 0, stream>>>(
      h1, Wqkv_t, 2048, 3072, 1024, nullptr, nullptr, nullptr, nullptr, Qb, Kb, Vt);

  attn_fwd<<<1024, 256, 0, stream>>>(Qb, Kb, Vt, attnb);

  // W_o: 64x128 tiles, split-K=2 -> 512 blocks (2/CU)
  gemm_bf16<64, 128, 4, 2><<<dim3(8, 32, 2), 256, 0, stream>>>(
      attnb, Wo_t, 2048, 1024, 1024, nullptr, p0, p1, nullptr, nullptr, nullptr, nullptr);

  reduce_ln<<<2048, 256, 0, stream>>>(x, p0, p1, ln_mw, ln_mb, x2, h2);

  // FF1: 128x64 tiles -> 1024 blocks (4/CU)
  gemm_bf16<128, 64, 2, 1><<<dim3(64, 16), 256, 0, stream>>>(
      h2, W1_t, 2048, 4096, 1024, b1, nullptr, nullptr, ffb, nullptr, nullptr, nullptr);

  // FF2: 64x128 tiles, split-K=2 -> 512 blocks (2/CU)
  gemm_bf16<64, 128, 4, 2><<<dim3(8, 32, 2), 256, 0, stream>>>(
      ffb, W2_t, 2048, 1024, 4096, nullptr, p0, p1, nullptr, nullptr, nullptr, nullptr);

  reduce_out<<<2048, 256, 0, stream>>>(x2, b2, p0, p1, (float*)d_out);
}

// Round 7
// 169.931 us; speedup vs baseline: 1.9103x; 1.0985x over previous
//
#include <hip/hip_runtime.h>
#include <math.h>

typedef __bf16 bf16;
typedef __bf16 bf16x4 __attribute__((ext_vector_type(4)));
typedef __bf16 bf16x8 __attribute__((ext_vector_type(8)));
typedef float f32x4 __attribute__((ext_vector_type(4)));
typedef unsigned short u16;
typedef unsigned short u16x8 __attribute__((ext_vector_type(8)));
typedef unsigned int u32;

__device__ __forceinline__ u16 f2bf(float f) {
  union { float f; u32 u; } v; v.f = f;
  u32 u = v.u;
  return (u16)((u + 0x7FFFu + ((u >> 16) & 1u)) >> 16);
}

__device__ __forceinline__ f32x4 mfma16(bf16x8 a, bf16x8 b, f32x4 c) {
  return __builtin_amdgcn_mfma_f32_16x16x32_bf16(a, b, c, 0, 0, 0);
}

__device__ __forceinline__ void gld16(const void* g, void* l) {
  __builtin_amdgcn_global_load_lds(
      (const __attribute__((address_space(1))) void*)(void*)g,
      (__attribute__((address_space(3))) void*)l,
      16, 0, 0);
}

// ---------------- weight fp32 -> bf16 transpose (Wt[n][k] = W[k][n]) ----------
__device__ __forceinline__ void wconv_body(const float* __restrict__ W,
                                           u16* __restrict__ Wt, int K, int N,
                                           int bx, int by) {
  __shared__ float tile[64][65];
  const int k0 = by * 64, n0 = bx * 64;
  const int t = threadIdx.x;
  const int tr = t >> 4;
  const int tc = (t & 15) * 4;
#pragma unroll
  for (int it = 0; it < 4; it++) {
    const int r = tr + it * 16;
    const float4 v = *(const float4*)(W + (size_t)(k0 + r) * N + n0 + tc);
    tile[r][tc] = v.x; tile[r][tc + 1] = v.y; tile[r][tc + 2] = v.z; tile[r][tc + 3] = v.w;
  }
  __syncthreads();
#pragma unroll
  for (int it = 0; it < 4; it++) {
    const int rn = tr + it * 16;
    ushort4 o;
    o.x = f2bf(tile[tc][rn]);
    o.y = f2bf(tile[tc + 1][rn]);
    o.z = f2bf(tile[tc + 2][rn]);
    o.w = f2bf(tile[tc + 3][rn]);
    *(ushort4*)(Wt + (size_t)(n0 + rn) * K + k0 + tc) = o;
  }
}

__global__ __launch_bounds__(256)
void wconv_all(const float* __restrict__ Wqkv, const float* __restrict__ Wo,
               const float* __restrict__ W1, const float* __restrict__ W2,
               u16* __restrict__ Wqkv_t, u16* __restrict__ Wo_t,
               u16* __restrict__ W1_t, u16* __restrict__ W2_t) {
  const int id = blockIdx.x;  // uniform per block
  if (id < 768)       { wconv_body(Wqkv, Wqkv_t, 1024, 3072, id % 48, id / 48); }
  else if (id < 1024) { const int j = id - 768;  wconv_body(Wo, Wo_t, 1024, 1024, j % 16, j / 16); }
  else if (id < 2048) { const int j = id - 1024; wconv_body(W1, W1_t, 1024, 4096, j % 64, j / 64); }
  else                { const int j = id - 2048; wconv_body(W2, W2_t, 4096, 1024, j % 16, j / 16); }
}

// ---------------- LayerNorm (fp32 in -> bf16 out) ----------------------------
__global__ __launch_bounds__(256)
void ln_bf16(const float* __restrict__ x, const float* __restrict__ w,
             const float* __restrict__ b, u16* __restrict__ out) {
  const int row = blockIdx.x;
  const int t = threadIdx.x;
  const float4 v = *(const float4*)(x + (size_t)row * 1024 + t * 4);
  float s = v.x + v.y + v.z + v.w;
  float s2 = v.x * v.x + v.y * v.y + v.z * v.z + v.w * v.w;
#pragma unroll
  for (int m = 1; m < 64; m <<= 1) {
    s += __shfl_xor(s, m);
    s2 += __shfl_xor(s2, m);
  }
  __shared__ float red[8];
  if ((t & 63) == 0) { red[t >> 6] = s; red[4 + (t >> 6)] = s2; }
  __syncthreads();
  s = red[0] + red[1] + red[2] + red[3];
  s2 = red[4] + red[5] + red[6] + red[7];
  const float mu = s * (1.f / 1024.f);
  const float var = fmaxf(s2 * (1.f / 1024.f) - mu * mu, 0.f);
  const float rstd = rsqrtf(var + 1e-5f);
  const float* wp = w + t * 4;
  const float* bp = b + t * 4;
  ushort4 o;
  o.x = f2bf((v.x - mu) * rstd * wp[0] + bp[0]);
  o.y = f2bf((v.y - mu) * rstd * wp[1] + bp[1]);
  o.z = f2bf((v.z - mu) * rstd * wp[2] + bp[2]);
  o.w = f2bf((v.w - mu) * rstd * wp[3] + bp[3]);
  *(ushort4*)(out + (size_t)row * 1024 + t * 4) = o;
}

// ---------------- fused: x2 = x + p0 + p1 ; h2 = LN(x2) ----------------------
__global__ __launch_bounds__(256)
void reduce_ln(const float* __restrict__ x, const float* __restrict__ p0,
               const float* __restrict__ p1, const float* __restrict__ w,
               const float* __restrict__ b, float* __restrict__ x2,
               u16* __restrict__ h2) {
  const int row = blockIdx.x;
  const int t = threadIdx.x;
  const size_t base = (size_t)row * 1024 + t * 4;
  float4 v = *(const float4*)(x + base);
  const float4 a = *(const float4*)(p0 + base);
  const float4 c = *(const float4*)(p1 + base);
  v.x += a.x + c.x; v.y += a.y + c.y; v.z += a.z + c.z; v.w += a.w + c.w;
  *(float4*)(x2 + base) = v;
  float s = v.x + v.y + v.z + v.w;
  float s2 = v.x * v.x + v.y * v.y + v.z * v.z + v.w * v.w;
#pragma unroll
  for (int m = 1; m < 64; m <<= 1) {
    s += __shfl_xor(s, m);
    s2 += __shfl_xor(s2, m);
  }
  __shared__ float red[8];
  if ((t & 63) == 0) { red[t >> 6] = s; red[4 + (t >> 6)] = s2; }
  __syncthreads();
  s = red[0] + red[1] + red[2] + red[3];
  s2 = red[4] + red[5] + red[6] + red[7];
  const float mu = s * (1.f / 1024.f);
  const float var = fmaxf(s2 * (1.f / 1024.f) - mu * mu, 0.f);
  const float rstd = rsqrtf(var + 1e-5f);
  const float* wp = w + t * 4;
  const float* bp = b + t * 4;
  ushort4 o;
  o.x = f2bf((v.x - mu) * rstd * wp[0] + bp[0]);
  o.y = f2bf((v.y - mu) * rstd * wp[1] + bp[1]);
  o.z = f2bf((v.z - mu) * rstd * wp[2] + bp[2]);
  o.w = f2bf((v.w - mu) * rstd * wp[3] + bp[3]);
  *(ushort4*)(h2 + base) = o;
}

// ---------------- fused: out = x2 + bias + p0 + p1 ---------------------------
__global__ __launch_bounds__(256)
void reduce_out(const float* __restrict__ x2, const float* __restrict__ bias,
                const float* __restrict__ p0, const float* __restrict__ p1,
                float* __restrict__ out) {
  const size_t base = ((size_t)blockIdx.x * 256 + threadIdx.x) * 4;
  const int col = (int)(base & 1023);
  float4 v = *(const float4*)(x2 + base);
  const float4 a = *(const float4*)(p0 + base);
  const float4 c = *(const float4*)(p1 + base);
  const float4 bb = *(const float4*)(bias + col);
  v.x += a.x + c.x + bb.x;
  v.y += a.y + c.y + bb.y;
  v.z += a.z + c.z + bb.z;
  v.w += a.w + c.w + bb.w;
  *(float4*)(out + base) = v;
}

// ---------------- bf16 GEMM, BMxBN tile, BK=32, counted-vmcnt pipeline -------
// A: [M][K] bf16 row-major; Bt: [N][K] bf16 (B transposed). fp32 accum.
// 128x128: 4 waves as 2x2 of 64x64 (acc 4x4) -> 0.5 KB LDS-read/MFMA.
// 64x128:  4 waves as 1x4 of 64x32 (acc 4x2).
// EPI 0: QKV split -> MFMA-fragment-packed Qp/Kp/Vp:
//   Qp,Kp: [h][kt][f][kk][lane][8] ; Vp: [h][kt][nb][lane][8]  (2048 u16/kt)
// EPI 2: outB = bf16(gelu(C + bias)); EPI 4: fp32 partial -> po{0,1}
template <int BM, int BN, int EPI, int KS>
__global__ __launch_bounds__(256)
void gemm_bf16(const u16* __restrict__ A, const u16* __restrict__ Bt,
               int M, int N, int K,
               const float* __restrict__ bias,
               float* __restrict__ po0, float* __restrict__ po1,
               u16* __restrict__ outB,
               u16* __restrict__ qo, u16* __restrict__ ko, u16* __restrict__ vo) {
  constexpr int ASZ = BM * 32;
  constexpr int BSZ = BN * 32;
  constexpr int NLD = (BM == 128 ? 2 : 1) + (BN == 128 ? 2 : 1);
  __shared__ __attribute__((aligned(16))) u16 lA[2 * ASZ];
  __shared__ __attribute__((aligned(16))) u16 lB[2 * BSZ];
  const int t = threadIdx.x;
  const int l = t & 63;
  const int w = t >> 6;
  constexpr int NJ = (BM == 128 && BN == 128) ? 4 : 2;
  const int WR = (BM == 128) ? (w >> 1) * 64 : 0;
  const int WC = (BM == 128) ? ((BN == 128) ? (w & 1) * 64 : (w & 1) * 32)
                             : w * 32;
  const int l15 = l & 15, lg = l >> 4;

  // XCD-chunked swizzle (requires gridDim.x % 8 == 0; true at all call sites)
  const int nx = gridDim.x;
  const u32 bid = blockIdx.y * nx + blockIdx.x;
  const int nxc = nx >> 3;
  const u32 r = bid >> 3;
  const int bx = (bid & 7) * nxc + (int)(r % (u32)nxc);
  const int by = (int)(r / (u32)nxc);

  const int m0 = by * BM, n0 = bx * BN;
  const int KC = K / KS;
  const int kbase = blockIdx.z * KC;

  f32x4 acc[4][NJ] = {};

  const int lr = t >> 2;
  const int lc = ((t & 3) << 3) + kbase;
  const u16* ag0 = A + (size_t)(m0 + lr) * K + lc;
  const u16* ag1 = A + (size_t)(m0 + 64 + lr) * K + lc;
  const u16* bg0 = Bt + (size_t)(n0 + lr) * K + lc;
  const u16* bg1 = Bt + (size_t)(n0 + 64 + lr) * K + lc;

  const int nt = KC / 32;
  auto stage = [&](int buf, int kt) {  // NLD gld16 per call
    const int k0 = kt * 32;
    gld16(ag0 + k0, &lA[buf * ASZ + t * 8]);
    if (BM == 128) gld16(ag1 + k0, &lA[buf * ASZ + 2048 + t * 8]);
    gld16(bg0 + k0, &lB[buf * BSZ + t * 8]);
    if (BN == 128) gld16(bg1 + k0, &lB[buf * BSZ + 2048 + t * 8]);
  };

  stage(0, 0);

  for (int kt = 0; kt < nt; kt++) {
    const int cur = kt & 1;
    if (kt + 1 < nt) {
      stage(cur ^ 1, kt + 1);  // next tile's loads stay in flight
      if constexpr (NLD == 4) {
        asm volatile("s_waitcnt vmcnt(4)" ::: "memory");  // tile kt landed
      } else {
        asm volatile("s_waitcnt vmcnt(3)" ::: "memory");
      }
    } else {
      asm volatile("s_waitcnt vmcnt(0)" ::: "memory");
    }
    __builtin_amdgcn_s_barrier();  // buf[cur] visible to all waves
    bf16x8 af[4], bfr[NJ];
#pragma unroll
    for (int i = 0; i < 4; i++)
      af[i] = *(const bf16x8*)&lA[cur * ASZ + (WR + i * 16 + l15) * 32 + lg * 8];
#pragma unroll
    for (int j = 0; j < NJ; j++)
      bfr[j] = *(const bf16x8*)&lB[cur * BSZ + (WC + j * 16 + l15) * 32 + lg * 8];
    asm volatile("s_waitcnt lgkmcnt(0)" ::: "memory");  // reads in regs
    __builtin_amdgcn_s_barrier();        // all waves done reading buf[cur]
    __builtin_amdgcn_sched_barrier(0);   // pin MFMA below (rule #18)
#pragma unroll
    for (int i = 0; i < 4; i++)
#pragma unroll
      for (int j = 0; j < NJ; j++)
        acc[i][j] = mfma16(af[i], bfr[j], acc[i][j]);  // overlaps t+1 loads
  }

  float* po = (KS == 2 && blockIdx.z == 1) ? po1 : po0;
  const int mr0 = m0 + WR + lg * 4;
  const int nc0 = n0 + WC + l15;
#pragma unroll
  for (int i = 0; i < 4; i++) {
    const int mr = mr0 + i * 16;  // s base (multiple of 4)
#pragma unroll
    for (int j = 0; j < NJ; j++) {
      const int nc = nc0 + j * 16;
      if (EPI == 0) {
        const int sel = nc >> 10;
        const int d = nc & 1023;
        const int h = d >> 6, dl = d & 63;
        const int kt2 = mr >> 5;
        if (sel == 2) {
          // Vp[h][kt][nb][lane(lgp*16+l15p)][el] ; lgp from s, l15p from d
          const int lgp = (mr >> 3) & 3, el0 = mr & 7;
          const int nb = dl >> 4, l15p = dl & 15;
          u16* dst = vo + (size_t)(h * 64 + kt2) * 2048 + nb * 512 +
                     (lgp * 16 + l15p) * 8 + el0;
          ushort4 o;
          o.x = f2bf(acc[i][j][0]); o.y = f2bf(acc[i][j][1]);
          o.z = f2bf(acc[i][j][2]); o.w = f2bf(acc[i][j][3]);
          *(ushort4*)dst = o;
        } else {
          // Qp/Kp[h][kt][f][kk][lane(lgp*16+l15p)][el] ; l15p from s (+e)
          const int f = (mr >> 4) & 1, l15p0 = mr & 15;
          const int kk = dl >> 5, lgp = (dl >> 3) & 3, el = dl & 7;
          u16* dst = (sel == 0 ? qo : ko) + (size_t)(h * 64 + kt2) * 2048 +
                     f * 1024 + kk * 512 + (lgp * 16 + l15p0) * 8 + el;
#pragma unroll
          for (int e = 0; e < 4; e++)
            dst[e * 8] = f2bf(acc[i][j][e]);
        }
      } else if (EPI == 2) {
        const float bb = bias[nc];
#pragma unroll
        for (int e = 0; e < 4; e++) {
          const float v = acc[i][j][e] + bb;
          const float g = 0.5f * v * (1.0f + tanhf(0.7978845608028654f * (v + 0.044715f * v * v * v)));
          outB[(size_t)(mr + e) * N + nc] = f2bf(g);
        }
      } else {
#pragma unroll
        for (int e = 0; e < 4; e++)
          po[(size_t)(mr + e) * N + nc] = acc[i][j][e];
      }
    }
  }
}

// ---------------- causal flash attention v4 ----------------------------------
// Qp/Kp/Vp are MFMA-fragment-packed: every fragment load is one coalesced 1-KB
// global_load_dwordx4 (lane l reads base + l*16B). Register-double-buffered
// K/V prefetch; exp2 no-max softmax; XCD-chunked swizzle; setprio on MFMA.
__device__ __forceinline__ void attn_load(
    bf16x8 (&kf)[2][2], bf16x8 (&vf)[4],
    const u16* __restrict__ Kp, const u16* __restrict__ Vp,
    int hkt, int l) {  // hkt = (h*64 + kt) * 2048
#pragma unroll
  for (int f = 0; f < 2; f++)
#pragma unroll
    for (int kk = 0; kk < 2; kk++)
      kf[kk][f] = *(const bf16x8*)(Kp + hkt + f * 1024 + kk * 512 + l * 8);
#pragma unroll
  for (int nb = 0; nb < 4; nb++)
    vf[nb] = *(const bf16x8*)(Vp + hkt + nb * 512 + l * 8);
}

__device__ __forceinline__ void attn_tile(
    const bf16x8 (&kf)[2][2], const bf16x8 (&vf)[4], const bf16x8 (&qf)[2][2],
    f32x4 (&accO)[2][4], float (&lsum)[2], u16* myP,
    int k0, bool diag, int qb, int l15, int lg) {
  f32x4 sv[2][2] = {};
  __builtin_amdgcn_s_setprio(1);
#pragma unroll
  for (int g = 0; g < 2; g++)
#pragma unroll
    for (int f = 0; f < 2; f++)
#pragma unroll
      for (int kk = 0; kk < 2; kk++)
        sv[g][f] = mfma16(kf[kk][f], qf[g][kk], sv[g][f]);
  __builtin_amdgcn_s_setprio(0);
  // sv[g][f][e] = score(q = qb+g*16+l15, k = k0+f*16+lg*4+e)
#pragma unroll
  for (int g = 0; g < 2; g++) {
#pragma unroll
    for (int f = 0; f < 2; f++) {
      bf16x4 pk;
      float ps = 0.f;
#pragma unroll
      for (int e = 0; e < 4; e++) {
        float p = exp2f(sv[g][f][e] * 0.1803368801f);  // exp(s/8)
        if (diag && (k0 + f * 16 + lg * 4 + e > qb + g * 16 + l15)) p = 0.f;
        ps += p;
        pk[e] = (bf16)p;
      }
      lsum[g] += ps;
      *(bf16x4*)(myP + g * 640 + l15 * 40 + f * 16 + lg * 4) = pk;
    }
  }
  const bf16x8 pf0 = *(const bf16x8*)(myP + l15 * 40 + lg * 8);
  const bf16x8 pf1 = *(const bf16x8*)(myP + 640 + l15 * 40 + lg * 8);
  __builtin_amdgcn_s_setprio(1);
#pragma unroll
  for (int nb = 0; nb < 4; nb++) {
    accO[0][nb] = mfma16(pf0, vf[nb], accO[0][nb]);
    accO[1][nb] = mfma16(pf1, vf[nb], accO[1][nb]);
  }
  __builtin_amdgcn_s_setprio(0);
}

__global__ __launch_bounds__(256)
void attn_fwd(const u16* __restrict__ Qp, const u16* __restrict__ Kp,
              const u16* __restrict__ Vp, u16* __restrict__ Ob) {
  __shared__ __attribute__((aligned(16))) char smem[33280];
  float* sO = (float*)smem;            // [4][2048] f32 (after barrier)
  float* sL = (float*)(smem + 32768);  // [4][32]
  u16* lP = (u16*)smem;                // [2 buf][4 waves][1280 u16] (pre-barrier)

  const int t = threadIdx.x;
  const int l = t & 63, w = t >> 6;
  const int l15 = l & 15, lg = l >> 4;
  // XCD-chunked swizzle: xcd = bid%8 gets contiguous 128 vb -> 2 heads/XCD
  const u32 bid = blockIdx.x;
  const u32 vb = (bid & 7) * 128 + (bid >> 3);
  const int h = (int)(vb >> 6);
  const int qt = 63 - (int)(vb & 63);  // LPT within chunk
  const int qb = qt * 32;

  u16* myPA = lP + w * 1280;
  u16* myPB = lP + 5120 + w * 1280;

  bf16x8 qf[2][2];
#pragma unroll
  for (int g = 0; g < 2; g++)
#pragma unroll
    for (int kk = 0; kk < 2; kk++)
      qf[g][kk] = *(const bf16x8*)(Qp + (size_t)(h * 64 + qt) * 2048 +
                                   g * 1024 + kk * 512 + l * 8);

  f32x4 accO[2][4] = {};
  float lsum[2] = {0.f, 0.f};

  if (w <= qt) {
    const int hb = h * 64;
    bf16x8 kfA[2][2], vfA[4], kfB[2][2], vfB[4];
    attn_load(kfA, vfA, Kp, Vp, (hb + w) * 2048, l);
    int kt = w;
    while (true) {
      const int ktB = kt + 4;
      const bool hasB = (ktB <= qt);
      attn_load(kfB, vfB, Kp, Vp, (hb + (hasB ? ktB : kt)) * 2048, l);
      attn_tile(kfA, vfA, qf, accO, lsum, myPA, kt * 32, kt == qt, qb, l15, lg);
      if (!hasB) break;
      const int ktA = kt + 8;
      const bool hasA = (ktA <= qt);
      attn_load(kfA, vfA, Kp, Vp, (hb + (hasA ? ktA : ktB)) * 2048, l);
      attn_tile(kfB, vfB, qf, accO, lsum, myPB, ktB * 32, ktB == qt, qb, l15, lg);
      if (!hasA) break;
      kt = ktA;
    }
  }

  float lsr[2];
#pragma unroll
  for (int g = 0; g < 2; g++) {
    float v = lsum[g];
    v += __shfl_xor(v, 16);
    v += __shfl_xor(v, 32);
    lsr[g] = v;
  }

  __syncthreads();  // all waves done with lP; smem becomes sO
#pragma unroll
  for (int g = 0; g < 2; g++) {
#pragma unroll
    for (int nb = 0; nb < 4; nb++)
#pragma unroll
      for (int e = 0; e < 4; e++)
        sO[w * 2048 + (g * 16 + lg * 4 + e) * 64 + nb * 16 + l15] = accO[g][nb][e];
    if (lg == 0) sL[w * 32 + g * 16 + l15] = lsr[g];
  }
  __syncthreads();

  const int base = t * 8;
  const int row = base >> 6;
  const int col = base & 63;
  f32x4 a0 = {}, a1 = {};
  float ls = 0.f;
#pragma unroll
  for (int ww = 0; ww < 4; ww++) {
    a0 += *(const f32x4*)&sO[ww * 2048 + base];
    a1 += *(const f32x4*)&sO[ww * 2048 + base + 4];
    ls += sL[ww * 32 + row];
  }
  const float rinv = 1.0f / ls;
  u16x8 o;
#pragma unroll
  for (int j = 0; j < 4; j++) {
    o[j] = f2bf(a0[j] * rinv);
    o[4 + j] = f2bf(a1[j] * rinv);
  }
  *(u16x8*)(Ob + (size_t)(qb + row) * 1024 + h * 64 + col) = o;
}

// ---------------- launch ----------------------------------------------------
extern "C" void kernel_launch(void* const* d_in, const int* in_sizes, int n_in,
                              void* d_out, int out_size, void* d_ws, size_t ws_size,
                              hipStream_t stream) {
  const float* x     = (const float*)d_in[0];
  const float* W_qkv = (const float*)d_in[1];
  const float* W_o   = (const float*)d_in[2];
  const float* W1    = (const float*)d_in[3];
  const float* b1    = (const float*)d_in[4];
  const float* W2    = (const float*)d_in[5];
  const float* b2    = (const float*)d_in[6];
  const float* ln_aw = (const float*)d_in[7];
  const float* ln_ab = (const float*)d_in[8];
  const float* ln_mw = (const float*)d_in[9];
  const float* ln_mb = (const float*)d_in[10];

  // workspace layout (lifetime-aliased; peak 70.5 MB):
  char* ws = (char*)d_ws;
  u16* Wqkv_t = (u16*)(ws);                  // [3072][1024] bf16   6 MB  persistent
  u16* Wo_t   = (u16*)(ws + 6291456);        // [1024][1024]        2 MB  persistent
  u16* W1_t   = (u16*)(ws + 8388608);        // [4096][1024]        8 MB  persistent
  u16* W2_t   = (u16*)(ws + 16777216);       // [1024][4096]        8 MB  persistent
  u16* h1     = (u16*)(ws + 25165824);       // [2048][1024]        4 MB  (h2 aliases)
  u16* h2     = h1;                          //                     dead-by-then alias
  u16* Qp     = (u16*)(ws + 29360128);       // frag-packed Q       4 MB
  u16* Kp     = (u16*)(ws + 33554432);       // frag-packed K       4 MB
  u16* Vp     = (u16*)(ws + 37748736);       // frag-packed V       4 MB
  u16* attnb  = (u16*)(ws + 41943040);       // [2048][1024]        4 MB
  u16* ffb    = (u16*)(ws + 29360128);       // [2048][4096]       16 MB  aliases Qp..attnb (dead)
  float* p0   = (float*)(ws + 46137344);     // [2048][1024] f32    8 MB  split-K partial
  float* p1   = (float*)(ws + 54525952);     // [2048][1024] f32    8 MB  split-K partial
  float* x2   = (float*)(ws + 62914560);     // [2048][1024] f32    8 MB
  (void)ws_size; (void)in_sizes; (void)n_in; (void)out_size;

  wconv_all<<<3072, 256, 0, stream>>>(W_qkv, W_o, W1, W2, Wqkv_t, Wo_t, W1_t, W2_t);

  ln_bf16<<<2048, 256, 0, stream>>>(x, ln_aw, ln_ab, h1);

  // QKV: 128x128 tiles -> 384 blocks
  gemm_bf16<128, 128, 0, 1><<<dim3(24, 16), 256, 0, stream>>>(
      h1, Wqkv_t, 2048, 3072, 1024, nullptr, nullptr, nullptr, nullptr, Qp, Kp, Vp);

  attn_fwd<<<1024, 256, 0, stream>>>(Qp, Kp, Vp, attnb);

  // W_o: 64x128 tiles, split-K=2 -> 512 blocks (2/CU)
  gemm_bf16<64, 128, 4, 2><<<dim3(8, 32, 2), 256, 0, stream>>>(
      attnb, Wo_t, 2048, 1024, 1024, nullptr, p0, p1, nullptr, nullptr, nullptr, nullptr);

  reduce_ln<<<2048, 256, 0, stream>>>(x, p0, p1, ln_mw, ln_mb, x2, h2);

  // FF1: 128x128 tiles -> 512 blocks (2/CU)
  gemm_bf16<128, 128, 2, 1><<<dim3(32, 16), 256, 0, stream>>>(
      h2, W1_t, 2048, 4096, 1024, b1, nullptr, nullptr, ffb, nullptr, nullptr, nullptr);

  // FF2: 64x128 tiles, split-K=2 -> 512 blocks (2/CU)
  gemm_bf16<64, 128, 4, 2><<<dim3(8, 32, 2), 256, 0, stream>>>(
      ffb, W2_t, 2048, 1024, 4096, nullptr, p0, p1, nullptr, nullptr, nullptr, nullptr);

  reduce_out<<<2048, 256, 0, stream>>>(x2, b2, p0, p1, (float*)d_out);
}

// Round 8
// 167.578 us; speedup vs baseline: 1.9371x; 1.0140x over previous
//
#include <hip/hip_runtime.h>
#include <math.h>

typedef __bf16 bf16;
typedef __bf16 bf16x4 __attribute__((ext_vector_type(4)));
typedef __bf16 bf16x8 __attribute__((ext_vector_type(8)));
typedef float f32x4 __attribute__((ext_vector_type(4)));
typedef unsigned short u16;
typedef unsigned short u16x8 __attribute__((ext_vector_type(8)));
typedef unsigned int u32;

__device__ __forceinline__ u16 f2bf(float f) {
  union { float f; u32 u; } v; v.f = f;
  u32 u = v.u;
  return (u16)((u + 0x7FFFu + ((u >> 16) & 1u)) >> 16);
}

__device__ __forceinline__ f32x4 mfma16(bf16x8 a, bf16x8 b, f32x4 c) {
  return __builtin_amdgcn_mfma_f32_16x16x32_bf16(a, b, c, 0, 0, 0);
}

__device__ __forceinline__ void gld16(const void* g, void* l) {
  __builtin_amdgcn_global_load_lds(
      (const __attribute__((address_space(1))) void*)(void*)g,
      (__attribute__((address_space(3))) void*)l,
      16, 0, 0);
}

// ---------------- weight fp32 -> bf16 transpose (Wt[n][k] = W[k][n]) ----------
__device__ __forceinline__ void wconv_body(const float* __restrict__ W,
                                           u16* __restrict__ Wt, int K, int N,
                                           int bx, int by) {
  __shared__ float tile[64][65];
  const int k0 = by * 64, n0 = bx * 64;
  const int t = threadIdx.x;
  const int tr = t >> 4;
  const int tc = (t & 15) * 4;
#pragma unroll
  for (int it = 0; it < 4; it++) {
    const int r = tr + it * 16;
    const float4 v = *(const float4*)(W + (size_t)(k0 + r) * N + n0 + tc);
    tile[r][tc] = v.x; tile[r][tc + 1] = v.y; tile[r][tc + 2] = v.z; tile[r][tc + 3] = v.w;
  }
  __syncthreads();
#pragma unroll
  for (int it = 0; it < 4; it++) {
    const int rn = tr + it * 16;
    ushort4 o;
    o.x = f2bf(tile[tc][rn]);
    o.y = f2bf(tile[tc + 1][rn]);
    o.z = f2bf(tile[tc + 2][rn]);
    o.w = f2bf(tile[tc + 3][rn]);
    *(ushort4*)(Wt + (size_t)(n0 + rn) * K + k0 + tc) = o;
  }
}

__global__ __launch_bounds__(256)
void wconv_all(const float* __restrict__ Wqkv, const float* __restrict__ Wo,
               const float* __restrict__ W1, const float* __restrict__ W2,
               u16* __restrict__ Wqkv_t, u16* __restrict__ Wo_t,
               u16* __restrict__ W1_t, u16* __restrict__ W2_t) {
  const int id = blockIdx.x;  // uniform per block
  if (id < 768)       { wconv_body(Wqkv, Wqkv_t, 1024, 3072, id % 48, id / 48); }
  else if (id < 1024) { const int j = id - 768;  wconv_body(Wo, Wo_t, 1024, 1024, j % 16, j / 16); }
  else if (id < 2048) { const int j = id - 1024; wconv_body(W1, W1_t, 1024, 4096, j % 64, j / 64); }
  else                { const int j = id - 2048; wconv_body(W2, W2_t, 4096, 1024, j % 16, j / 16); }
}

// ---------------- LayerNorm (fp32 in -> bf16 out) ----------------------------
__global__ __launch_bounds__(256)
void ln_bf16(const float* __restrict__ x, const float* __restrict__ w,
             const float* __restrict__ b, u16* __restrict__ out) {
  const int row = blockIdx.x;
  const int t = threadIdx.x;
  const float4 v = *(const float4*)(x + (size_t)row * 1024 + t * 4);
  float s = v.x + v.y + v.z + v.w;
  float s2 = v.x * v.x + v.y * v.y + v.z * v.z + v.w * v.w;
#pragma unroll
  for (int m = 1; m < 64; m <<= 1) {
    s += __shfl_xor(s, m);
    s2 += __shfl_xor(s2, m);
  }
  __shared__ float red[8];
  if ((t & 63) == 0) { red[t >> 6] = s; red[4 + (t >> 6)] = s2; }
  __syncthreads();
  s = red[0] + red[1] + red[2] + red[3];
  s2 = red[4] + red[5] + red[6] + red[7];
  const float mu = s * (1.f / 1024.f);
  const float var = fmaxf(s2 * (1.f / 1024.f) - mu * mu, 0.f);
  const float rstd = rsqrtf(var + 1e-5f);
  const float* wp = w + t * 4;
  const float* bp = b + t * 4;
  ushort4 o;
  o.x = f2bf((v.x - mu) * rstd * wp[0] + bp[0]);
  o.y = f2bf((v.y - mu) * rstd * wp[1] + bp[1]);
  o.z = f2bf((v.z - mu) * rstd * wp[2] + bp[2]);
  o.w = f2bf((v.w - mu) * rstd * wp[3] + bp[3]);
  *(ushort4*)(out + (size_t)row * 1024 + t * 4) = o;
}

// ---------------- fused: x2 = x + p0 + p1 ; h2 = LN(x2) ----------------------
__global__ __launch_bounds__(256)
void reduce_ln(const float* __restrict__ x, const float* __restrict__ p0,
               const float* __restrict__ p1, const float* __restrict__ w,
               const float* __restrict__ b, float* __restrict__ x2,
               u16* __restrict__ h2) {
  const int row = blockIdx.x;
  const int t = threadIdx.x;
  const size_t base = (size_t)row * 1024 + t * 4;
  float4 v = *(const float4*)(x + base);
  const float4 a = *(const float4*)(p0 + base);
  const float4 c = *(const float4*)(p1 + base);
  v.x += a.x + c.x; v.y += a.y + c.y; v.z += a.z + c.z; v.w += a.w + c.w;
  *(float4*)(x2 + base) = v;
  float s = v.x + v.y + v.z + v.w;
  float s2 = v.x * v.x + v.y * v.y + v.z * v.z + v.w * v.w;
#pragma unroll
  for (int m = 1; m < 64; m <<= 1) {
    s += __shfl_xor(s, m);
    s2 += __shfl_xor(s2, m);
  }
  __shared__ float red[8];
  if ((t & 63) == 0) { red[t >> 6] = s; red[4 + (t >> 6)] = s2; }
  __syncthreads();
  s = red[0] + red[1] + red[2] + red[3];
  s2 = red[4] + red[5] + red[6] + red[7];
  const float mu = s * (1.f / 1024.f);
  const float var = fmaxf(s2 * (1.f / 1024.f) - mu * mu, 0.f);
  const float rstd = rsqrtf(var + 1e-5f);
  const float* wp = w + t * 4;
  const float* bp = b + t * 4;
  ushort4 o;
  o.x = f2bf((v.x - mu) * rstd * wp[0] + bp[0]);
  o.y = f2bf((v.y - mu) * rstd * wp[1] + bp[1]);
  o.z = f2bf((v.z - mu) * rstd * wp[2] + bp[2]);
  o.w = f2bf((v.w - mu) * rstd * wp[3] + bp[3]);
  *(ushort4*)(h2 + base) = o;
}

// ---------------- fused: out = x2 + bias + p0 + p1 ---------------------------
__global__ __launch_bounds__(256)
void reduce_out(const float* __restrict__ x2, const float* __restrict__ bias,
                const float* __restrict__ p0, const float* __restrict__ p1,
                float* __restrict__ out) {
  const size_t base = ((size_t)blockIdx.x * 256 + threadIdx.x) * 4;
  const int col = (int)(base & 1023);
  float4 v = *(const float4*)(x2 + base);
  const float4 a = *(const float4*)(p0 + base);
  const float4 c = *(const float4*)(p1 + base);
  const float4 bb = *(const float4*)(bias + col);
  v.x += a.x + c.x + bb.x;
  v.y += a.y + c.y + bb.y;
  v.z += a.z + c.z + bb.z;
  v.w += a.w + c.w + bb.w;
  *(float4*)(out + base) = v;
}

// ---------------- bf16 GEMM, BMxBN, BK=32, reg-pipelined 4-buf schedule ------
// A: [M][K] bf16 row-major; Bt: [N][K] bf16 (B transposed). fp32 accum.
// Per iter t: stage(t+2) -> vmcnt(NLD) [stage(t+1) landed; t+2 in flight] ->
// s_barrier -> ds_read frags(t+1) -> regs -> lgkmcnt(NFR) [frags(t) complete;
// frags(t+1) in flight] -> sched_barrier -> MFMA(t). One barrier per iter;
// 4 LDS buffers make the skew safe (write t+4 is >=2 barriers after reads of
// t-2 finish). ds_read latency and stage latency both hide under MFMA.
template <int BM, int BN, int EPI, int KS>
__global__ __launch_bounds__(256)
void gemm_bf16(const u16* __restrict__ A, const u16* __restrict__ Bt,
               int M, int N, int K,
               const float* __restrict__ bias,
               float* __restrict__ po0, float* __restrict__ po1,
               u16* __restrict__ outB,
               u16* __restrict__ qo, u16* __restrict__ ko, u16* __restrict__ vo) {
  constexpr int ASZ = BM * 32;
  constexpr int BSZ = BN * 32;
  constexpr int NLD = (BM == 128 ? 2 : 1) + (BN == 128 ? 2 : 1);
  constexpr int NJ = (BM == 128 && BN == 128) ? 4 : 2;
  constexpr int NFR = 4 + NJ;  // ds_read_b128 per wave per tile
  __shared__ __attribute__((aligned(16))) u16 lA[4 * ASZ];
  __shared__ __attribute__((aligned(16))) u16 lB[4 * BSZ];
  const int t = threadIdx.x;
  const int l = t & 63;
  const int w = t >> 6;
  const int WR = (BM == 128) ? (w >> 1) * 64 : 0;
  const int WC = (BM == 128) ? ((BN == 128) ? (w & 1) * 64 : (w & 1) * 32)
                             : w * 32;
  const int l15 = l & 15, lg = l >> 4;

  // XCD-chunked swizzle (requires gridDim.x % 8 == 0; true at all call sites)
  const int nx = gridDim.x;
  const u32 bid = blockIdx.y * nx + blockIdx.x;
  const int nxc = nx >> 3;
  const u32 r = bid >> 3;
  const int bx = (bid & 7) * nxc + (int)(r % (u32)nxc);
  const int by = (int)(r / (u32)nxc);

  const int m0 = by * BM, n0 = bx * BN;
  const int KC = K / KS;
  const int kbase = blockIdx.z * KC;

  f32x4 acc[4][NJ] = {};

  const int lr = t >> 2;
  const int lc = ((t & 3) << 3) + kbase;
  const u16* ag0 = A + (size_t)(m0 + lr) * K + lc;
  const u16* ag1 = A + (size_t)(m0 + 64 + lr) * K + lc;
  const u16* bg0 = Bt + (size_t)(n0 + lr) * K + lc;
  const u16* bg1 = Bt + (size_t)(n0 + 64 + lr) * K + lc;

  const int nt = KC / 32;  // even at all call sites (>=16)
  auto stage = [&](int buf, int kt) {  // NLD gld16 per call
    const int k0 = kt * 32;
    gld16(ag0 + k0, &lA[buf * ASZ + t * 8]);
    if (BM == 128) gld16(ag1 + k0, &lA[buf * ASZ + 2048 + t * 8]);
    gld16(bg0 + k0, &lB[buf * BSZ + t * 8]);
    if (BN == 128) gld16(bg1 + k0, &lB[buf * BSZ + 2048 + t * 8]);
  };
  auto ldfrag = [&](int buf, bf16x8 (&af)[4], bf16x8 (&bf_)[NJ]) {
#pragma unroll
    for (int i = 0; i < 4; i++)
      af[i] = *(const bf16x8*)&lA[buf * ASZ + (WR + i * 16 + l15) * 32 + lg * 8];
#pragma unroll
    for (int j = 0; j < NJ; j++)
      bf_[j] = *(const bf16x8*)&lB[buf * BSZ + (WC + j * 16 + l15) * 32 + lg * 8];
  };
  auto body = [&](int ti, bf16x8 (&afc)[4], bf16x8 (&bfc)[NJ],
                  bf16x8 (&afn)[4], bf16x8 (&bfn)[NJ]) {
    if (ti + 2 < nt) {
      stage((ti + 2) & 3, ti + 2);
      if constexpr (NLD == 4) asm volatile("s_waitcnt vmcnt(4)" ::: "memory");
      else                    asm volatile("s_waitcnt vmcnt(3)" ::: "memory");
    } else {
      asm volatile("s_waitcnt vmcnt(0)" ::: "memory");
    }
    __builtin_amdgcn_s_barrier();  // stage(ti+1) visible to all waves
    if (ti + 1 < nt) {
      ldfrag((ti + 1) & 3, afn, bfn);  // issue; completes during MFMA
      if constexpr (NFR == 8) asm volatile("s_waitcnt lgkmcnt(8)" ::: "memory");
      else                    asm volatile("s_waitcnt lgkmcnt(6)" ::: "memory");
    } else {
      asm volatile("s_waitcnt lgkmcnt(0)" ::: "memory");
    }
    __builtin_amdgcn_sched_barrier(0);  // rule #18: pin MFMA below lgkm wait
#pragma unroll
    for (int i = 0; i < 4; i++)
#pragma unroll
      for (int j = 0; j < NJ; j++)
        acc[i][j] = mfma16(afc[i], bfc[j], acc[i][j]);
  };

  // prologue: two tiles staged, tile0 fragments issued
  stage(0, 0);
  stage(1, 1);
  if constexpr (NLD == 4) asm volatile("s_waitcnt vmcnt(4)" ::: "memory");
  else                    asm volatile("s_waitcnt vmcnt(3)" ::: "memory");
  __builtin_amdgcn_s_barrier();
  bf16x8 afA[4], bfA[NJ], afB[4], bfB[NJ];
  ldfrag(0, afA, bfA);

  for (int ti = 0; ti < nt; ti += 2) {
    body(ti, afA, bfA, afB, bfB);
    body(ti + 1, afB, bfB, afA, bfA);
  }

  float* po = (KS == 2 && blockIdx.z == 1) ? po1 : po0;
  const int mr0 = m0 + WR + lg * 4;
  const int nc0 = n0 + WC + l15;
#pragma unroll
  for (int i = 0; i < 4; i++) {
    const int mr = mr0 + i * 16;  // s base (multiple of 4)
#pragma unroll
    for (int j = 0; j < NJ; j++) {
      const int nc = nc0 + j * 16;
      if (EPI == 0) {
        const int sel = nc >> 10;
        const int d = nc & 1023;
        const int h = d >> 6, dl = d & 63;
        const int kt2 = mr >> 5;
        if (sel == 2) {
          // Vp[h][kt][nb][lane(lgp*16+l15p)][el] ; lgp from s, l15p from d
          const int lgp = (mr >> 3) & 3, el0 = mr & 7;
          const int nb = dl >> 4, l15p = dl & 15;
          u16* dst = vo + (size_t)(h * 64 + kt2) * 2048 + nb * 512 +
                     (lgp * 16 + l15p) * 8 + el0;
          ushort4 o;
          o.x = f2bf(acc[i][j][0]); o.y = f2bf(acc[i][j][1]);
          o.z = f2bf(acc[i][j][2]); o.w = f2bf(acc[i][j][3]);
          *(ushort4*)dst = o;
        } else {
          // Qp/Kp[h][kt][f][kk][lane(lgp*16+l15p)][el] ; l15p from s (+e)
          const int f = (mr >> 4) & 1, l15p0 = mr & 15;
          const int kk = dl >> 5, lgp = (dl >> 3) & 3, el = dl & 7;
          u16* dst = (sel == 0 ? qo : ko) + (size_t)(h * 64 + kt2) * 2048 +
                     f * 1024 + kk * 512 + (lgp * 16 + l15p0) * 8 + el;
#pragma unroll
          for (int e = 0; e < 4; e++)
            dst[e * 8] = f2bf(acc[i][j][e]);
        }
      } else if (EPI == 2) {
        const float bb = bias[nc];
#pragma unroll
        for (int e = 0; e < 4; e++) {
          const float v = acc[i][j][e] + bb;
          const float g = 0.5f * v * (1.0f + tanhf(0.7978845608028654f * (v + 0.044715f * v * v * v)));
          outB[(size_t)(mr + e) * N + nc] = f2bf(g);
        }
      } else {
#pragma unroll
        for (int e = 0; e < 4; e++)
          po[(size_t)(mr + e) * N + nc] = acc[i][j][e];
      }
    }
  }
}

// ---------------- causal flash attention v4 ----------------------------------
// Qp/Kp/Vp are MFMA-fragment-packed: every fragment load is one coalesced 1-KB
// global_load_dwordx4 (lane l reads base + l*16B). Register-double-buffered
// K/V prefetch; exp2 no-max softmax; XCD-chunked swizzle; setprio on MFMA.
__device__ __forceinline__ void attn_load(
    bf16x8 (&kf)[2][2], bf16x8 (&vf)[4],
    const u16* __restrict__ Kp, const u16* __restrict__ Vp,
    int hkt, int l) {  // hkt = (h*64 + kt) * 2048
#pragma unroll
  for (int f = 0; f < 2; f++)
#pragma unroll
    for (int kk = 0; kk < 2; kk++)
      kf[kk][f] = *(const bf16x8*)(Kp + hkt + f * 1024 + kk * 512 + l * 8);
#pragma unroll
  for (int nb = 0; nb < 4; nb++)
    vf[nb] = *(const bf16x8*)(Vp + hkt + nb * 512 + l * 8);
}

__device__ __forceinline__ void attn_tile(
    const bf16x8 (&kf)[2][2], const bf16x8 (&vf)[4], const bf16x8 (&qf)[2][2],
    f32x4 (&accO)[2][4], float (&lsum)[2], u16* myP,
    int k0, bool diag, int qb, int l15, int lg) {
  f32x4 sv[2][2] = {};
  __builtin_amdgcn_s_setprio(1);
#pragma unroll
  for (int g = 0; g < 2; g++)
#pragma unroll
    for (int f = 0; f < 2; f++)
#pragma unroll
      for (int kk = 0; kk < 2; kk++)
        sv[g][f] = mfma16(kf[kk][f], qf[g][kk], sv[g][f]);
  __builtin_amdgcn_s_setprio(0);
  // sv[g][f][e] = score(q = qb+g*16+l15, k = k0+f*16+lg*4+e)
#pragma unroll
  for (int g = 0; g < 2; g++) {
#pragma unroll
    for (int f = 0; f < 2; f++) {
      bf16x4 pk;
      float ps = 0.f;
#pragma unroll
      for (int e = 0; e < 4; e++) {
        float p = exp2f(sv[g][f][e] * 0.1803368801f);  // exp(s/8)
        if (diag && (k0 + f * 16 + lg * 4 + e > qb + g * 16 + l15)) p = 0.f;
        ps += p;
        pk[e] = (bf16)p;
      }
      lsum[g] += ps;
      *(bf16x4*)(myP + g * 640 + l15 * 40 + f * 16 + lg * 4) = pk;
    }
  }
  const bf16x8 pf0 = *(const bf16x8*)(myP + l15 * 40 + lg * 8);
  const bf16x8 pf1 = *(const bf16x8*)(myP + 640 + l15 * 40 + lg * 8);
  __builtin_amdgcn_s_setprio(1);
#pragma unroll
  for (int nb = 0; nb < 4; nb++) {
    accO[0][nb] = mfma16(pf0, vf[nb], accO[0][nb]);
    accO[1][nb] = mfma16(pf1, vf[nb], accO[1][nb]);
  }
  __builtin_amdgcn_s_setprio(0);
}

__global__ __launch_bounds__(256)
void attn_fwd(const u16* __restrict__ Qp, const u16* __restrict__ Kp,
              const u16* __restrict__ Vp, u16* __restrict__ Ob) {
  __shared__ __attribute__((aligned(16))) char smem[33280];
  float* sO = (float*)smem;            // [4][2048] f32 (after barrier)
  float* sL = (float*)(smem + 32768);  // [4][32]
  u16* lP = (u16*)smem;                // [2 buf][4 waves][1280 u16] (pre-barrier)

  const int t = threadIdx.x;
  const int l = t & 63, w = t >> 6;
  const int l15 = l & 15, lg = l >> 4;
  // XCD-chunked swizzle: xcd = bid%8 gets contiguous 128 vb -> 2 heads/XCD
  const u32 bid = blockIdx.x;
  const u32 vb = (bid & 7) * 128 + (bid >> 3);
  const int h = (int)(vb >> 6);
  const int qt = 63 - (int)(vb & 63);  // LPT within chunk
  const int qb = qt * 32;

  u16* myPA = lP + w * 1280;
  u16* myPB = lP + 5120 + w * 1280;

  bf16x8 qf[2][2];
#pragma unroll
  for (int g = 0; g < 2; g++)
#pragma unroll
    for (int kk = 0; kk < 2; kk++)
      qf[g][kk] = *(const bf16x8*)(Qp + (size_t)(h * 64 + qt) * 2048 +
                                   g * 1024 + kk * 512 + l * 8);

  f32x4 accO[2][4] = {};
  float lsum[2] = {0.f, 0.f};

  if (w <= qt) {
    const int hb = h * 64;
    bf16x8 kfA[2][2], vfA[4], kfB[2][2], vfB[4];
    attn_load(kfA, vfA, Kp, Vp, (hb + w) * 2048, l);
    int kt = w;
    while (true) {
      const int ktB = kt + 4;
      const bool hasB = (ktB <= qt);
      attn_load(kfB, vfB, Kp, Vp, (hb + (hasB ? ktB : kt)) * 2048, l);
      attn_tile(kfA, vfA, qf, accO, lsum, myPA, kt * 32, kt == qt, qb, l15, lg);
      if (!hasB) break;
      const int ktA = kt + 8;
      const bool hasA = (ktA <= qt);
      attn_load(kfA, vfA, Kp, Vp, (hb + (hasA ? ktA : ktB)) * 2048, l);
      attn_tile(kfB, vfB, qf, accO, lsum, myPB, ktB * 32, ktB == qt, qb, l15, lg);
      if (!hasA) break;
      kt = ktA;
    }
  }

  float lsr[2];
#pragma unroll
  for (int g = 0; g < 2; g++) {
    float v = lsum[g];
    v += __shfl_xor(v, 16);
    v += __shfl_xor(v, 32);
    lsr[g] = v;
  }

  __syncthreads();  // all waves done with lP; smem becomes sO
#pragma unroll
  for (int g = 0; g < 2; g++) {
#pragma unroll
    for (int nb = 0; nb < 4; nb++)
#pragma unroll
      for (int e = 0; e < 4; e++)
        sO[w * 2048 + (g * 16 + lg * 4 + e) * 64 + nb * 16 + l15] = accO[g][nb][e];
    if (lg == 0) sL[w * 32 + g * 16 + l15] = lsr[g];
  }
  __syncthreads();

  const int base = t * 8;
  const int row = base >> 6;
  const int col = base & 63;
  f32x4 a0 = {}, a1 = {};
  float ls = 0.f;
#pragma unroll
  for (int ww = 0; ww < 4; ww++) {
    a0 += *(const f32x4*)&sO[ww * 2048 + base];
    a1 += *(const f32x4*)&sO[ww * 2048 + base + 4];
    ls += sL[ww * 32 + row];
  }
  const float rinv = 1.0f / ls;
  u16x8 o;
#pragma unroll
  for (int j = 0; j < 4; j++) {
    o[j] = f2bf(a0[j] * rinv);
    o[4 + j] = f2bf(a1[j] * rinv);
  }
  *(u16x8*)(Ob + (size_t)(qb + row) * 1024 + h * 64 + col) = o;
}

// ---------------- launch ----------------------------------------------------
extern "C" void kernel_launch(void* const* d_in, const int* in_sizes, int n_in,
                              void* d_out, int out_size, void* d_ws, size_t ws_size,
                              hipStream_t stream) {
  const float* x     = (const float*)d_in[0];
  const float* W_qkv = (const float*)d_in[1];
  const float* W_o   = (const float*)d_in[2];
  const float* W1    = (const float*)d_in[3];
  const float* b1    = (const float*)d_in[4];
  const float* W2    = (const float*)d_in[5];
  const float* b2    = (const float*)d_in[6];
  const float* ln_aw = (const float*)d_in[7];
  const float* ln_ab = (const float*)d_in[8];
  const float* ln_mw = (const float*)d_in[9];
  const float* ln_mb = (const float*)d_in[10];

  // workspace layout (lifetime-aliased; peak 70.5 MB):
  char* ws = (char*)d_ws;
  u16* Wqkv_t = (u16*)(ws);                  // [3072][1024] bf16   6 MB  persistent
  u16* Wo_t   = (u16*)(ws + 6291456);        // [1024][1024]        2 MB  persistent
  u16* W1_t   = (u16*)(ws + 8388608);        // [4096][1024]        8 MB  persistent
  u16* W2_t   = (u16*)(ws + 16777216);       // [1024][4096]        8 MB  persistent
  u16* h1     = (u16*)(ws + 25165824);       // [2048][1024]        4 MB  (h2 aliases)
  u16* h2     = h1;                          //                     dead-by-then alias
  u16* Qp     = (u16*)(ws + 29360128);       // frag-packed Q       4 MB
  u16* Kp     = (u16*)(ws + 33554432);       // frag-packed K       4 MB
  u16* Vp     = (u16*)(ws + 37748736);       // frag-packed V       4 MB
  u16* attnb  = (u16*)(ws + 41943040);       // [2048][1024]        4 MB
  u16* ffb    = (u16*)(ws + 29360128);       // [2048][4096]       16 MB  aliases Qp..attnb (dead)
  float* p0   = (float*)(ws + 46137344);     // [2048][1024] f32    8 MB  split-K partial
  float* p1   = (float*)(ws + 54525952);     // [2048][1024] f32    8 MB  split-K partial
  float* x2   = (float*)(ws + 62914560);     // [2048][1024] f32    8 MB
  (void)ws_size; (void)in_sizes; (void)n_in; (void)out_size;

  wconv_all<<<3072, 256, 0, stream>>>(W_qkv, W_o, W1, W2, Wqkv_t, Wo_t, W1_t, W2_t);

  ln_bf16<<<2048, 256, 0, stream>>>(x, ln_aw, ln_ab, h1);

  // QKV: 128x128 tiles -> 384 blocks
  gemm_bf16<128, 128, 0, 1><<<dim3(24, 16), 256, 0, stream>>>(
      h1, Wqkv_t, 2048, 3072, 1024, nullptr, nullptr, nullptr, nullptr, Qp, Kp, Vp);

  attn_fwd<<<1024, 256, 0, stream>>>(Qp, Kp, Vp, attnb);

  // W_o: 64x128 tiles, split-K=2 -> 512 blocks (2/CU)
  gemm_bf16<64, 128, 4, 2><<<dim3(8, 32, 2), 256, 0, stream>>>(
      attnb, Wo_t, 2048, 1024, 1024, nullptr, p0, p1, nullptr, nullptr, nullptr, nullptr);

  reduce_ln<<<2048, 256, 0, stream>>>(x, p0, p1, ln_mw, ln_mb, x2, h2);

  // FF1: 128x128 tiles -> 512 blocks (2/CU)
  gemm_bf16<128, 128, 2, 1><<<dim3(32, 16), 256, 0, stream>>>(
      h2, W1_t, 2048, 4096, 1024, b1, nullptr, nullptr, ffb, nullptr, nullptr, nullptr);

  // FF2: 64x128 tiles, split-K=2 -> 512 blocks (2/CU)
  gemm_bf16<64, 128, 4, 2><<<dim3(8, 32, 2), 256, 0, stream>>>(
      ffb, W2_t, 2048, 1024, 4096, nullptr, p0, p1, nullptr, nullptr, nullptr, nullptr);

  reduce_out<<<2048, 256, 0, stream>>>(x2, b2, p0, p1, (float*)d_out);
}

// Round 9
// 151.412 us; speedup vs baseline: 2.1439x; 1.1068x over previous
//
#include <hip/hip_runtime.h>
#include <math.h>

typedef __bf16 bf16;
typedef __bf16 bf16x4 __attribute__((ext_vector_type(4)));
typedef __bf16 bf16x8 __attribute__((ext_vector_type(8)));
typedef float f32x4 __attribute__((ext_vector_type(4)));
typedef unsigned short u16;
typedef unsigned short u16x8 __attribute__((ext_vector_type(8)));
typedef unsigned int u32;

__device__ __forceinline__ u16 f2bf(float f) {
  union { float f; u32 u; } v; v.f = f;
  u32 u = v.u;
  return (u16)((u + 0x7FFFu + ((u >> 16) & 1u)) >> 16);
}
__device__ __forceinline__ float bf2f(u16 u) {
  union { u32 u; float f; } v; v.u = (u32)u << 16;
  return v.f;
}

__device__ __forceinline__ f32x4 mfma16(bf16x8 a, bf16x8 b, f32x4 c) {
  return __builtin_amdgcn_mfma_f32_16x16x32_bf16(a, b, c, 0, 0, 0);
}

// Generic MFMA-fragment-packed layout for a [R][C] bf16 matrix consumed as
// 16-row x 32-col fragments:
//   addr(r,c) = ((r>>4)*(C>>5) + (c>>5))*512 + ((c>>3)&3)*128 + (r&15)*8 + (c&7)
// Consumer: lane l of a wave reads 16B at fragbase + l*16B -> one coalesced
// 1-KB global_load_dwordx4 per fragment.
__device__ __forceinline__ size_t pk_addr(int r, int c, int C) {
  return ((size_t)(r >> 4) * (C >> 5) + (c >> 5)) * 512 +
         ((c >> 3) & 3) * 128 + (r & 15) * 8 + (c & 7);
}

// ---------------- weight fp32 -> bf16 frag-packed transpose ------------------
// Wt_packed holds Bt[n][k] (= W[k][n]) in pk layout with R=N rows, C=K cols.
__device__ __forceinline__ void wconv_body(const float* __restrict__ W,
                                           u16* __restrict__ Wt, int K, int N,
                                           int bx, int by) {
  __shared__ float tile[64][65];
  const int k0 = by * 64, n0 = bx * 64;
  const int t = threadIdx.x;
  const int tr = t >> 4;
  const int tc = (t & 15) * 4;
#pragma unroll
  for (int it = 0; it < 4; it++) {
    const int r = tr + it * 16;
    const float4 v = *(const float4*)(W + (size_t)(k0 + r) * N + n0 + tc);
    tile[r][tc] = v.x; tile[r][tc + 1] = v.y; tile[r][tc + 2] = v.z; tile[r][tc + 3] = v.w;
  }
  __syncthreads();
#pragma unroll
  for (int it = 0; it < 4; it++) {
    const int rn = tr + it * 16;
    const int n = n0 + rn;
    const int k = k0 + tc;  // 4 consecutive k, within one 8-elem slot
    ushort4 o;
    o.x = f2bf(tile[tc][rn]);
    o.y = f2bf(tile[tc + 1][rn]);
    o.z = f2bf(tile[tc + 2][rn]);
    o.w = f2bf(tile[tc + 3][rn]);
    *(ushort4*)(Wt + pk_addr(n, k, K)) = o;
  }
}

__global__ __launch_bounds__(256)
void wconv_all(const float* __restrict__ Wqkv, const float* __restrict__ Wo,
               const float* __restrict__ W1, const float* __restrict__ W2,
               u16* __restrict__ Wqkv_t, u16* __restrict__ Wo_t,
               u16* __restrict__ W1_t, u16* __restrict__ W2_t) {
  const int id = blockIdx.x;  // uniform per block
  if (id < 768)       { wconv_body(Wqkv, Wqkv_t, 1024, 3072, id % 48, id / 48); }
  else if (id < 1024) { const int j = id - 768;  wconv_body(Wo, Wo_t, 1024, 1024, j % 16, j / 16); }
  else if (id < 2048) { const int j = id - 1024; wconv_body(W1, W1_t, 1024, 4096, j % 64, j / 64); }
  else                { const int j = id - 2048; wconv_body(W2, W2_t, 4096, 1024, j % 16, j / 16); }
}

// ---------------- LayerNorm (fp32 in -> frag-packed bf16 out) ----------------
__global__ __launch_bounds__(256)
void ln_bf16(const float* __restrict__ x, const float* __restrict__ w,
             const float* __restrict__ b, u16* __restrict__ out) {
  const int row = blockIdx.x;
  const int t = threadIdx.x;
  const float4 v = *(const float4*)(x + (size_t)row * 1024 + t * 4);
  float s = v.x + v.y + v.z + v.w;
  float s2 = v.x * v.x + v.y * v.y + v.z * v.z + v.w * v.w;
#pragma unroll
  for (int m = 1; m < 64; m <<= 1) {
    s += __shfl_xor(s, m);
    s2 += __shfl_xor(s2, m);
  }
  __shared__ float red[8];
  if ((t & 63) == 0) { red[t >> 6] = s; red[4 + (t >> 6)] = s2; }
  __syncthreads();
  s = red[0] + red[1] + red[2] + red[3];
  s2 = red[4] + red[5] + red[6] + red[7];
  const float mu = s * (1.f / 1024.f);
  const float var = fmaxf(s2 * (1.f / 1024.f) - mu * mu, 0.f);
  const float rstd = rsqrtf(var + 1e-5f);
  const float* wp = w + t * 4;
  const float* bp = b + t * 4;
  ushort4 o;
  o.x = f2bf((v.x - mu) * rstd * wp[0] + bp[0]);
  o.y = f2bf((v.y - mu) * rstd * wp[1] + bp[1]);
  o.z = f2bf((v.z - mu) * rstd * wp[2] + bp[2]);
  o.w = f2bf((v.w - mu) * rstd * wp[3] + bp[3]);
  *(ushort4*)(out + pk_addr(row, t * 4, 1024)) = o;
}

// ---------------- fused: x2 = x + sum(pb[0..3]); h2 = LN(x2) packed ----------
__global__ __launch_bounds__(256)
void reduce_ln(const float* __restrict__ x, const u16* __restrict__ pb,
               const float* __restrict__ w, const float* __restrict__ b,
               float* __restrict__ x2, u16* __restrict__ h2) {
  const int row = blockIdx.x;
  const int t = threadIdx.x;
  const size_t base = (size_t)row * 1024 + t * 4;
  float4 v = *(const float4*)(x + base);
#pragma unroll
  for (int z = 0; z < 4; z++) {
    const ushort4 p = *(const ushort4*)(pb + (size_t)z * 2097152 + base);
    v.x += bf2f(p.x); v.y += bf2f(p.y); v.z += bf2f(p.z); v.w += bf2f(p.w);
  }
  *(float4*)(x2 + base) = v;
  float s = v.x + v.y + v.z + v.w;
  float s2 = v.x * v.x + v.y * v.y + v.z * v.z + v.w * v.w;
#pragma unroll
  for (int m = 1; m < 64; m <<= 1) {
    s += __shfl_xor(s, m);
    s2 += __shfl_xor(s2, m);
  }
  __shared__ float red[8];
  if ((t & 63) == 0) { red[t >> 6] = s; red[4 + (t >> 6)] = s2; }
  __syncthreads();
  s = red[0] + red[1] + red[2] + red[3];
  s2 = red[4] + red[5] + red[6] + red[7];
  const float mu = s * (1.f / 1024.f);
  const float var = fmaxf(s2 * (1.f / 1024.f) - mu * mu, 0.f);
  const float rstd = rsqrtf(var + 1e-5f);
  const float* wp = w + t * 4;
  const float* bp = b + t * 4;
  ushort4 o;
  o.x = f2bf((v.x - mu) * rstd * wp[0] + bp[0]);
  o.y = f2bf((v.y - mu) * rstd * wp[1] + bp[1]);
  o.z = f2bf((v.z - mu) * rstd * wp[2] + bp[2]);
  o.w = f2bf((v.w - mu) * rstd * wp[3] + bp[3]);
  *(ushort4*)(h2 + pk_addr(row, t * 4, 1024)) = o;
}

// ---------------- fused: out = x2 + bias + sum(pb[0..3]) ---------------------
__global__ __launch_bounds__(256)
void reduce_out(const float* __restrict__ x2, const float* __restrict__ bias,
                const u16* __restrict__ pb, float* __restrict__ out) {
  const size_t base = ((size_t)blockIdx.x * 256 + threadIdx.x) * 4;
  const int col = (int)(base & 1023);
  float4 v = *(const float4*)(x2 + base);
  const float4 bb = *(const float4*)(bias + col);
  v.x += bb.x; v.y += bb.y; v.z += bb.z; v.w += bb.w;
#pragma unroll
  for (int z = 0; z < 4; z++) {
    const ushort4 p = *(const ushort4*)(pb + (size_t)z * 2097152 + base);
    v.x += bf2f(p.x); v.y += bf2f(p.y); v.z += bf2f(p.z); v.w += bf2f(p.w);
  }
  *(float4*)(out + base) = v;
}

// ---------------- LDS-free frag-packed bf16 GEMM, 128x128, split-K ----------
// Ap: pk-packed [M][K]; Bp: pk-packed [N][K]. No LDS, no barriers: each wave
// owns a 64x64 output tile and loads its 8 fragments per k-tile directly
// global->reg as coalesced 1-KB dwordx4 (attn-v4 structure, which measured
// latency-covered). Register double-buffer; compiler inserts counted vmcnt.
// EPI 0: QKV split -> attn-packed Qp/Kp/Vp
// EPI 2: ffb = pk(gelu(C + bias))      (packed for FF2's A)
// EPI 4: bf16 partial -> pb + z*M*N    (row-major)
template <int EPI, int KS>
__global__ __launch_bounds__(256)
void gemm_pk(const u16* __restrict__ Ap, const u16* __restrict__ Bp,
             int M, int N, int K,
             const float* __restrict__ bias, u16* __restrict__ pb,
             u16* __restrict__ outB,
             u16* __restrict__ qo, u16* __restrict__ ko, u16* __restrict__ vo) {
  const int t = threadIdx.x;
  const int l = t & 63;
  const int w = t >> 6;
  const int WR = (w >> 1) * 64, WC = (w & 1) * 64;
  const int l15 = l & 15, lg = l >> 4;

  // XCD-chunked swizzle (gridDim.x % 8 == 0 at all call sites)
  const int nx = gridDim.x;
  const u32 bid = blockIdx.y * nx + blockIdx.x;
  const int nxc = nx >> 3;
  const u32 r = bid >> 3;
  const int bx = (bid & 7) * nxc + (int)(r % (u32)nxc);
  const int by = (int)(r / (u32)nxc);

  const int m0 = by * 128, n0 = bx * 128;
  const int KT = K >> 5;               // total k-tiles
  const int nt = (K / KS) >> 5;        // k-tiles this z-slice (even everywhere)
  const int t0 = blockIdx.z * nt;

  const u16* aB = Ap + ((size_t)((m0 + WR) >> 4) * KT + t0) * 512 + l * 8;
  const u16* bB = Bp + ((size_t)((n0 + WC) >> 4) * KT + t0) * 512 + l * 8;

  f32x4 acc[4][4] = {};
  bf16x8 a0[4], b0[4], a1[4], b1[4];

  auto LD = [&](bf16x8 (&af)[4], bf16x8 (&bf_)[4], int ti) {
#pragma unroll
    for (int i = 0; i < 4; i++)
      af[i] = *(const bf16x8*)(aB + ((size_t)i * KT + ti) * 512);
#pragma unroll
    for (int j = 0; j < 4; j++)
      bf_[j] = *(const bf16x8*)(bB + ((size_t)j * KT + ti) * 512);
  };
  auto FMA = [&](bf16x8 (&af)[4], bf16x8 (&bf_)[4]) {
    __builtin_amdgcn_s_setprio(1);
#pragma unroll
    for (int i = 0; i < 4; i++)
#pragma unroll
      for (int j = 0; j < 4; j++)
        acc[i][j] = mfma16(af[i], bf_[j], acc[i][j]);
    __builtin_amdgcn_s_setprio(0);
  };

  LD(a0, b0, 0);
  for (int ti = 0; ti < nt; ti += 2) {
    LD(a1, b1, (ti + 1 < nt) ? ti + 1 : ti);   // prefetch; clamped tail reload
    FMA(a0, b0);
    LD(a0, b0, (ti + 2 < nt) ? ti + 2 : ti);
    FMA(a1, b1);
  }

  const int mr0 = m0 + WR + lg * 4;
  const int nc0 = n0 + WC + l15;
#pragma unroll
  for (int i = 0; i < 4; i++) {
    const int mr = mr0 + i * 16;  // base row (multiple of 4); rows mr..mr+3
#pragma unroll
    for (int j = 0; j < 4; j++) {
      const int nc = nc0 + j * 16;
      if (EPI == 0) {
        const int sel = nc >> 10;
        const int d = nc & 1023;
        const int h = d >> 6, dl = d & 63;
        const int kt2 = mr >> 5;
        if (sel == 2) {
          // Vp[h][kt][nb][lane][el] (attn layout); lane parts from s and d
          const int lgp = (mr >> 3) & 3, el0 = mr & 7;
          const int nb = dl >> 4, l15p = dl & 15;
          u16* dst = vo + (size_t)(h * 64 + kt2) * 2048 + nb * 512 +
                     (lgp * 16 + l15p) * 8 + el0;
          ushort4 o;
          o.x = f2bf(acc[i][j][0]); o.y = f2bf(acc[i][j][1]);
          o.z = f2bf(acc[i][j][2]); o.w = f2bf(acc[i][j][3]);
          *(ushort4*)dst = o;
        } else {
          // Qp/Kp[h][kt][f][kk][lane][el] (attn layout)
          const int f = (mr >> 4) & 1, l15p0 = mr & 15;
          const int kk = dl >> 5, lgp = (dl >> 3) & 3, el = dl & 7;
          u16* dst = (sel == 0 ? qo : ko) + (size_t)(h * 64 + kt2) * 2048 +
                     f * 1024 + kk * 512 + (lgp * 16 + l15p0) * 8 + el;
#pragma unroll
          for (int e = 0; e < 4; e++)
            dst[e * 8] = f2bf(acc[i][j][e]);
        }
      } else if (EPI == 2) {
        const float bb = bias[nc];
#pragma unroll
        for (int e = 0; e < 4; e++) {
          const float v = acc[i][j][e] + bb;
          const float g = 0.5f * v * (1.0f + tanhf(0.7978845608028654f * (v + 0.044715f * v * v * v)));
          outB[pk_addr(mr + e, nc, 4096)] = f2bf(g);
        }
      } else {
        u16* po = pb + (size_t)blockIdx.z * M * N;
#pragma unroll
        for (int e = 0; e < 4; e++)
          po[(size_t)(mr + e) * N + nc] = f2bf(acc[i][j][e]);
      }
    }
  }
}

// ---------------- causal flash attention v4 (unchanged core) -----------------
__device__ __forceinline__ void attn_load(
    bf16x8 (&kf)[2][2], bf16x8 (&vf)[4],
    const u16* __restrict__ Kp, const u16* __restrict__ Vp,
    int hkt, int l) {  // hkt = (h*64 + kt) * 2048
#pragma unroll
  for (int f = 0; f < 2; f++)
#pragma unroll
    for (int kk = 0; kk < 2; kk++)
      kf[kk][f] = *(const bf16x8*)(Kp + hkt + f * 1024 + kk * 512 + l * 8);
#pragma unroll
  for (int nb = 0; nb < 4; nb++)
    vf[nb] = *(const bf16x8*)(Vp + hkt + nb * 512 + l * 8);
}

__device__ __forceinline__ void attn_tile(
    const bf16x8 (&kf)[2][2], const bf16x8 (&vf)[4], const bf16x8 (&qf)[2][2],
    f32x4 (&accO)[2][4], float (&lsum)[2], u16* myP,
    int k0, bool diag, int qb, int l15, int lg) {
  f32x4 sv[2][2] = {};
  __builtin_amdgcn_s_setprio(1);
#pragma unroll
  for (int g = 0; g < 2; g++)
#pragma unroll
    for (int f = 0; f < 2; f++)
#pragma unroll
      for (int kk = 0; kk < 2; kk++)
        sv[g][f] = mfma16(kf[kk][f], qf[g][kk], sv[g][f]);
  __builtin_amdgcn_s_setprio(0);
#pragma unroll
  for (int g = 0; g < 2; g++) {
#pragma unroll
    for (int f = 0; f < 2; f++) {
      bf16x4 pk;
      float ps = 0.f;
#pragma unroll
      for (int e = 0; e < 4; e++) {
        float p = exp2f(sv[g][f][e] * 0.1803368801f);  // exp(s/8)
        if (diag && (k0 + f * 16 + lg * 4 + e > qb + g * 16 + l15)) p = 0.f;
        ps += p;
        pk[e] = (bf16)p;
      }
      lsum[g] += ps;
      *(bf16x4*)(myP + g * 640 + l15 * 40 + f * 16 + lg * 4) = pk;
    }
  }
  const bf16x8 pf0 = *(const bf16x8*)(myP + l15 * 40 + lg * 8);
  const bf16x8 pf1 = *(const bf16x8*)(myP + 640 + l15 * 40 + lg * 8);
  __builtin_amdgcn_s_setprio(1);
#pragma unroll
  for (int nb = 0; nb < 4; nb++) {
    accO[0][nb] = mfma16(pf0, vf[nb], accO[0][nb]);
    accO[1][nb] = mfma16(pf1, vf[nb], accO[1][nb]);
  }
  __builtin_amdgcn_s_setprio(0);
}

__global__ __launch_bounds__(256)
void attn_fwd(const u16* __restrict__ Qp, const u16* __restrict__ Kp,
              const u16* __restrict__ Vp, u16* __restrict__ Ob) {
  __shared__ __attribute__((aligned(16))) char smem[33280];
  float* sO = (float*)smem;            // [4][2048] f32 (after barrier)
  float* sL = (float*)(smem + 32768);  // [4][32]
  u16* lP = (u16*)smem;                // [2 buf][4 waves][1280 u16]

  const int t = threadIdx.x;
  const int l = t & 63, w = t >> 6;
  const int l15 = l & 15, lg = l >> 4;
  const u32 bid = blockIdx.x;
  const u32 vb = (bid & 7) * 128 + (bid >> 3);
  const int h = (int)(vb >> 6);
  const int qt = 63 - (int)(vb & 63);  // LPT within chunk
  const int qb = qt * 32;

  u16* myPA = lP + w * 1280;
  u16* myPB = lP + 5120 + w * 1280;

  bf16x8 qf[2][2];
#pragma unroll
  for (int g = 0; g < 2; g++)
#pragma unroll
    for (int kk = 0; kk < 2; kk++)
      qf[g][kk] = *(const bf16x8*)(Qp + (size_t)(h * 64 + qt) * 2048 +
                                   g * 1024 + kk * 512 + l * 8);

  f32x4 accO[2][4] = {};
  float lsum[2] = {0.f, 0.f};

  if (w <= qt) {
    const int hb = h * 64;
    bf16x8 kfA[2][2], vfA[4], kfB[2][2], vfB[4];
    attn_load(kfA, vfA, Kp, Vp, (hb + w) * 2048, l);
    int kt = w;
    while (true) {
      const int ktB = kt + 4;
      const bool hasB = (ktB <= qt);
      attn_load(kfB, vfB, Kp, Vp, (hb + (hasB ? ktB : kt)) * 2048, l);
      attn_tile(kfA, vfA, qf, accO, lsum, myPA, kt * 32, kt == qt, qb, l15, lg);
      if (!hasB) break;
      const int ktA = kt + 8;
      const bool hasA = (ktA <= qt);
      attn_load(kfA, vfA, Kp, Vp, (hb + (hasA ? ktA : ktB)) * 2048, l);
      attn_tile(kfB, vfB, qf, accO, lsum, myPB, ktB * 32, ktB == qt, qb, l15, lg);
      if (!hasA) break;
      kt = ktA;
    }
  }

  float lsr[2];
#pragma unroll
  for (int g = 0; g < 2; g++) {
    float v = lsum[g];
    v += __shfl_xor(v, 16);
    v += __shfl_xor(v, 32);
    lsr[g] = v;
  }

  __syncthreads();  // all waves done with lP; smem becomes sO
#pragma unroll
  for (int g = 0; g < 2; g++) {
#pragma unroll
    for (int nb = 0; nb < 4; nb++)
#pragma unroll
      for (int e = 0; e < 4; e++)
        sO[w * 2048 + (g * 16 + lg * 4 + e) * 64 + nb * 16 + l15] = accO[g][nb][e];
    if (lg == 0) sL[w * 32 + g * 16 + l15] = lsr[g];
  }
  __syncthreads();

  const int base = t * 8;
  const int row = base >> 6;       // 0..31 within q-tile
  const int col = base & 63;       // 0..56 step 8 within head
  f32x4 a0 = {}, a1 = {};
  float ls = 0.f;
#pragma unroll
  for (int ww = 0; ww < 4; ww++) {
    a0 += *(const f32x4*)&sO[ww * 2048 + base];
    a1 += *(const f32x4*)&sO[ww * 2048 + base + 4];
    ls += sL[ww * 32 + row];
  }
  const float rinv = 1.0f / ls;
  u16x8 o;
#pragma unroll
  for (int j = 0; j < 4; j++) {
    o[j] = f2bf(a0[j] * rinv);
    o[4 + j] = f2bf(a1[j] * rinv);
  }
  // frag-packed write (generic pk layout, C=1024); 8 cols share one slot run
  const int grow = qb + row;
  const int gcol = h * 64 + col;
  *(u16x8*)(Ob + pk_addr(grow, gcol, 1024)) = o;
}

// ---------------- launch ----------------------------------------------------
extern "C" void kernel_launch(void* const* d_in, const int* in_sizes, int n_in,
                              void* d_out, int out_size, void* d_ws, size_t ws_size,
                              hipStream_t stream) {
  const float* x     = (const float*)d_in[0];
  const float* W_qkv = (const float*)d_in[1];
  const float* W_o   = (const float*)d_in[2];
  const float* W1    = (const float*)d_in[3];
  const float* b1    = (const float*)d_in[4];
  const float* W2    = (const float*)d_in[5];
  const float* b2    = (const float*)d_in[6];
  const float* ln_aw = (const float*)d_in[7];
  const float* ln_ab = (const float*)d_in[8];
  const float* ln_mw = (const float*)d_in[9];
  const float* ln_mb = (const float*)d_in[10];

  // workspace (lifetime-aliased; peak 71.3 MB):
  char* ws = (char*)d_ws;
  u16* Wqkv_t = (u16*)(ws);                  // pk [3072][1024]     6 MB persistent
  u16* Wo_t   = (u16*)(ws + 6291456);        // pk [1024][1024]     2 MB persistent
  u16* W1_t   = (u16*)(ws + 8388608);        // pk [4096][1024]     8 MB persistent
  u16* W2_t   = (u16*)(ws + 16777216);       // pk [1024][4096]     8 MB persistent
  u16* h1     = (u16*)(ws + 25165824);       // pk [2048][1024]     4 MB (h2 alias)
  u16* h2     = h1;
  u16* Qp     = (u16*)(ws + 29360128);       // attn-packed Q       4 MB
  u16* Kp     = (u16*)(ws + 33554432);       // attn-packed K       4 MB
  u16* Vp     = (u16*)(ws + 37748736);       // attn-packed V       4 MB
  u16* attnb  = (u16*)(ws + 41943040);       // pk [2048][1024]     4 MB
  u16* ffb    = (u16*)(ws + 29360128);       // pk [2048][4096]    16 MB aliases Qp..attnb
  u16* pb     = (u16*)(ws + 46137344);       // 4x bf16 [2048][1024] 16 MB split-K partials
  float* x2   = (float*)(ws + 62914560);     // f32 [2048][1024]    8 MB
  (void)ws_size; (void)in_sizes; (void)n_in; (void)out_size;

  wconv_all<<<3072, 256, 0, stream>>>(W_qkv, W_o, W1, W2, Wqkv_t, Wo_t, W1_t, W2_t);

  ln_bf16<<<2048, 256, 0, stream>>>(x, ln_aw, ln_ab, h1);

  // QKV: M=2048 N=3072 K=1024 -> (24,16) = 384 blocks
  gemm_pk<0, 1><<<dim3(24, 16), 256, 0, stream>>>(
      h1, Wqkv_t, 2048, 3072, 1024, nullptr, nullptr, nullptr, Qp, Kp, Vp);

  attn_fwd<<<1024, 256, 0, stream>>>(Qp, Kp, Vp, attnb);

  // W_o: M=2048 N=1024 K=1024, split-K=4 -> (8,16,4) = 512 blocks
  gemm_pk<4, 4><<<dim3(8, 16, 4), 256, 0, stream>>>(
      attnb, Wo_t, 2048, 1024, 1024, nullptr, pb, nullptr, nullptr, nullptr, nullptr);

  reduce_ln<<<2048, 256, 0, stream>>>(x, pb, ln_mw, ln_mb, x2, h2);

  // FF1: M=2048 N=4096 K=1024 -> (32,16) = 512 blocks
  gemm_pk<2, 1><<<dim3(32, 16), 256, 0, stream>>>(
      h2, W1_t, 2048, 4096, 1024, b1, nullptr, ffb, nullptr, nullptr, nullptr);

  // FF2: M=2048 N=1024 K=4096, split-K=4 -> (8,16,4) = 512 blocks
  gemm_pk<4, 4><<<dim3(8, 16, 4), 256, 0, stream>>>(
      ffb, W2_t, 2048, 1024, 4096, nullptr, pb, nullptr, nullptr, nullptr, nullptr);

  reduce_out<<<2048, 256, 0, stream>>>(x2, b2, pb, (float*)d_out);
}